// Round 6
// baseline (3603.890 us; speedup 1.0000x reference)
//
#include <hip/hip_runtime.h>
#include <hip/hip_bf16.h>
#include <math.h>

typedef __bf16 bf16;
typedef bf16 bf16x8 __attribute__((ext_vector_type(8)));
typedef bf16 bf16x4 __attribute__((ext_vector_type(4)));
typedef float f32x4 __attribute__((ext_vector_type(4)));

#define BQ 32
#define TT 197
#define DD 768
#define HH 12
#define FF 3072
#define LL 12
#define TP 224
#define MR 6304   // B*T
#define MP 6400   // padded to 50*128 (= 25*256)
#define MQ 75648  // B*T*H rows for qkv gemm (591*128)
#define KST 72    // K LDS row stride (elements)
#define PST 232   // P / Vt LDS row stride (elements)
#define NSPLIT 4  // MLP2 split-K factor

typedef __attribute__((address_space(1))) const void gv_t;
typedef __attribute__((address_space(3))) void lv_t;

__device__ __forceinline__ void gld16(const void* g, void* l) {
    __builtin_amdgcn_global_load_lds((gv_t*)g, (lv_t*)l, 16, 0, 0);
}

__device__ __forceinline__ f32x4 mfma16(bf16x8 a, bf16x8 b, f32x4 c) {
    return __builtin_amdgcn_mfma_f32_16x16x32_bf16(a, b, c, 0, 0, 0);
}

// tanh-approx GELU via hw v_exp_f32; overflow-safe (e=inf -> th=1)
__device__ __forceinline__ float fast_gelu(float v) {
    float t = 0.79788456080286535588f * v * (1.0f + 0.044715f * v * v);
    float e = __expf(2.0f * t);
    float th = 1.0f - 2.0f / (e + 1.0f);
    return 0.5f * v * (1.0f + th);
}

// bijective XCD swizzle (m204): consecutive wgid stay on one XCD
__device__ __forceinline__ int xcd_swz(int bid, int nwg) {
    int q = nwg >> 3, r = nwg & 7;
    int xcd = bid & 7, pos = bid >> 3;
    int base = (xcd < r) ? xcd * (q + 1) : r * (q + 1) + (xcd - r) * q;
    return base + pos;
}

// ---------------------------------------------------------------------------
// 256x256 tile GEMM, BK=64, 8 waves (2M x 4N), 128 KiB LDS double-buffer.
// Per wave: 128x64 output = 8 m-frags x 4 n-frags (acc 128 VGPR).
// Pipeline: stage(t+1) spread over the 4 compute phases of tile t
// (2 gld16/thread/phase); per-phase setprio-wrapped 16-MFMA cluster +
// barrier; ONE vmcnt(0)+barrier per K-tile (issue-to-drain distance =
// 4 phases of MFMA -> HBM latency hidden). XOR swizzle cb^(row&7) on the
// global SOURCE (LDS dest linear, rule #21), mirrored on ds_read side
// (0 bank conflicts, PMC-verified r4/r5).
// EPI 1: +bias, fast GELU -> bf16 out (stride N)
// EPI 3: raw partial write -> outF[ks*MP*DD + row*DD + col] (no bias)
// ---------------------------------------------------------------------------
template <int EPI, int SPLITK>
__global__ __launch_bounds__(512, 2)
void gemm256(const bf16* __restrict__ A, const bf16* __restrict__ W,
             const float* __restrict__ bias, int K, int N,
             float* __restrict__ outF, bf16* __restrict__ outB,
             int gx, int gy) {
    __shared__ __align__(16) bf16 As[2][256 * 64];
    __shared__ __align__(16) bf16 Bs[2][256 * 64];
    const int tid = threadIdx.x;
    const int lane = tid & 63, wave = tid >> 6;
    const int wm = wave >> 2, wn = wave & 3;

    const int wgid = xcd_swz(blockIdx.x, gridDim.x);
    const int ks   = (SPLITK > 1) ? wgid / (gx * gy) : 0;
    const int rem  = (SPLITK > 1) ? wgid % (gx * gy) : wgid;
    const int bx = rem % gx, by = rem / gx;
    const int m0 = by * 256, n0 = bx * 256;

    const int kb = K / SPLITK;
    const int k0 = ks * kb;
    const int nt = kb / 64;

    f32x4 acc[8][4] = {};
    const bf16* Ab = A + (size_t)m0 * K;
    const bf16* Wb = W + (size_t)n0 * K;

    // stage unit u (0..3) of tile half: 512 units of 16B per matrix per tile
    auto stageA = [&](int buf, int kt, int u) {
        int idx = u * 512 + tid;
        int row = idx >> 3, cb = idx & 7;
        int gcb = cb ^ (row & 7);
        gld16(Ab + (size_t)row * K + kt + gcb * 8, &As[buf][idx * 8]);
    };
    auto stageB = [&](int buf, int kt, int u) {
        int idx = u * 512 + tid;
        int row = idx >> 3, cb = idx & 7;
        int gcb = cb ^ (row & 7);
        gld16(Wb + (size_t)row * K + kt + gcb * 8, &Bs[buf][idx * 8]);
    };

#pragma unroll
    for (int u = 0; u < 4; u++) { stageA(0, k0, u); stageB(0, k0, u); }
    asm volatile("s_waitcnt vmcnt(0)" ::: "memory");
    __syncthreads();

    int cur = 0;
    for (int t = 0; t < nt; ++t) {
        const int ktn = k0 + (t + 1) * 64;
        const bool pf = (t + 1 < nt);
        const int ca = lane >> 4;
        bf16x8 bfr[4][2];
#pragma unroll
        for (int p = 0; p < 4; p++) {
            if (pf) { stageA(cur ^ 1, ktn, p); stageB(cur ^ 1, ktn, p); }
            if (p == 0) {
#pragma unroll
                for (int nf = 0; nf < 4; nf++) {
                    int rowb = wn * 64 + nf * 16 + (lane & 15);
                    int mb = rowb & 7;
                    bfr[nf][0] = *(const bf16x8*)(&Bs[cur][rowb * 64 + ((ca    ) ^ mb) * 8]);
                    bfr[nf][1] = *(const bf16x8*)(&Bs[cur][rowb * 64 + ((ca + 4) ^ mb) * 8]);
                }
            }
            bf16x8 af[2][2];
#pragma unroll
            for (int mi = 0; mi < 2; mi++) {
                int rowa = wm * 128 + (p * 2 + mi) * 16 + (lane & 15);
                int ma = rowa & 7;
                af[mi][0] = *(const bf16x8*)(&As[cur][rowa * 64 + ((ca    ) ^ ma) * 8]);
                af[mi][1] = *(const bf16x8*)(&As[cur][rowa * 64 + ((ca + 4) ^ ma) * 8]);
            }
            __builtin_amdgcn_s_setprio(1);
#pragma unroll
            for (int mi = 0; mi < 2; mi++)
#pragma unroll
                for (int nf = 0; nf < 4; nf++)
#pragma unroll
                    for (int kh = 0; kh < 2; kh++)
                        acc[p * 2 + mi][nf] = mfma16(af[mi][kh], bfr[nf][kh],
                                                     acc[p * 2 + mi][nf]);
            __builtin_amdgcn_s_setprio(0);
            if (p < 3) __syncthreads();
        }
        asm volatile("s_waitcnt vmcnt(0)" ::: "memory");
        __syncthreads();
        cur ^= 1;
    }

    const int r0 = m0 + wm * 128, c0 = n0 + wn * 64;
#pragma unroll
    for (int mf = 0; mf < 8; mf++) {
#pragma unroll
        for (int j = 0; j < 4; j++) {
            int row = r0 + mf * 16 + ((lane >> 4) * 4) + j;
#pragma unroll
            for (int nf = 0; nf < 4; nf++) {
                int col = c0 + nf * 16 + (lane & 15);
                float v = acc[mf][nf][j];
                if (EPI == 1) {
                    v += bias[col];
                    outB[(size_t)row * N + col] = (bf16)fast_gelu(v);
                } else {
                    outF[(size_t)(ks * MP + row) * DD + col] = v;
                }
            }
        }
    }
}

// ---------------------------------------------------------------------------
// 128x128 tile GEMM (r5-proven), kept for patch embed + fallback.
// EPI 0: +bias, patch-embed -> h rows (b*197+1+n) += pos_enc (fp32 write)
// EPI 2: +bias, direct residual += into fp32 out (stride 768)
// ---------------------------------------------------------------------------
template <int EPI, int SPLITK>
__global__ __launch_bounds__(256, 4)
void gemm_bt(const bf16* __restrict__ A, const bf16* __restrict__ W,
             const float* __restrict__ bias, int K, int N,
             float* __restrict__ outF, bf16* __restrict__ outB,
             const float* __restrict__ pos, int gx, int gy) {
    __shared__ bf16 As[128 * 64];
    __shared__ bf16 Bs[128 * 64];
    const int tid = threadIdx.x;
    const int lane = tid & 63, wave = tid >> 6;
    const int wm = wave >> 1, wn = wave & 1;

    const int wgid = xcd_swz(blockIdx.x, gridDim.x);
    const int ks   = (SPLITK > 1) ? wgid / (gx * gy) : 0;
    const int rem  = (SPLITK > 1) ? wgid % (gx * gy) : wgid;
    const int bx = rem % gx, by = rem / gx;
    const int m0 = by * 128, n0 = bx * 128;

    const int kb = K / SPLITK;
    const int k0 = ks * kb, k1 = k0 + kb;

    f32x4 acc[4][4] = {};
    const bf16* Ab = A + (size_t)m0 * K;
    const bf16* Wb = W + (size_t)n0 * K;

    for (int kt = k0; kt < k1; kt += 64) {
#pragma unroll
        for (int i = 0; i < 4; i++) {
            int idx = i * 256 + tid;
            int row = idx >> 3, cb = idx & 7;
            int gcb = cb ^ (row & 7);
            gld16(Ab + (size_t)row * K + kt + gcb * 8, As + idx * 8);
            gld16(Wb + (size_t)row * K + kt + gcb * 8, Bs + idx * 8);
        }
        __syncthreads();
        bf16x8 af[4][2], bfr[4][2];
        const int ca = lane >> 4;
#pragma unroll
        for (int f = 0; f < 4; f++) {
            int rowa = wm * 64 + f * 16 + (lane & 15);
            int ma = rowa & 7;
            af[f][0] = *(const bf16x8*)(As + rowa * 64 + ((ca    ) ^ ma) * 8);
            af[f][1] = *(const bf16x8*)(As + rowa * 64 + ((ca + 4) ^ ma) * 8);
            int rowb = wn * 64 + f * 16 + (lane & 15);
            int mb = rowb & 7;
            bfr[f][0] = *(const bf16x8*)(Bs + rowb * 64 + ((ca    ) ^ mb) * 8);
            bfr[f][1] = *(const bf16x8*)(Bs + rowb * 64 + ((ca + 4) ^ mb) * 8);
        }
#pragma unroll
        for (int kh = 0; kh < 2; kh++)
#pragma unroll
            for (int mf = 0; mf < 4; mf++)
#pragma unroll
                for (int nf = 0; nf < 4; nf++)
                    acc[mf][nf] = mfma16(af[mf][kh], bfr[nf][kh], acc[mf][nf]);
        __syncthreads();
    }

    const int r0 = m0 + wm * 64, c0 = n0 + wn * 64;
#pragma unroll
    for (int mf = 0; mf < 4; mf++) {
#pragma unroll
        for (int j = 0; j < 4; j++) {
            int row = r0 + mf * 16 + ((lane >> 4) * 4) + j;
            int pb = 0, pn = 0;
            if (EPI == 0) { pb = row / 196; pn = row - pb * 196; }
#pragma unroll
            for (int nf = 0; nf < 4; nf++) {
                int col = c0 + nf * 16 + (lane & 15);
                float v = acc[mf][nf][j];
                if (EPI == 0) {
                    v += bias[col];
                    float pv = pos[(size_t)(1 + pn) * DD + col];
                    outF[(size_t)(pb * TT + 1 + pn) * DD + col] = v + pv;
                } else if (EPI == 1) {
                    v += bias[col];
                    outB[(size_t)row * N + col] = (bf16)fast_gelu(v);
                } else if (EPI == 2) {
                    v += bias[col];
                    if (row < MR) outF[(size_t)row * DD + col] += v;
                } else {
                    outF[(size_t)(ks * MP + row) * DD + col] = v;
                }
            }
        }
    }
}

// ---------------------------------------------------------------------------
// QKV: A = hn viewed as (B*T*H, 64) contiguous (since D = H*64).
// C (MQ,192) = A @ qkv_w(192,64)^T + qkv_b, scattered to Q/K/V (B*H, 224, 64)
// ---------------------------------------------------------------------------
__global__ __launch_bounds__(256, 2)
void qkv_kernel(const bf16* __restrict__ hn, const bf16* __restrict__ qw,
                const float* __restrict__ qb, bf16* __restrict__ Q,
                bf16* __restrict__ Kb, bf16* __restrict__ Vb) {
    __shared__ bf16 Asm[128 * 64];
    __shared__ bf16 Wsm[192 * 64];
    const int tid = threadIdx.x, lane = tid & 63, wave = tid >> 6;
    const bf16* Ab = hn + (size_t)blockIdx.x * (128 * 64);
#pragma unroll
    for (int i = 0; i < 4; i++) {
        int idx = i * 256 + tid;
        int row = idx >> 3, cb = idx & 7;
        int gcb = cb ^ (row & 7);
        gld16(Ab + (size_t)row * 64 + gcb * 8, Asm + idx * 8);
    }
#pragma unroll
    for (int i = 0; i < 6; i++) {
        int idx = i * 256 + tid;
        int row = idx >> 3, cb = idx & 7;
        int gcb = cb ^ (row & 7);
        gld16(qw + (size_t)row * 64 + gcb * 8, Wsm + idx * 8);
    }
    __syncthreads();

    const int ca = lane >> 4;
    bf16x8 af[2][2];
#pragma unroll
    for (int mf = 0; mf < 2; mf++) {
        int row = wave * 32 + mf * 16 + (lane & 15);
        int m7 = row & 7;
        af[mf][0] = *(const bf16x8*)(Asm + row * 64 + ((ca    ) ^ m7) * 8);
        af[mf][1] = *(const bf16x8*)(Asm + row * 64 + ((ca + 4) ^ m7) * 8);
    }
    f32x4 acc[2][12] = {};
#pragma unroll
    for (int nf = 0; nf < 12; nf++) {
        int row = nf * 16 + (lane & 15);
        int m7 = row & 7;
        bf16x8 b0 = *(const bf16x8*)(Wsm + row * 64 + ((ca    ) ^ m7) * 8);
        bf16x8 b1 = *(const bf16x8*)(Wsm + row * 64 + ((ca + 4) ^ m7) * 8);
#pragma unroll
        for (int mf = 0; mf < 2; mf++) {
            acc[mf][nf] = mfma16(af[mf][0], b0, acc[mf][nf]);
            acc[mf][nf] = mfma16(af[mf][1], b1, acc[mf][nf]);
        }
    }
    const int r0 = blockIdx.x * 128 + wave * 32;
#pragma unroll
    for (int mf = 0; mf < 2; mf++)
#pragma unroll
        for (int j = 0; j < 4; j++) {
            int r = r0 + mf * 16 + (lane >> 4) * 4 + j;
            int bt = r / 12, hh = r - bt * 12;
            int b = bt / 197, t = bt - b * 197;
            size_t dbase = ((size_t)(b * HH + hh) * TP + t) * 64;
#pragma unroll
            for (int nf = 0; nf < 12; nf++) {
                int col = nf * 16 + (lane & 15);
                float v = acc[mf][nf][j] + qb[col];
                int sel = nf >> 2, e = col & 63;
                bf16* dst = (sel == 0) ? Q : (sel == 1 ? Kb : Vb);
                dst[dbase + e] = (bf16)v;
            }
        }
}

// ---------------------------------------------------------------------------
// Fused attention per (b,h): scores = QK^T*0.125 (masked >=197), softmax,
// O = P@V, h += O (residual).
// ---------------------------------------------------------------------------
__global__ __launch_bounds__(256, 1)
void attn_kernel(const bf16* __restrict__ Q, const bf16* __restrict__ Kg,
                 const bf16* __restrict__ Vg, float* __restrict__ h) {
    __shared__ bf16 Ks[TP * KST];
    __shared__ bf16 Vt[64 * PST];
    __shared__ bf16 Pw[4 * 16 * PST];
    const int tid = threadIdx.x, lane = tid & 63, wave = tid >> 6;
    const int bh = blockIdx.x;
    const int b = bh / HH, hh = bh - b * HH;
    const bf16* Kp = Kg + (size_t)bh * TP * 64;
    const bf16* Vp = Vg + (size_t)bh * TP * 64;
    const bf16* Qp = Q + (size_t)bh * TP * 64;

#pragma unroll
    for (int i = 0; i < 7; i++) {
        int idx = i * 256 + tid;
        int row = idx >> 3, cb = idx & 7;
        bf16x8 kv = *(const bf16x8*)(Kp + idx * 8);
        *(bf16x8*)(Ks + row * KST + cb * 8) = kv;
        bf16x8 vv = *(const bf16x8*)(Vp + idx * 8);
#pragma unroll
        for (int j = 0; j < 8; j++) Vt[(cb * 8 + j) * PST + row] = vv[j];
    }
    __syncthreads();

    bf16* Pm = Pw + wave * 16 * PST;
    for (int ch = wave; ch < 13; ch += 4) {
        const int q0 = ch * 16;
        const bf16* qp = Qp + (q0 + (lane & 15)) * 64 + (lane >> 4) * 8;
        bf16x8 aq0 = *(const bf16x8*)qp;
        bf16x8 aq1 = *(const bf16x8*)(qp + 32);
        f32x4 s[14] = {};
#pragma unroll
        for (int nf = 0; nf < 14; nf++) {
            int rb = (nf * 16 + (lane & 15)) * KST + (lane >> 4) * 8;
            bf16x8 b0 = *(const bf16x8*)(Ks + rb);
            bf16x8 b1 = *(const bf16x8*)(Ks + rb + 32);
            s[nf] = mfma16(aq0, b0, s[nf]);
            s[nf] = mfma16(aq1, b1, s[nf]);
        }
        const int colbase = lane & 15;
#pragma unroll
        for (int j = 0; j < 4; j++) {
            float pv[14];
            float m = -1e30f;
#pragma unroll
            for (int nf = 0; nf < 14; nf++) {
                int col = nf * 16 + colbase;
                float v = s[nf][j] * 0.125f;
                v = (col < TT) ? v : -1e30f;
                pv[nf] = v;
                m = fmaxf(m, v);
            }
#pragma unroll
            for (int dd = 1; dd < 16; dd <<= 1) m = fmaxf(m, __shfl_xor(m, dd));
            float sum = 0.0f;
#pragma unroll
            for (int nf = 0; nf < 14; nf++) { float e = __expf(pv[nf] - m); pv[nf] = e; sum += e; }
#pragma unroll
            for (int dd = 1; dd < 16; dd <<= 1) sum += __shfl_xor(sum, dd);
            float inv = 1.0f / sum;
            int pr = (lane >> 4) * 4 + j;
#pragma unroll
            for (int nf = 0; nf < 14; nf++)
                Pm[pr * PST + nf * 16 + colbase] = (bf16)(pv[nf] * inv);
        }
        asm volatile("s_waitcnt lgkmcnt(0)" ::: "memory");
        f32x4 o[4] = {};
#pragma unroll
        for (int ks = 0; ks < 7; ks++) {
            bf16x8 pa = *(const bf16x8*)(Pm + (lane & 15) * PST + ks * 32 + (lane >> 4) * 8);
#pragma unroll
            for (int nf = 0; nf < 4; nf++) {
                bf16x8 bv = *(const bf16x8*)(Vt + (nf * 16 + (lane & 15)) * PST + ks * 32 + (lane >> 4) * 8);
                o[nf] = mfma16(pa, bv, o[nf]);
            }
        }
#pragma unroll
        for (int nf = 0; nf < 4; nf++)
#pragma unroll
            for (int j = 0; j < 4; j++) {
                int qr = q0 + (lane >> 4) * 4 + j;
                if (qr < TT) {
                    int d = nf * 16 + (lane & 15);
                    h[(size_t)(b * TT + qr) * DD + hh * 64 + d] += o[nf][j];
                }
            }
    }
}

// ---------------------------------------------------------------------------
// LayerNorm, one row per wave (4 rows/block), fp32 in -> bf16 out
// ---------------------------------------------------------------------------
__device__ __forceinline__ void ln_core(float4 a[3], const float* g, const float* bt,
                                        bf16* hn, int row, int lane) {
    float sum = 0.0f;
#pragma unroll
    for (int i = 0; i < 3; i++) sum += a[i].x + a[i].y + a[i].z + a[i].w;
#pragma unroll
    for (int dd = 1; dd < 64; dd <<= 1) sum += __shfl_xor(sum, dd);
    const float mu = sum * (1.0f / 768.0f);
    float sq = 0.0f;
#pragma unroll
    for (int i = 0; i < 3; i++) {
        float dx = a[i].x - mu, dy = a[i].y - mu, dz = a[i].z - mu, dw = a[i].w - mu;
        sq += dx * dx + dy * dy + dz * dz + dw * dw;
    }
#pragma unroll
    for (int dd = 1; dd < 64; dd <<= 1) sq += __shfl_xor(sq, dd);
    const float is = rsqrtf(sq * (1.0f / 768.0f) + 1e-5f);
#pragma unroll
    for (int i = 0; i < 3; i++) {
        int c4 = lane + i * 64;
        float4 gg = ((const float4*)g)[c4];
        float4 bb = ((const float4*)bt)[c4];
        bf16x4 o;
        o[0] = (bf16)((a[i].x - mu) * is * gg.x + bb.x);
        o[1] = (bf16)((a[i].y - mu) * is * gg.y + bb.y);
        o[2] = (bf16)((a[i].z - mu) * is * gg.z + bb.z);
        o[3] = (bf16)((a[i].w - mu) * is * gg.w + bb.w);
        ((bf16x4*)(hn + (size_t)row * DD))[c4] = o;
    }
}

__global__ void ln_kernel(const float* __restrict__ h, const float* __restrict__ g,
                          const float* __restrict__ bt, bf16* __restrict__ hn) {
    const int lane = threadIdx.x & 63, wave = threadIdx.x >> 6;
    const int row = blockIdx.x * 4 + wave;
    const float* x = h + (size_t)row * DD;
    float4 a[3];
#pragma unroll
    for (int i = 0; i < 3; i++) a[i] = ((const float4*)x)[lane + i * 64];
    ln_core(a, g, bt, hn, row, lane);
}

// h += sum(NS partials) + b2; write h; hn = LN(h)
template <int NS>
__global__ void ln_acc_kernel(float* __restrict__ h, const float* __restrict__ part,
                              const float* __restrict__ b2,
                              const float* __restrict__ g, const float* __restrict__ bt,
                              bf16* __restrict__ hn) {
    const int lane = threadIdx.x & 63, wave = threadIdx.x >> 6;
    const int row = blockIdx.x * 4 + wave;
    float* x = h + (size_t)row * DD;
    float4 a[3];
#pragma unroll
    for (int i = 0; i < 3; i++) a[i] = ((const float4*)x)[lane + i * 64];
#pragma unroll
    for (int s = 0; s < NS; s++) {
        const float4* ps = (const float4*)(part + ((size_t)s * MP + row) * DD);
#pragma unroll
        for (int i = 0; i < 3; i++) {
            float4 p = ps[lane + i * 64];
            a[i].x += p.x; a[i].y += p.y; a[i].z += p.z; a[i].w += p.w;
        }
    }
#pragma unroll
    for (int i = 0; i < 3; i++) {
        float4 bb = ((const float4*)b2)[lane + i * 64];
        a[i].x += bb.x; a[i].y += bb.y; a[i].z += bb.z; a[i].w += bb.w;
        ((float4*)x)[lane + i * 64] = a[i];
    }
    ln_core(a, g, bt, hn, row, lane);
}

// ---------------------------------------------------------------------------
__global__ void patch_extract(const float* __restrict__ x, bf16* __restrict__ p) {
    int idx = blockIdx.x * 256 + threadIdx.x;
    if (idx >= 6272 * 768) return;
    int k = idx % 768, row = idx / 768;
    int c = k % 3, pc = (k / 3) % 16, pr = k / 48;
    int b = row / 196, n = row - b * 196;
    int hp = n / 14, wp = n - hp * 14;
    p[idx] = (bf16)x[((size_t)(b * 3 + c) * 224 + hp * 16 + pr) * 224 + wp * 16 + pc];
}

__global__ void cast_bf16(const float* __restrict__ in, bf16* __restrict__ out, int n4) {
    int i = blockIdx.x * 256 + threadIdx.x;
    int stride = gridDim.x * 256;
    for (; i < n4; i += stride) {
        float4 v = ((const float4*)in)[i];
        bf16x4 o;
        o[0] = (bf16)v.x; o[1] = (bf16)v.y; o[2] = (bf16)v.z; o[3] = (bf16)v.w;
        ((bf16x4*)out)[i] = o;
    }
}

__global__ void cls_init(const float* __restrict__ cls, const float* __restrict__ pos,
                         float* __restrict__ h) {
    int i = blockIdx.x * 256 + threadIdx.x;
    if (i >= BQ * DD) return;
    int b = i / DD, c = i - b * DD;
    h[(size_t)(b * TT) * DD + c] = cls[c] + pos[c];
}

__global__ void head_kernel(const float* __restrict__ h, const float* __restrict__ hw,
                            const float* __restrict__ hb, float* __restrict__ out) {
    __shared__ float xr[DD];
    const int b = blockIdx.y;
    const int n = blockIdx.x * 256 + threadIdx.x;
    for (int i = threadIdx.x; i < DD; i += 256) xr[i] = h[(size_t)(b * TT) * DD + i];
    __syncthreads();
    if (n < 1000) {
        float s = hb[n];
        const float4* w = (const float4*)(hw + (size_t)n * DD);
        float acc = 0.0f;
#pragma unroll 4
        for (int k = 0; k < DD / 4; k++) {
            float4 wv = w[k];
            float4 xv = ((const float4*)xr)[k];
            acc += wv.x * xv.x + wv.y * xv.y + wv.z * xv.z + wv.w * xv.w;
        }
        out[b * 1000 + n] = s + acc;
    }
}

// ---------------------------------------------------------------------------
extern "C" void kernel_launch(void* const* d_in, const int* in_sizes, int n_in,
                              void* d_out, int out_size, void* d_ws, size_t ws_size,
                              hipStream_t stream) {
    const float* x       = (const float*)d_in[0];
    const float* patch_w = (const float*)d_in[1];
    const float* patch_b = (const float*)d_in[2];
    const float* pos_enc = (const float*)d_in[3];
    const float* cls_tok = (const float*)d_in[4];
    const float* qkv_w   = (const float*)d_in[5];
    const float* qkv_b   = (const float*)d_in[6];
    const float* ln_g    = (const float*)d_in[7];
    const float* ln_b    = (const float*)d_in[8];
    const float* w1      = (const float*)d_in[9];
    const float* b1      = (const float*)d_in[10];
    const float* w2      = (const float*)d_in[11];
    const float* b2      = (const float*)d_in[12];
    const float* head_w  = (const float*)d_in[13];
    const float* head_b  = (const float*)d_in[14];

    char* wp = (char*)d_ws;
    auto carve = [&](size_t bytes) {
        char* r = wp;
        wp += (bytes + 255) & ~(size_t)255;
        return r;
    };
    auto fits = [&](size_t bytes) {
        return (size_t)(wp - (char*)d_ws) + bytes + 256 <= ws_size;
    };
    float* h  = (float*)carve((size_t)MP * DD * 4);
    bf16* hn  = (bf16*)carve((size_t)MP * DD * 2);
    bf16* u   = (bf16*)carve((size_t)MP * FF * 2);
    bf16* qs  = (bf16*)carve((size_t)BQ * HH * TP * 64 * 2);
    bf16* ks  = (bf16*)carve((size_t)BQ * HH * TP * 64 * 2);
    bf16* vs  = (bf16*)carve((size_t)BQ * HH * TP * 64 * 2);
    bf16* p   = (bf16*)carve((size_t)6272 * DD * 2);
    bf16* pwb = (bf16*)carve((size_t)DD * DD * 2);
    bf16* qwb = (bf16*)carve((size_t)LL * 192 * 64 * 2);

    // split-K partials (NSPLIT x MP x DD fp32), if ws allows
    float* part = nullptr;
    if (fits((size_t)NSPLIT * MP * DD * 4))
        part = (float*)carve((size_t)NSPLIT * MP * DD * 4);
    const bool use_part = (part != nullptr);

    // precast-all weights, if ws allows
    const size_t wfull = (size_t)LL * FF * DD * 2;
    const bool precast = fits(2 * (wfull + 256));
    bf16* w1b = (bf16*)carve(precast ? wfull : (size_t)FF * DD * 2);
    bf16* w2b = (bf16*)carve(precast ? wfull : (size_t)DD * FF * 2);

    cast_bf16<<<512, 256, 0, stream>>>(patch_w, pwb, (DD * DD) / 4);
    cast_bf16<<<144, 256, 0, stream>>>(qkv_w, qwb, (LL * 192 * 64) / 4);
    if (precast) {
        cast_bf16<<<4096, 256, 0, stream>>>(w1, w1b, (LL * FF * DD) / 4);
        cast_bf16<<<4096, 256, 0, stream>>>(w2, w2b, (LL * FF * DD) / 4);
    }
    patch_extract<<<18816, 256, 0, stream>>>(x, p);
    cls_init<<<96, 256, 0, stream>>>(cls_tok, pos_enc, h);
    gemm_bt<0, 1><<<294, 256, 0, stream>>>(p, pwb, patch_b, 768, 768, h, nullptr,
                                           pos_enc, 6, 49);

    for (int i = 0; i < LL; i++) {
        const bf16* w1i = precast ? (w1b + (size_t)i * FF * DD) : w1b;
        const bf16* w2i = precast ? (w2b + (size_t)i * FF * DD) : w2b;

        // ln1 (fused with previous layer's MLP2 partial reduction + b2 + residual)
        if (use_part && i > 0)
            ln_acc_kernel<NSPLIT><<<MP / 4, 256, 0, stream>>>(h, part, b2 + (i - 1) * DD,
                                                              ln_g + i * DD, ln_b + i * DD, hn);
        else
            ln_kernel<<<MP / 4, 256, 0, stream>>>(h, ln_g + i * DD, ln_b + i * DD, hn);

        qkv_kernel<<<MQ / 128, 256, 0, stream>>>(hn, qwb + i * 192 * 64, qkv_b + i * 192,
                                                 qs, ks, vs);
        attn_kernel<<<BQ * HH, 256, 0, stream>>>(qs, ks, vs, h);
        ln_kernel<<<MP / 4, 256, 0, stream>>>(h, ln_g + i * DD, ln_b + i * DD, hn);
        if (!precast)
            cast_bf16<<<2048, 256, 0, stream>>>(w1 + (size_t)i * FF * DD, w1b, (FF * DD) / 4);
        // MLP1: 256^2 tile, M=6400(25) x N=3072(12) -> 300 blocks
        gemm256<1, 1><<<300, 512, 0, stream>>>(hn, w1i, b1 + i * FF, 768, 3072,
                                               nullptr, u, 12, 25);
        if (!precast)
            cast_bf16<<<2048, 256, 0, stream>>>(w2 + (size_t)i * FF * DD, w2b, (FF * DD) / 4);
        if (use_part)
            // MLP2: 256^2 tile, split-K=4, M=6400(25) x N=768(3) -> 300 blocks
            gemm256<3, NSPLIT><<<75 * NSPLIT, 512, 0, stream>>>(u, w2i, nullptr, 3072, 768,
                                                                part, nullptr, 3, 25);
        else
            gemm_bt<2, 1><<<300, 256, 0, stream>>>(u, w2i, b2 + i * DD, 3072, 768,
                                                   h, nullptr, nullptr, 6, 50);
    }
    if (use_part)  // final reduction of layer 11's MLP2 into h (hn output unused)
        ln_acc_kernel<NSPLIT><<<MP / 4, 256, 0, stream>>>(h, part, b2 + 11 * DD,
                                                          ln_g, ln_b, hn);
    head_kernel<<<dim3(4, BQ), 256, 0, stream>>>(h, head_w, head_b, (float*)d_out);
}

// Round 7
// 3024.525 us; speedup vs baseline: 1.1916x; 1.1916x over previous
//
#include <hip/hip_runtime.h>
#include <hip/hip_bf16.h>
#include <math.h>

typedef __bf16 bf16;
typedef bf16 bf16x8 __attribute__((ext_vector_type(8)));
typedef bf16 bf16x4 __attribute__((ext_vector_type(4)));
typedef float f32x4 __attribute__((ext_vector_type(4)));

#define BQ 32
#define TT 197
#define DD 768
#define HH 12
#define FF 3072
#define LL 12
#define TP 224
#define MR 6304   // B*T
#define MP 6400   // padded to 50*128 (= 25*256)
#define MQ 75648  // B*T*H rows for qkv gemm (591*128)
#define KST 72    // K LDS row stride (elements)
#define PST 232   // P / Vt LDS row stride (elements)
#define NSPLIT 2  // MLP2 split-K factor

typedef __attribute__((address_space(1))) const void gv_t;
typedef __attribute__((address_space(3))) void lv_t;

__device__ __forceinline__ void gld16(const void* g, void* l) {
    __builtin_amdgcn_global_load_lds((gv_t*)g, (lv_t*)l, 16, 0, 0);
}

__device__ __forceinline__ f32x4 mfma16(bf16x8 a, bf16x8 b, f32x4 c) {
    return __builtin_amdgcn_mfma_f32_16x16x32_bf16(a, b, c, 0, 0, 0);
}

// tanh-approx GELU via hw v_exp_f32; overflow-safe (e=inf -> th=1)
__device__ __forceinline__ float fast_gelu(float v) {
    float t = 0.79788456080286535588f * v * (1.0f + 0.044715f * v * v);
    float e = __expf(2.0f * t);
    float th = 1.0f - 2.0f / (e + 1.0f);
    return 0.5f * v * (1.0f + th);
}

// bijective XCD swizzle (m204): consecutive wgid stay on one XCD
__device__ __forceinline__ int xcd_swz(int bid, int nwg) {
    int q = nwg >> 3, r = nwg & 7;
    int xcd = bid & 7, pos = bid >> 3;
    int base = (xcd < r) ? xcd * (q + 1) : r * (q + 1) + (xcd - r) * q;
    return base + pos;
}

// ---------------------------------------------------------------------------
// Deep-pipelined GEMM: 256x128 tile, BK=64, 8 waves (2M x 4N), 512 threads,
// THREE LDS buffers (144 KiB ring). Counted vmcnt (T4):
//   iter t: s_waitcnt vmcnt(6)   // tile t complete; tile t+1 stays IN FLIGHT
//           raw s_barrier        // NOT __syncthreads (which drains vmcnt(0))
//           stage(t+2 -> buf[(t+2)%3])   // 6 gld16/thread, lands 2 tiles later
//           compute tile t (32 MFMA/wave, setprio-wrapped)
// Prefetch distance = 2 tile-computes (~2500 cyc) >> HBM latency (~900).
// XOR swizzle cb^(row&7) on global SOURCE (LDS dest linear, rule #21),
// mirrored on ds_read side -> 0 bank conflicts (PMC-verified r4/r5).
// EPI 1: +bias, fast GELU -> bf16 out (stride N)
// EPI 3: raw partial write -> outF[ks*MP*DD + row*DD + col] (no bias)
// ---------------------------------------------------------------------------
template <int EPI, int SPLITK>
__global__ __launch_bounds__(512, 1)
void gemm_pipe(const bf16* __restrict__ A, const bf16* __restrict__ W,
               const float* __restrict__ bias, int K, int N,
               float* __restrict__ outF, bf16* __restrict__ outB,
               int gx, int gy) {
    __shared__ __align__(16) bf16 As[3][256 * 64];
    __shared__ __align__(16) bf16 Bs[3][128 * 64];
    const int tid = threadIdx.x;
    const int lane = tid & 63, wave = tid >> 6;
    const int wm = wave >> 2, wn = wave & 3;   // 2M x 4N

    const int wgid = xcd_swz(blockIdx.x, gridDim.x);
    const int ks   = (SPLITK > 1) ? wgid / (gx * gy) : 0;
    const int rem  = (SPLITK > 1) ? wgid % (gx * gy) : wgid;
    const int bx = rem % gx, by = rem / gx;
    const int m0 = by * 256, n0 = bx * 128;

    const int kb = K / SPLITK;
    const int k0 = ks * kb;
    const int nt = kb / 64;

    f32x4 acc[8][2] = {};
    const bf16* Ab = A + (size_t)m0 * K;
    const bf16* Wb = W + (size_t)n0 * K;

    // stage one K-tile (A: 4 units, B: 2 units; 6 gld16/thread)
    auto stage = [&](int buf, int kt) {
#pragma unroll
        for (int u = 0; u < 4; u++) {
            int idx = u * 512 + tid;
            int row = idx >> 3, cb = idx & 7;
            int gcb = cb ^ (row & 7);
            gld16(Ab + (size_t)row * K + kt + gcb * 8, &As[buf][idx * 8]);
        }
#pragma unroll
        for (int u = 0; u < 2; u++) {
            int idx = u * 512 + tid;
            int row = idx >> 3, cb = idx & 7;
            int gcb = cb ^ (row & 7);
            gld16(Wb + (size_t)row * K + kt + gcb * 8, &Bs[buf][idx * 8]);
        }
    };

    stage(0, k0);
    if (nt > 1) stage(1, k0 + 64);

    for (int t = 0; t < nt; ++t) {
        if (t + 1 < nt) {
            asm volatile("s_waitcnt vmcnt(6)" ::: "memory");
        } else {
            asm volatile("s_waitcnt vmcnt(0)" ::: "memory");
        }
        __builtin_amdgcn_s_barrier();          // raw: no implicit vmcnt(0)
        if (t + 2 < nt) stage((t + 2) % 3, k0 + (t + 2) * 64);

        const bf16* Asb = &As[t % 3][0];
        const bf16* Bsb = &Bs[t % 3][0];
        const int ca = lane >> 4;
        bf16x8 bfr[2][2];
#pragma unroll
        for (int nf = 0; nf < 2; nf++) {
            int rowb = wn * 32 + nf * 16 + (lane & 15);
            int mb = rowb & 7;
            bfr[nf][0] = *(const bf16x8*)(Bsb + rowb * 64 + ((ca    ) ^ mb) * 8);
            bfr[nf][1] = *(const bf16x8*)(Bsb + rowb * 64 + ((ca + 4) ^ mb) * 8);
        }
#pragma unroll
        for (int p = 0; p < 4; p++) {
            bf16x8 af[2][2];
#pragma unroll
            for (int mi = 0; mi < 2; mi++) {
                int rowa = wm * 128 + (p * 2 + mi) * 16 + (lane & 15);
                int ma = rowa & 7;
                af[mi][0] = *(const bf16x8*)(Asb + rowa * 64 + ((ca    ) ^ ma) * 8);
                af[mi][1] = *(const bf16x8*)(Asb + rowa * 64 + ((ca + 4) ^ ma) * 8);
            }
            __builtin_amdgcn_s_setprio(1);
#pragma unroll
            for (int mi = 0; mi < 2; mi++)
#pragma unroll
                for (int nf = 0; nf < 2; nf++)
#pragma unroll
                    for (int kh = 0; kh < 2; kh++)
                        acc[p * 2 + mi][nf] = mfma16(af[mi][kh], bfr[nf][kh],
                                                     acc[p * 2 + mi][nf]);
            __builtin_amdgcn_s_setprio(0);
        }
    }

    const int r0 = m0 + wm * 128, c0 = n0 + wn * 32;
#pragma unroll
    for (int mf = 0; mf < 8; mf++) {
#pragma unroll
        for (int j = 0; j < 4; j++) {
            int row = r0 + mf * 16 + ((lane >> 4) * 4) + j;
#pragma unroll
            for (int nf = 0; nf < 2; nf++) {
                int col = c0 + nf * 16 + (lane & 15);
                float v = acc[mf][nf][j];
                if (EPI == 1) {
                    v += bias[col];
                    outB[(size_t)row * N + col] = (bf16)fast_gelu(v);
                } else {
                    outF[(size_t)(ks * MP + row) * DD + col] = v;
                }
            }
        }
    }
}

// ---------------------------------------------------------------------------
// 128x128 tile GEMM (r5-proven), kept for patch embed.
// EPI 0: +bias, patch-embed -> h rows (b*197+1+n) += pos_enc (fp32 write)
// ---------------------------------------------------------------------------
template <int EPI, int SPLITK>
__global__ __launch_bounds__(256, 4)
void gemm_bt(const bf16* __restrict__ A, const bf16* __restrict__ W,
             const float* __restrict__ bias, int K, int N,
             float* __restrict__ outF, bf16* __restrict__ outB,
             const float* __restrict__ pos, int gx, int gy) {
    __shared__ bf16 As[128 * 64];
    __shared__ bf16 Bs[128 * 64];
    const int tid = threadIdx.x;
    const int lane = tid & 63, wave = tid >> 6;
    const int wm = wave >> 1, wn = wave & 1;

    const int wgid = xcd_swz(blockIdx.x, gridDim.x);
    const int ks   = (SPLITK > 1) ? wgid / (gx * gy) : 0;
    const int rem  = (SPLITK > 1) ? wgid % (gx * gy) : wgid;
    const int bx = rem % gx, by = rem / gx;
    const int m0 = by * 128, n0 = bx * 128;

    const int kb = K / SPLITK;
    const int k0 = ks * kb, k1 = k0 + kb;

    f32x4 acc[4][4] = {};
    const bf16* Ab = A + (size_t)m0 * K;
    const bf16* Wb = W + (size_t)n0 * K;

    for (int kt = k0; kt < k1; kt += 64) {
#pragma unroll
        for (int i = 0; i < 4; i++) {
            int idx = i * 256 + tid;
            int row = idx >> 3, cb = idx & 7;
            int gcb = cb ^ (row & 7);
            gld16(Ab + (size_t)row * K + kt + gcb * 8, As + idx * 8);
            gld16(Wb + (size_t)row * K + kt + gcb * 8, Bs + idx * 8);
        }
        __syncthreads();
        bf16x8 af[4][2], bfr[4][2];
        const int ca = lane >> 4;
#pragma unroll
        for (int f = 0; f < 4; f++) {
            int rowa = wm * 64 + f * 16 + (lane & 15);
            int ma = rowa & 7;
            af[f][0] = *(const bf16x8*)(As + rowa * 64 + ((ca    ) ^ ma) * 8);
            af[f][1] = *(const bf16x8*)(As + rowa * 64 + ((ca + 4) ^ ma) * 8);
            int rowb = wn * 64 + f * 16 + (lane & 15);
            int mb = rowb & 7;
            bfr[f][0] = *(const bf16x8*)(Bs + rowb * 64 + ((ca    ) ^ mb) * 8);
            bfr[f][1] = *(const bf16x8*)(Bs + rowb * 64 + ((ca + 4) ^ mb) * 8);
        }
#pragma unroll
        for (int kh = 0; kh < 2; kh++)
#pragma unroll
            for (int mf = 0; mf < 4; mf++)
#pragma unroll
                for (int nf = 0; nf < 4; nf++)
                    acc[mf][nf] = mfma16(af[mf][kh], bfr[nf][kh], acc[mf][nf]);
        __syncthreads();
    }

    const int r0 = m0 + wm * 64, c0 = n0 + wn * 64;
#pragma unroll
    for (int mf = 0; mf < 4; mf++) {
#pragma unroll
        for (int j = 0; j < 4; j++) {
            int row = r0 + mf * 16 + ((lane >> 4) * 4) + j;
            int pb = 0, pn = 0;
            if (EPI == 0) { pb = row / 196; pn = row - pb * 196; }
#pragma unroll
            for (int nf = 0; nf < 4; nf++) {
                int col = c0 + nf * 16 + (lane & 15);
                float v = acc[mf][nf][j];
                if (EPI == 0) {
                    v += bias[col];
                    float pv = pos[(size_t)(1 + pn) * DD + col];
                    outF[(size_t)(pb * TT + 1 + pn) * DD + col] = v + pv;
                } else if (EPI == 1) {
                    v += bias[col];
                    outB[(size_t)row * N + col] = (bf16)fast_gelu(v);
                } else if (EPI == 2) {
                    v += bias[col];
                    if (row < MR) outF[(size_t)row * DD + col] += v;
                } else {
                    outF[(size_t)(ks * MP + row) * DD + col] = v;
                }
            }
        }
    }
}

// ---------------------------------------------------------------------------
// QKV: A = hn viewed as (B*T*H, 64) contiguous (since D = H*64).
// C (MQ,192) = A @ qkv_w(192,64)^T + qkv_b, scattered to Q/K/V (B*H, 224, 64)
// ---------------------------------------------------------------------------
__global__ __launch_bounds__(256, 2)
void qkv_kernel(const bf16* __restrict__ hn, const bf16* __restrict__ qw,
                const float* __restrict__ qb, bf16* __restrict__ Q,
                bf16* __restrict__ Kb, bf16* __restrict__ Vb) {
    __shared__ bf16 Asm[128 * 64];
    __shared__ bf16 Wsm[192 * 64];
    const int tid = threadIdx.x, lane = tid & 63, wave = tid >> 6;
    const bf16* Ab = hn + (size_t)blockIdx.x * (128 * 64);
#pragma unroll
    for (int i = 0; i < 4; i++) {
        int idx = i * 256 + tid;
        int row = idx >> 3, cb = idx & 7;
        int gcb = cb ^ (row & 7);
        gld16(Ab + (size_t)row * 64 + gcb * 8, Asm + idx * 8);
    }
#pragma unroll
    for (int i = 0; i < 6; i++) {
        int idx = i * 256 + tid;
        int row = idx >> 3, cb = idx & 7;
        int gcb = cb ^ (row & 7);
        gld16(qw + (size_t)row * 64 + gcb * 8, Wsm + idx * 8);
    }
    __syncthreads();

    const int ca = lane >> 4;
    bf16x8 af[2][2];
#pragma unroll
    for (int mf = 0; mf < 2; mf++) {
        int row = wave * 32 + mf * 16 + (lane & 15);
        int m7 = row & 7;
        af[mf][0] = *(const bf16x8*)(Asm + row * 64 + ((ca    ) ^ m7) * 8);
        af[mf][1] = *(const bf16x8*)(Asm + row * 64 + ((ca + 4) ^ m7) * 8);
    }
    f32x4 acc[2][12] = {};
#pragma unroll
    for (int nf = 0; nf < 12; nf++) {
        int row = nf * 16 + (lane & 15);
        int m7 = row & 7;
        bf16x8 b0 = *(const bf16x8*)(Wsm + row * 64 + ((ca    ) ^ m7) * 8);
        bf16x8 b1 = *(const bf16x8*)(Wsm + row * 64 + ((ca + 4) ^ m7) * 8);
#pragma unroll
        for (int mf = 0; mf < 2; mf++) {
            acc[mf][nf] = mfma16(af[mf][0], b0, acc[mf][nf]);
            acc[mf][nf] = mfma16(af[mf][1], b1, acc[mf][nf]);
        }
    }
    const int r0 = blockIdx.x * 128 + wave * 32;
#pragma unroll
    for (int mf = 0; mf < 2; mf++)
#pragma unroll
        for (int j = 0; j < 4; j++) {
            int r = r0 + mf * 16 + (lane >> 4) * 4 + j;
            int bt = r / 12, hh = r - bt * 12;
            int b = bt / 197, t = bt - b * 197;
            size_t dbase = ((size_t)(b * HH + hh) * TP + t) * 64;
#pragma unroll
            for (int nf = 0; nf < 12; nf++) {
                int col = nf * 16 + (lane & 15);
                float v = acc[mf][nf][j] + qb[col];
                int sel = nf >> 2, e = col & 63;
                bf16* dst = (sel == 0) ? Q : (sel == 1 ? Kb : Vb);
                dst[dbase + e] = (bf16)v;
            }
        }
}

// ---------------------------------------------------------------------------
// Fused attention per (b,h): scores = QK^T*0.125 (masked >=197), softmax,
// O = P@V, h += O (residual).
// ---------------------------------------------------------------------------
__global__ __launch_bounds__(256, 1)
void attn_kernel(const bf16* __restrict__ Q, const bf16* __restrict__ Kg,
                 const bf16* __restrict__ Vg, float* __restrict__ h) {
    __shared__ bf16 Ks[TP * KST];
    __shared__ bf16 Vt[64 * PST];
    __shared__ bf16 Pw[4 * 16 * PST];
    const int tid = threadIdx.x, lane = tid & 63, wave = tid >> 6;
    const int bh = blockIdx.x;
    const int b = bh / HH, hh = bh - b * HH;
    const bf16* Kp = Kg + (size_t)bh * TP * 64;
    const bf16* Vp = Vg + (size_t)bh * TP * 64;
    const bf16* Qp = Q + (size_t)bh * TP * 64;

#pragma unroll
    for (int i = 0; i < 7; i++) {
        int idx = i * 256 + tid;
        int row = idx >> 3, cb = idx & 7;
        bf16x8 kv = *(const bf16x8*)(Kp + idx * 8);
        *(bf16x8*)(Ks + row * KST + cb * 8) = kv;
        bf16x8 vv = *(const bf16x8*)(Vp + idx * 8);
#pragma unroll
        for (int j = 0; j < 8; j++) Vt[(cb * 8 + j) * PST + row] = vv[j];
    }
    __syncthreads();

    bf16* Pm = Pw + wave * 16 * PST;
    for (int ch = wave; ch < 13; ch += 4) {
        const int q0 = ch * 16;
        const bf16* qp = Qp + (q0 + (lane & 15)) * 64 + (lane >> 4) * 8;
        bf16x8 aq0 = *(const bf16x8*)qp;
        bf16x8 aq1 = *(const bf16x8*)(qp + 32);
        f32x4 s[14] = {};
#pragma unroll
        for (int nf = 0; nf < 14; nf++) {
            int rb = (nf * 16 + (lane & 15)) * KST + (lane >> 4) * 8;
            bf16x8 b0 = *(const bf16x8*)(Ks + rb);
            bf16x8 b1 = *(const bf16x8*)(Ks + rb + 32);
            s[nf] = mfma16(aq0, b0, s[nf]);
            s[nf] = mfma16(aq1, b1, s[nf]);
        }
        const int colbase = lane & 15;
#pragma unroll
        for (int j = 0; j < 4; j++) {
            float pv[14];
            float m = -1e30f;
#pragma unroll
            for (int nf = 0; nf < 14; nf++) {
                int col = nf * 16 + colbase;
                float v = s[nf][j] * 0.125f;
                v = (col < TT) ? v : -1e30f;
                pv[nf] = v;
                m = fmaxf(m, v);
            }
#pragma unroll
            for (int dd = 1; dd < 16; dd <<= 1) m = fmaxf(m, __shfl_xor(m, dd));
            float sum = 0.0f;
#pragma unroll
            for (int nf = 0; nf < 14; nf++) { float e = __expf(pv[nf] - m); pv[nf] = e; sum += e; }
#pragma unroll
            for (int dd = 1; dd < 16; dd <<= 1) sum += __shfl_xor(sum, dd);
            float inv = 1.0f / sum;
            int pr = (lane >> 4) * 4 + j;
#pragma unroll
            for (int nf = 0; nf < 14; nf++)
                Pm[pr * PST + nf * 16 + colbase] = (bf16)(pv[nf] * inv);
        }
        asm volatile("s_waitcnt lgkmcnt(0)" ::: "memory");
        f32x4 o[4] = {};
#pragma unroll
        for (int ks = 0; ks < 7; ks++) {
            bf16x8 pa = *(const bf16x8*)(Pm + (lane & 15) * PST + ks * 32 + (lane >> 4) * 8);
#pragma unroll
            for (int nf = 0; nf < 4; nf++) {
                bf16x8 bv = *(const bf16x8*)(Vt + (nf * 16 + (lane & 15)) * PST + ks * 32 + (lane >> 4) * 8);
                o[nf] = mfma16(pa, bv, o[nf]);
            }
        }
#pragma unroll
        for (int nf = 0; nf < 4; nf++)
#pragma unroll
            for (int j = 0; j < 4; j++) {
                int qr = q0 + (lane >> 4) * 4 + j;
                if (qr < TT) {
                    int d = nf * 16 + (lane & 15);
                    h[(size_t)(b * TT + qr) * DD + hh * 64 + d] += o[nf][j];
                }
            }
    }
}

// ---------------------------------------------------------------------------
// LayerNorm, one row per wave (4 rows/block), fp32 in -> bf16 out
// ---------------------------------------------------------------------------
__device__ __forceinline__ void ln_core(float4 a[3], const float* g, const float* bt,
                                        bf16* hn, int row, int lane) {
    float sum = 0.0f;
#pragma unroll
    for (int i = 0; i < 3; i++) sum += a[i].x + a[i].y + a[i].z + a[i].w;
#pragma unroll
    for (int dd = 1; dd < 64; dd <<= 1) sum += __shfl_xor(sum, dd);
    const float mu = sum * (1.0f / 768.0f);
    float sq = 0.0f;
#pragma unroll
    for (int i = 0; i < 3; i++) {
        float dx = a[i].x - mu, dy = a[i].y - mu, dz = a[i].z - mu, dw = a[i].w - mu;
        sq += dx * dx + dy * dy + dz * dz + dw * dw;
    }
#pragma unroll
    for (int dd = 1; dd < 64; dd <<= 1) sq += __shfl_xor(sq, dd);
    const float is = rsqrtf(sq * (1.0f / 768.0f) + 1e-5f);
#pragma unroll
    for (int i = 0; i < 3; i++) {
        int c4 = lane + i * 64;
        float4 gg = ((const float4*)g)[c4];
        float4 bb = ((const float4*)bt)[c4];
        bf16x4 o;
        o[0] = (bf16)((a[i].x - mu) * is * gg.x + bb.x);
        o[1] = (bf16)((a[i].y - mu) * is * gg.y + bb.y);
        o[2] = (bf16)((a[i].z - mu) * is * gg.z + bb.z);
        o[3] = (bf16)((a[i].w - mu) * is * gg.w + bb.w);
        ((bf16x4*)(hn + (size_t)row * DD))[c4] = o;
    }
}

__global__ void ln_kernel(const float* __restrict__ h, const float* __restrict__ g,
                          const float* __restrict__ bt, bf16* __restrict__ hn) {
    const int lane = threadIdx.x & 63, wave = threadIdx.x >> 6;
    const int row = blockIdx.x * 4 + wave;
    const float* x = h + (size_t)row * DD;
    float4 a[3];
#pragma unroll
    for (int i = 0; i < 3; i++) a[i] = ((const float4*)x)[lane + i * 64];
    ln_core(a, g, bt, hn, row, lane);
}

// h += sum(NS partials) + b2; write h; hn = LN(h)
template <int NS>
__global__ void ln_acc_kernel(float* __restrict__ h, const float* __restrict__ part,
                              const float* __restrict__ b2,
                              const float* __restrict__ g, const float* __restrict__ bt,
                              bf16* __restrict__ hn) {
    const int lane = threadIdx.x & 63, wave = threadIdx.x >> 6;
    const int row = blockIdx.x * 4 + wave;
    float* x = h + (size_t)row * DD;
    float4 a[3];
#pragma unroll
    for (int i = 0; i < 3; i++) a[i] = ((const float4*)x)[lane + i * 64];
#pragma unroll
    for (int s = 0; s < NS; s++) {
        const float4* ps = (const float4*)(part + ((size_t)s * MP + row) * DD);
#pragma unroll
        for (int i = 0; i < 3; i++) {
            float4 p = ps[lane + i * 64];
            a[i].x += p.x; a[i].y += p.y; a[i].z += p.z; a[i].w += p.w;
        }
    }
#pragma unroll
    for (int i = 0; i < 3; i++) {
        float4 bb = ((const float4*)b2)[lane + i * 64];
        a[i].x += bb.x; a[i].y += bb.y; a[i].z += bb.z; a[i].w += bb.w;
        ((float4*)x)[lane + i * 64] = a[i];
    }
    ln_core(a, g, bt, hn, row, lane);
}

// ---------------------------------------------------------------------------
__global__ void patch_extract(const float* __restrict__ x, bf16* __restrict__ p) {
    int idx = blockIdx.x * 256 + threadIdx.x;
    if (idx >= 6272 * 768) return;
    int k = idx % 768, row = idx / 768;
    int c = k % 3, pc = (k / 3) % 16, pr = k / 48;
    int b = row / 196, n = row - b * 196;
    int hp = n / 14, wp = n - hp * 14;
    p[idx] = (bf16)x[((size_t)(b * 3 + c) * 224 + hp * 16 + pr) * 224 + wp * 16 + pc];
}

__global__ void cast_bf16(const float* __restrict__ in, bf16* __restrict__ out, int n4) {
    int i = blockIdx.x * 256 + threadIdx.x;
    int stride = gridDim.x * 256;
    for (; i < n4; i += stride) {
        float4 v = ((const float4*)in)[i];
        bf16x4 o;
        o[0] = (bf16)v.x; o[1] = (bf16)v.y; o[2] = (bf16)v.z; o[3] = (bf16)v.w;
        ((bf16x4*)out)[i] = o;
    }
}

__global__ void cls_init(const float* __restrict__ cls, const float* __restrict__ pos,
                         float* __restrict__ h) {
    int i = blockIdx.x * 256 + threadIdx.x;
    if (i >= BQ * DD) return;
    int b = i / DD, c = i - b * DD;
    h[(size_t)(b * TT) * DD + c] = cls[c] + pos[c];
}

__global__ void head_kernel(const float* __restrict__ h, const float* __restrict__ hw,
                            const float* __restrict__ hb, float* __restrict__ out) {
    __shared__ float xr[DD];
    const int b = blockIdx.y;
    const int n = blockIdx.x * 256 + threadIdx.x;
    for (int i = threadIdx.x; i < DD; i += 256) xr[i] = h[(size_t)(b * TT) * DD + i];
    __syncthreads();
    if (n < 1000) {
        float s = hb[n];
        const float4* w = (const float4*)(hw + (size_t)n * DD);
        float acc = 0.0f;
#pragma unroll 4
        for (int k = 0; k < DD / 4; k++) {
            float4 wv = w[k];
            float4 xv = ((const float4*)xr)[k];
            acc += wv.x * xv.x + wv.y * xv.y + wv.z * xv.z + wv.w * xv.w;
        }
        out[b * 1000 + n] = s + acc;
    }
}

// ---------------------------------------------------------------------------
extern "C" void kernel_launch(void* const* d_in, const int* in_sizes, int n_in,
                              void* d_out, int out_size, void* d_ws, size_t ws_size,
                              hipStream_t stream) {
    const float* x       = (const float*)d_in[0];
    const float* patch_w = (const float*)d_in[1];
    const float* patch_b = (const float*)d_in[2];
    const float* pos_enc = (const float*)d_in[3];
    const float* cls_tok = (const float*)d_in[4];
    const float* qkv_w   = (const float*)d_in[5];
    const float* qkv_b   = (const float*)d_in[6];
    const float* ln_g    = (const float*)d_in[7];
    const float* ln_b    = (const float*)d_in[8];
    const float* w1      = (const float*)d_in[9];
    const float* b1      = (const float*)d_in[10];
    const float* w2      = (const float*)d_in[11];
    const float* b2      = (const float*)d_in[12];
    const float* head_w  = (const float*)d_in[13];
    const float* head_b  = (const float*)d_in[14];

    char* wp = (char*)d_ws;
    auto carve = [&](size_t bytes) {
        char* r = wp;
        wp += (bytes + 255) & ~(size_t)255;
        return r;
    };
    auto fits = [&](size_t bytes) {
        return (size_t)(wp - (char*)d_ws) + bytes + 256 <= ws_size;
    };
    float* h  = (float*)carve((size_t)MP * DD * 4);
    bf16* hn  = (bf16*)carve((size_t)MP * DD * 2);
    bf16* u   = (bf16*)carve((size_t)MP * FF * 2);
    bf16* qs  = (bf16*)carve((size_t)BQ * HH * TP * 64 * 2);
    bf16* ks  = (bf16*)carve((size_t)BQ * HH * TP * 64 * 2);
    bf16* vs  = (bf16*)carve((size_t)BQ * HH * TP * 64 * 2);
    bf16* p   = (bf16*)carve((size_t)6272 * DD * 2);
    bf16* pwb = (bf16*)carve((size_t)DD * DD * 2);
    bf16* qwb = (bf16*)carve((size_t)LL * 192 * 64 * 2);

    // split-K partials (NSPLIT x MP x DD fp32), if ws allows
    float* part = nullptr;
    if (fits((size_t)NSPLIT * MP * DD * 4))
        part = (float*)carve((size_t)NSPLIT * MP * DD * 4);
    const bool use_part = (part != nullptr);

    // precast-all weights, if ws allows
    const size_t wfull = (size_t)LL * FF * DD * 2;
    const bool precast = fits(2 * (wfull + 256));
    bf16* w1b = (bf16*)carve(precast ? wfull : (size_t)FF * DD * 2);
    bf16* w2b = (bf16*)carve(precast ? wfull : (size_t)DD * FF * 2);

    cast_bf16<<<512, 256, 0, stream>>>(patch_w, pwb, (DD * DD) / 4);
    cast_bf16<<<144, 256, 0, stream>>>(qkv_w, qwb, (LL * 192 * 64) / 4);
    if (precast) {
        cast_bf16<<<4096, 256, 0, stream>>>(w1, w1b, (LL * FF * DD) / 4);
        cast_bf16<<<4096, 256, 0, stream>>>(w2, w2b, (LL * FF * DD) / 4);
    }
    patch_extract<<<18816, 256, 0, stream>>>(x, p);
    cls_init<<<96, 256, 0, stream>>>(cls_tok, pos_enc, h);
    gemm_bt<0, 1><<<294, 256, 0, stream>>>(p, pwb, patch_b, 768, 768, h, nullptr,
                                           pos_enc, 6, 49);

    for (int i = 0; i < LL; i++) {
        const bf16* w1i = precast ? (w1b + (size_t)i * FF * DD) : w1b;
        const bf16* w2i = precast ? (w2b + (size_t)i * FF * DD) : w2b;

        // ln1 (fused with previous layer's MLP2 partial reduction + b2 + residual)
        if (use_part && i > 0)
            ln_acc_kernel<NSPLIT><<<MP / 4, 256, 0, stream>>>(h, part, b2 + (i - 1) * DD,
                                                              ln_g + i * DD, ln_b + i * DD, hn);
        else
            ln_kernel<<<MP / 4, 256, 0, stream>>>(h, ln_g + i * DD, ln_b + i * DD, hn);

        qkv_kernel<<<MQ / 128, 256, 0, stream>>>(hn, qwb + i * 192 * 64, qkv_b + i * 192,
                                                 qs, ks, vs);
        attn_kernel<<<BQ * HH, 256, 0, stream>>>(qs, ks, vs, h);
        ln_kernel<<<MP / 4, 256, 0, stream>>>(h, ln_g + i * DD, ln_b + i * DD, hn);
        if (!precast)
            cast_bf16<<<2048, 256, 0, stream>>>(w1 + (size_t)i * FF * DD, w1b, (FF * DD) / 4);
        // MLP1: 256x128 tile, M=6400(25) x N=3072(24) -> 600 blocks
        gemm_pipe<1, 1><<<600, 512, 0, stream>>>(hn, w1i, b1 + i * FF, 768, 3072,
                                                 nullptr, u, 24, 25);
        if (!precast)
            cast_bf16<<<2048, 256, 0, stream>>>(w2 + (size_t)i * FF * DD, w2b, (FF * DD) / 4);
        if (use_part)
            // MLP2: 256x128 tile, split-K=2, M=6400(25) x N=768(6) -> 300 blocks
            gemm_pipe<3, NSPLIT><<<150 * NSPLIT, 512, 0, stream>>>(u, w2i, nullptr, 3072, 768,
                                                                   part, nullptr, 6, 25);
        else
            gemm_bt<2, 1><<<300, 256, 0, stream>>>(u, w2i, b2 + i * DD, 3072, 768,
                                                   h, nullptr, nullptr, 6, 50);
    }
    if (use_part)  // final reduction of layer 11's MLP2 into h (hn output unused)
        ln_acc_kernel<NSPLIT><<<MP / 4, 256, 0, stream>>>(h, part, b2 + 11 * DD,
                                                          ln_g, ln_b, hn);
    head_kernel<<<dim3(4, BQ), 256, 0, stream>>>(h, head_w, head_b, (float*)d_out);
}

// Round 8
// 2260.837 us; speedup vs baseline: 1.5941x; 1.3378x over previous
//
#include <hip/hip_runtime.h>
#include <hip/hip_bf16.h>
#include <math.h>

typedef __bf16 bf16;
typedef bf16 bf16x8 __attribute__((ext_vector_type(8)));
typedef bf16 bf16x4 __attribute__((ext_vector_type(4)));
typedef float f32x4 __attribute__((ext_vector_type(4)));

#define BQ 32
#define TT 197
#define DD 768
#define HH 12
#define FF 3072
#define LL 12
#define TP 224
#define MR 6304   // B*T
#define MP 6400   // padded to 50*128
#define MQ 75648  // B*T*H rows for qkv gemm (591*128)
#define KST 72    // K LDS row stride (elements)
#define PST 232   // P / Vt LDS row stride (elements)
#define NSPLIT 2  // MLP2 split-K factor

typedef __attribute__((address_space(1))) const void gv_t;
typedef __attribute__((address_space(3))) void lv_t;

__device__ __forceinline__ void gld16(const void* g, void* l) {
    __builtin_amdgcn_global_load_lds((gv_t*)g, (lv_t*)l, 16, 0, 0);
}

__device__ __forceinline__ f32x4 mfma16(bf16x8 a, bf16x8 b, f32x4 c) {
    return __builtin_amdgcn_mfma_f32_16x16x32_bf16(a, b, c, 0, 0, 0);
}

// tanh-approx GELU via hw v_exp_f32; overflow-safe (e=inf -> th=1)
__device__ __forceinline__ float fast_gelu(float v) {
    float t = 0.79788456080286535588f * v * (1.0f + 0.044715f * v * v);
    float e = __expf(2.0f * t);
    float th = 1.0f - 2.0f / (e + 1.0f);
    return 0.5f * v * (1.0f + th);
}

// bijective XCD swizzle (m204): consecutive wgid stay on one XCD
__device__ __forceinline__ int xcd_swz(int bid, int nwg) {
    int q = nwg >> 3, r = nwg & 7;
    int xcd = bid & 7, pos = bid >> 3;
    int base = (xcd < r) ? xcd * (q + 1) : r * (q + 1) + (xcd - r) * q;
    return base + pos;
}

// ---------------------------------------------------------------------------
// C = A(M,K) @ W(N,K)^T GEMM, 128x128 tile, BK=64, 4 waves, single-buffered
// (m97 structure; r5-proven: best measured config). Compile-time K/N/geometry
// -> constexpr trip count, full K-loop unroll, no runtime div in addressing.
// XOR swizzle cb^(row&7) on the global SOURCE side of global_load_lds (LDS
// dest linear, rule #21), mirrored on the ds_read side -> 0 bank conflicts
// (PMC-verified r4/r5).
// EPI 0: +bias, patch-embed -> h rows (b*197+1+n) += pos_enc (fp32 write)
// EPI 1: +bias, fast GELU -> bf16 out (stride NN)
// EPI 2: +bias, direct residual += into fp32 out (stride 768)
// EPI 3: raw partial write -> outF[ks*MP*DD + row*DD + col] (no bias)
// ---------------------------------------------------------------------------
template <int EPI, int SPLITK, int KTOT, int NN, int GX, int GY>
__global__ __launch_bounds__(256, 4)
void gemm_bt(const bf16* __restrict__ A, const bf16* __restrict__ W,
             const float* __restrict__ bias,
             float* __restrict__ outF, bf16* __restrict__ outB,
             const float* __restrict__ pos) {
    __shared__ bf16 As[128 * 64];
    __shared__ bf16 Bs[128 * 64];
    const int tid = threadIdx.x;
    const int lane = tid & 63, wave = tid >> 6;
    const int wm = wave >> 1, wn = wave & 1;

    const int wgid = xcd_swz(blockIdx.x, GX * GY * SPLITK);
    const int ks   = (SPLITK > 1) ? wgid / (GX * GY) : 0;
    const int rem  = (SPLITK > 1) ? wgid % (GX * GY) : wgid;
    const int bx = rem % GX, by = rem / GX;
    const int m0 = by * 128, n0 = bx * 128;

    constexpr int kb = KTOT / SPLITK;
    constexpr int nt = kb / 64;
    const int k0 = ks * kb;

    f32x4 acc[4][4] = {};
    const bf16* Ab = A + (size_t)m0 * KTOT;
    const bf16* Wb = W + (size_t)n0 * KTOT;

#pragma unroll
    for (int t = 0; t < nt; ++t) {
        const int kt = k0 + t * 64;
#pragma unroll
        for (int i = 0; i < 4; i++) {
            int idx = i * 256 + tid;
            int row = idx >> 3, cb = idx & 7;
            int gcb = cb ^ (row & 7);   // pre-swizzled source column-block
            gld16(Ab + (size_t)row * KTOT + kt + gcb * 8, As + idx * 8);
            gld16(Wb + (size_t)row * KTOT + kt + gcb * 8, Bs + idx * 8);
        }
        __syncthreads();
        bf16x8 af[4][2], bfr[4][2];
        const int ca = lane >> 4;
#pragma unroll
        for (int f = 0; f < 4; f++) {
            int rowa = wm * 64 + f * 16 + (lane & 15);
            int ma = rowa & 7;
            af[f][0] = *(const bf16x8*)(As + rowa * 64 + ((ca    ) ^ ma) * 8);
            af[f][1] = *(const bf16x8*)(As + rowa * 64 + ((ca + 4) ^ ma) * 8);
            int rowb = wn * 64 + f * 16 + (lane & 15);
            int mb = rowb & 7;
            bfr[f][0] = *(const bf16x8*)(Bs + rowb * 64 + ((ca    ) ^ mb) * 8);
            bfr[f][1] = *(const bf16x8*)(Bs + rowb * 64 + ((ca + 4) ^ mb) * 8);
        }
#pragma unroll
        for (int kh = 0; kh < 2; kh++)
#pragma unroll
            for (int mf = 0; mf < 4; mf++)
#pragma unroll
                for (int nf = 0; nf < 4; nf++)
                    acc[mf][nf] = mfma16(af[mf][kh], bfr[nf][kh], acc[mf][nf]);
        __syncthreads();
    }

    const int r0 = m0 + wm * 64, c0 = n0 + wn * 64;
#pragma unroll
    for (int mf = 0; mf < 4; mf++) {
#pragma unroll
        for (int j = 0; j < 4; j++) {
            int row = r0 + mf * 16 + ((lane >> 4) * 4) + j;
            int pb = 0, pn = 0;
            if (EPI == 0) { pb = row / 196; pn = row - pb * 196; }
#pragma unroll
            for (int nf = 0; nf < 4; nf++) {
                int col = c0 + nf * 16 + (lane & 15);
                float v = acc[mf][nf][j];
                if (EPI == 0) {
                    v += bias[col];
                    float pv = pos[(size_t)(1 + pn) * DD + col];
                    outF[(size_t)(pb * TT + 1 + pn) * DD + col] = v + pv;
                } else if (EPI == 1) {
                    v += bias[col];
                    outB[(size_t)row * NN + col] = (bf16)fast_gelu(v);
                } else if (EPI == 2) {
                    v += bias[col];
                    if (row < MR) outF[(size_t)row * DD + col] += v;
                } else {
                    outF[(size_t)(ks * MP + row) * DD + col] = v;
                }
            }
        }
    }
}

// ---------------------------------------------------------------------------
// QKV: A = hn viewed as (B*T*H, 64) contiguous (since D = H*64).
// C (MQ,192) = A @ qkv_w(192,64)^T + qkv_b, scattered to Q/K/V (B*H, 224, 64)
// ---------------------------------------------------------------------------
__global__ __launch_bounds__(256, 2)
void qkv_kernel(const bf16* __restrict__ hn, const bf16* __restrict__ qw,
                const float* __restrict__ qb, bf16* __restrict__ Q,
                bf16* __restrict__ Kb, bf16* __restrict__ Vb) {
    __shared__ bf16 Asm[128 * 64];
    __shared__ bf16 Wsm[192 * 64];
    const int tid = threadIdx.x, lane = tid & 63, wave = tid >> 6;
    const bf16* Ab = hn + (size_t)blockIdx.x * (128 * 64);
#pragma unroll
    for (int i = 0; i < 4; i++) {
        int idx = i * 256 + tid;
        int row = idx >> 3, cb = idx & 7;
        int gcb = cb ^ (row & 7);
        gld16(Ab + (size_t)row * 64 + gcb * 8, Asm + idx * 8);
    }
#pragma unroll
    for (int i = 0; i < 6; i++) {
        int idx = i * 256 + tid;
        int row = idx >> 3, cb = idx & 7;
        int gcb = cb ^ (row & 7);
        gld16(qw + (size_t)row * 64 + gcb * 8, Wsm + idx * 8);
    }
    __syncthreads();

    const int ca = lane >> 4;
    bf16x8 af[2][2];
#pragma unroll
    for (int mf = 0; mf < 2; mf++) {
        int row = wave * 32 + mf * 16 + (lane & 15);
        int m7 = row & 7;
        af[mf][0] = *(const bf16x8*)(Asm + row * 64 + ((ca    ) ^ m7) * 8);
        af[mf][1] = *(const bf16x8*)(Asm + row * 64 + ((ca + 4) ^ m7) * 8);
    }
    f32x4 acc[2][12] = {};
#pragma unroll
    for (int nf = 0; nf < 12; nf++) {
        int row = nf * 16 + (lane & 15);
        int m7 = row & 7;
        bf16x8 b0 = *(const bf16x8*)(Wsm + row * 64 + ((ca    ) ^ m7) * 8);
        bf16x8 b1 = *(const bf16x8*)(Wsm + row * 64 + ((ca + 4) ^ m7) * 8);
#pragma unroll
        for (int mf = 0; mf < 2; mf++) {
            acc[mf][nf] = mfma16(af[mf][0], b0, acc[mf][nf]);
            acc[mf][nf] = mfma16(af[mf][1], b1, acc[mf][nf]);
        }
    }
    const int r0 = blockIdx.x * 128 + wave * 32;
#pragma unroll
    for (int mf = 0; mf < 2; mf++)
#pragma unroll
        for (int j = 0; j < 4; j++) {
            int r = r0 + mf * 16 + (lane >> 4) * 4 + j;
            int bt = r / 12, hh = r - bt * 12;
            int b = bt / 197, t = bt - b * 197;
            size_t dbase = ((size_t)(b * HH + hh) * TP + t) * 64;
#pragma unroll
            for (int nf = 0; nf < 12; nf++) {
                int col = nf * 16 + (lane & 15);
                float v = acc[mf][nf][j] + qb[col];
                int sel = nf >> 2, e = col & 63;
                bf16* dst = (sel == 0) ? Q : (sel == 1 ? Kb : Vb);
                dst[dbase + e] = (bf16)v;
            }
        }
}

// ---------------------------------------------------------------------------
// Fused attention: block = (b,h,half). half 0 -> q-chunks 0..6, half 1 ->
// 7..12 (chunk = 16 q-rows). 768 blocks = 3 full occupancy rounds (tail fix).
// K in LDS [224][72], V^T [64][232], P per-wave [16][232]. h += P@V residual.
// ---------------------------------------------------------------------------
__global__ __launch_bounds__(256, 1)
void attn_kernel(const bf16* __restrict__ Q, const bf16* __restrict__ Kg,
                 const bf16* __restrict__ Vg, float* __restrict__ h) {
    __shared__ bf16 Ks[TP * KST];
    __shared__ bf16 Vt[64 * PST];
    __shared__ bf16 Pw[4 * 16 * PST];
    const int tid = threadIdx.x, lane = tid & 63, wave = tid >> 6;
    const int bh = blockIdx.x >> 1, sub = blockIdx.x & 1;
    const int b = bh / HH, hh = bh - b * HH;
    const bf16* Kp = Kg + (size_t)bh * TP * 64;
    const bf16* Vp = Vg + (size_t)bh * TP * 64;
    const bf16* Qp = Q + (size_t)bh * TP * 64;

#pragma unroll
    for (int i = 0; i < 7; i++) {
        int idx = i * 256 + tid;
        int row = idx >> 3, cb = idx & 7;
        bf16x8 kv = *(const bf16x8*)(Kp + idx * 8);
        *(bf16x8*)(Ks + row * KST + cb * 8) = kv;
        bf16x8 vv = *(const bf16x8*)(Vp + idx * 8);
#pragma unroll
        for (int j = 0; j < 8; j++) Vt[(cb * 8 + j) * PST + row] = vv[j];
    }
    __syncthreads();

    bf16* Pm = Pw + wave * 16 * PST;
    const int cEnd = sub ? 13 : 7;
    for (int ch = sub * 7 + wave; ch < cEnd; ch += 4) {
        const int q0 = ch * 16;
        const bf16* qp = Qp + (q0 + (lane & 15)) * 64 + (lane >> 4) * 8;
        bf16x8 aq0 = *(const bf16x8*)qp;
        bf16x8 aq1 = *(const bf16x8*)(qp + 32);
        f32x4 s[14] = {};
#pragma unroll
        for (int nf = 0; nf < 14; nf++) {
            int rb = (nf * 16 + (lane & 15)) * KST + (lane >> 4) * 8;
            bf16x8 b0 = *(const bf16x8*)(Ks + rb);
            bf16x8 b1 = *(const bf16x8*)(Ks + rb + 32);
            s[nf] = mfma16(aq0, b0, s[nf]);
            s[nf] = mfma16(aq1, b1, s[nf]);
        }
        const int colbase = lane & 15;
#pragma unroll
        for (int j = 0; j < 4; j++) {
            float pv[14];
            float m = -1e30f;
#pragma unroll
            for (int nf = 0; nf < 14; nf++) {
                int col = nf * 16 + colbase;
                float v = s[nf][j] * 0.125f;
                v = (col < TT) ? v : -1e30f;
                pv[nf] = v;
                m = fmaxf(m, v);
            }
#pragma unroll
            for (int dd = 1; dd < 16; dd <<= 1) m = fmaxf(m, __shfl_xor(m, dd));
            float sum = 0.0f;
#pragma unroll
            for (int nf = 0; nf < 14; nf++) { float e = __expf(pv[nf] - m); pv[nf] = e; sum += e; }
#pragma unroll
            for (int dd = 1; dd < 16; dd <<= 1) sum += __shfl_xor(sum, dd);
            float inv = 1.0f / sum;
            int pr = (lane >> 4) * 4 + j;
#pragma unroll
            for (int nf = 0; nf < 14; nf++)
                Pm[pr * PST + nf * 16 + colbase] = (bf16)(pv[nf] * inv);
        }
        asm volatile("s_waitcnt lgkmcnt(0)" ::: "memory");
        f32x4 o[4] = {};
#pragma unroll
        for (int ks = 0; ks < 7; ks++) {
            bf16x8 pa = *(const bf16x8*)(Pm + (lane & 15) * PST + ks * 32 + (lane >> 4) * 8);
#pragma unroll
            for (int nf = 0; nf < 4; nf++) {
                bf16x8 bv = *(const bf16x8*)(Vt + (nf * 16 + (lane & 15)) * PST + ks * 32 + (lane >> 4) * 8);
                o[nf] = mfma16(pa, bv, o[nf]);
            }
        }
#pragma unroll
        for (int nf = 0; nf < 4; nf++)
#pragma unroll
            for (int j = 0; j < 4; j++) {
                int qr = q0 + (lane >> 4) * 4 + j;
                if (qr < TT) {
                    int d = nf * 16 + (lane & 15);
                    h[(size_t)(b * TT + qr) * DD + hh * 64 + d] += o[nf][j];
                }
            }
    }
}

// ---------------------------------------------------------------------------
// LayerNorm, one row per wave (4 rows/block), fp32 in -> bf16 out
// ---------------------------------------------------------------------------
__device__ __forceinline__ void ln_core(float4 a[3], const float* g, const float* bt,
                                        bf16* hn, int row, int lane) {
    float sum = 0.0f;
#pragma unroll
    for (int i = 0; i < 3; i++) sum += a[i].x + a[i].y + a[i].z + a[i].w;
#pragma unroll
    for (int dd = 1; dd < 64; dd <<= 1) sum += __shfl_xor(sum, dd);
    const float mu = sum * (1.0f / 768.0f);
    float sq = 0.0f;
#pragma unroll
    for (int i = 0; i < 3; i++) {
        float dx = a[i].x - mu, dy = a[i].y - mu, dz = a[i].z - mu, dw = a[i].w - mu;
        sq += dx * dx + dy * dy + dz * dz + dw * dw;
    }
#pragma unroll
    for (int dd = 1; dd < 64; dd <<= 1) sq += __shfl_xor(sq, dd);
    const float is = rsqrtf(sq * (1.0f / 768.0f) + 1e-5f);
#pragma unroll
    for (int i = 0; i < 3; i++) {
        int c4 = lane + i * 64;
        float4 gg = ((const float4*)g)[c4];
        float4 bb = ((const float4*)bt)[c4];
        bf16x4 o;
        o[0] = (bf16)((a[i].x - mu) * is * gg.x + bb.x);
        o[1] = (bf16)((a[i].y - mu) * is * gg.y + bb.y);
        o[2] = (bf16)((a[i].z - mu) * is * gg.z + bb.z);
        o[3] = (bf16)((a[i].w - mu) * is * gg.w + bb.w);
        ((bf16x4*)(hn + (size_t)row * DD))[c4] = o;
    }
}

__global__ void ln_kernel(const float* __restrict__ h, const float* __restrict__ g,
                          const float* __restrict__ bt, bf16* __restrict__ hn) {
    const int lane = threadIdx.x & 63, wave = threadIdx.x >> 6;
    const int row = blockIdx.x * 4 + wave;
    const float* x = h + (size_t)row * DD;
    float4 a[3];
#pragma unroll
    for (int i = 0; i < 3; i++) a[i] = ((const float4*)x)[lane + i * 64];
    ln_core(a, g, bt, hn, row, lane);
}

// h += sum(NS partials) + b2; write h; hn = LN(h)
template <int NS>
__global__ void ln_acc_kernel(float* __restrict__ h, const float* __restrict__ part,
                              const float* __restrict__ b2,
                              const float* __restrict__ g, const float* __restrict__ bt,
                              bf16* __restrict__ hn) {
    const int lane = threadIdx.x & 63, wave = threadIdx.x >> 6;
    const int row = blockIdx.x * 4 + wave;
    float* x = h + (size_t)row * DD;
    float4 a[3];
#pragma unroll
    for (int i = 0; i < 3; i++) a[i] = ((const float4*)x)[lane + i * 64];
#pragma unroll
    for (int s = 0; s < NS; s++) {
        const float4* ps = (const float4*)(part + ((size_t)s * MP + row) * DD);
#pragma unroll
        for (int i = 0; i < 3; i++) {
            float4 p = ps[lane + i * 64];
            a[i].x += p.x; a[i].y += p.y; a[i].z += p.z; a[i].w += p.w;
        }
    }
#pragma unroll
    for (int i = 0; i < 3; i++) {
        float4 bb = ((const float4*)b2)[lane + i * 64];
        a[i].x += bb.x; a[i].y += bb.y; a[i].z += bb.z; a[i].w += bb.w;
        ((float4*)x)[lane + i * 64] = a[i];
    }
    ln_core(a, g, bt, hn, row, lane);
}

// ---------------------------------------------------------------------------
__global__ void patch_extract(const float* __restrict__ x, bf16* __restrict__ p) {
    int idx = blockIdx.x * 256 + threadIdx.x;
    if (idx >= 6272 * 768) return;
    int k = idx % 768, row = idx / 768;
    int c = k % 3, pc = (k / 3) % 16, pr = k / 48;
    int b = row / 196, n = row - b * 196;
    int hp = n / 14, wp = n - hp * 14;
    p[idx] = (bf16)x[((size_t)(b * 3 + c) * 224 + hp * 16 + pr) * 224 + wp * 16 + pc];
}

__global__ void cast_bf16(const float* __restrict__ in, bf16* __restrict__ out, int n4) {
    int i = blockIdx.x * 256 + threadIdx.x;
    int stride = gridDim.x * 256;
    for (; i < n4; i += stride) {
        float4 v = ((const float4*)in)[i];
        bf16x4 o;
        o[0] = (bf16)v.x; o[1] = (bf16)v.y; o[2] = (bf16)v.z; o[3] = (bf16)v.w;
        ((bf16x4*)out)[i] = o;
    }
}

__global__ void cls_init(const float* __restrict__ cls, const float* __restrict__ pos,
                         float* __restrict__ h) {
    int i = blockIdx.x * 256 + threadIdx.x;
    if (i >= BQ * DD) return;
    int b = i / DD, c = i - b * DD;
    h[(size_t)(b * TT) * DD + c] = cls[c] + pos[c];
}

__global__ void head_kernel(const float* __restrict__ h, const float* __restrict__ hw,
                            const float* __restrict__ hb, float* __restrict__ out) {
    __shared__ float xr[DD];
    const int b = blockIdx.y;
    const int n = blockIdx.x * 256 + threadIdx.x;
    for (int i = threadIdx.x; i < DD; i += 256) xr[i] = h[(size_t)(b * TT) * DD + i];
    __syncthreads();
    if (n < 1000) {
        float s = hb[n];
        const float4* w = (const float4*)(hw + (size_t)n * DD);
        float acc = 0.0f;
#pragma unroll 4
        for (int k = 0; k < DD / 4; k++) {
            float4 wv = w[k];
            float4 xv = ((const float4*)xr)[k];
            acc += wv.x * xv.x + wv.y * xv.y + wv.z * xv.z + wv.w * xv.w;
        }
        out[b * 1000 + n] = s + acc;
    }
}

// ---------------------------------------------------------------------------
extern "C" void kernel_launch(void* const* d_in, const int* in_sizes, int n_in,
                              void* d_out, int out_size, void* d_ws, size_t ws_size,
                              hipStream_t stream) {
    const float* x       = (const float*)d_in[0];
    const float* patch_w = (const float*)d_in[1];
    const float* patch_b = (const float*)d_in[2];
    const float* pos_enc = (const float*)d_in[3];
    const float* cls_tok = (const float*)d_in[4];
    const float* qkv_w   = (const float*)d_in[5];
    const float* qkv_b   = (const float*)d_in[6];
    const float* ln_g    = (const float*)d_in[7];
    const float* ln_b    = (const float*)d_in[8];
    const float* w1      = (const float*)d_in[9];
    const float* b1      = (const float*)d_in[10];
    const float* w2      = (const float*)d_in[11];
    const float* b2      = (const float*)d_in[12];
    const float* head_w  = (const float*)d_in[13];
    const float* head_b  = (const float*)d_in[14];

    char* wp = (char*)d_ws;
    auto carve = [&](size_t bytes) {
        char* r = wp;
        wp += (bytes + 255) & ~(size_t)255;
        return r;
    };
    auto fits = [&](size_t bytes) {
        return (size_t)(wp - (char*)d_ws) + bytes + 256 <= ws_size;
    };
    float* h  = (float*)carve((size_t)MP * DD * 4);
    bf16* hn  = (bf16*)carve((size_t)MP * DD * 2);
    bf16* u   = (bf16*)carve((size_t)MP * FF * 2);
    bf16* qs  = (bf16*)carve((size_t)BQ * HH * TP * 64 * 2);
    bf16* ks  = (bf16*)carve((size_t)BQ * HH * TP * 64 * 2);
    bf16* vs  = (bf16*)carve((size_t)BQ * HH * TP * 64 * 2);
    bf16* p   = (bf16*)carve((size_t)6272 * DD * 2);
    bf16* pwb = (bf16*)carve((size_t)DD * DD * 2);
    bf16* qwb = (bf16*)carve((size_t)LL * 192 * 64 * 2);

    // split-K partials (NSPLIT x MP x DD fp32), if ws allows
    float* part = nullptr;
    if (fits((size_t)NSPLIT * MP * DD * 4))
        part = (float*)carve((size_t)NSPLIT * MP * DD * 4);
    const bool use_part = (part != nullptr);

    // precast-all weights, if ws allows
    const size_t wfull = (size_t)LL * FF * DD * 2;
    const bool precast = fits(2 * (wfull + 256));
    bf16* w1b = (bf16*)carve(precast ? wfull : (size_t)FF * DD * 2);
    bf16* w2b = (bf16*)carve(precast ? wfull : (size_t)DD * FF * 2);

    cast_bf16<<<512, 256, 0, stream>>>(patch_w, pwb, (DD * DD) / 4);
    cast_bf16<<<144, 256, 0, stream>>>(qkv_w, qwb, (LL * 192 * 64) / 4);
    if (precast) {
        cast_bf16<<<4096, 256, 0, stream>>>(w1, w1b, (LL * FF * DD) / 4);
        cast_bf16<<<4096, 256, 0, stream>>>(w2, w2b, (LL * FF * DD) / 4);
    }
    patch_extract<<<18816, 256, 0, stream>>>(x, p);
    cls_init<<<96, 256, 0, stream>>>(cls_tok, pos_enc, h);
    gemm_bt<0, 1, 768, 768, 6, 49><<<294, 256, 0, stream>>>(p, pwb, patch_b,
                                                            h, nullptr, pos_enc);

    for (int i = 0; i < LL; i++) {
        const bf16* w1i = precast ? (w1b + (size_t)i * FF * DD) : w1b;
        const bf16* w2i = precast ? (w2b + (size_t)i * FF * DD) : w2b;

        // ln1 (fused with previous layer's MLP2 partial reduction + b2 + residual)
        if (use_part && i > 0)
            ln_acc_kernel<NSPLIT><<<MP / 4, 256, 0, stream>>>(h, part, b2 + (i - 1) * DD,
                                                              ln_g + i * DD, ln_b + i * DD, hn);
        else
            ln_kernel<<<MP / 4, 256, 0, stream>>>(h, ln_g + i * DD, ln_b + i * DD, hn);

        qkv_kernel<<<MQ / 128, 256, 0, stream>>>(hn, qwb + i * 192 * 64, qkv_b + i * 192,
                                                 qs, ks, vs);
        attn_kernel<<<BQ * HH * 2, 256, 0, stream>>>(qs, ks, vs, h);
        ln_kernel<<<MP / 4, 256, 0, stream>>>(h, ln_g + i * DD, ln_b + i * DD, hn);
        if (!precast)
            cast_bf16<<<2048, 256, 0, stream>>>(w1 + (size_t)i * FF * DD, w1b, (FF * DD) / 4);
        gemm_bt<1, 1, 768, 3072, 24, 50><<<1200, 256, 0, stream>>>(hn, w1i, b1 + i * FF,
                                                                   nullptr, u, nullptr);
        if (!precast)
            cast_bf16<<<2048, 256, 0, stream>>>(w2 + (size_t)i * FF * DD, w2b, (FF * DD) / 4);
        if (use_part)
            gemm_bt<3, NSPLIT, 3072, 768, 6, 50><<<300 * NSPLIT, 256, 0, stream>>>(
                u, w2i, nullptr, part, nullptr, nullptr);
        else
            gemm_bt<2, 1, 3072, 768, 6, 50><<<300, 256, 0, stream>>>(
                u, w2i, b2 + i * DD, h, nullptr, nullptr);
    }
    if (use_part)  // final reduction of layer 11's MLP2 into h (hn output unused)
        ln_acc_kernel<NSPLIT><<<MP / 4, 256, 0, stream>>>(h, part, b2 + 11 * DD,
                                                          ln_g, ln_b, hn);
    head_kernel<<<dim3(4, BQ), 256, 0, stream>>>(h, head_w, head_b, (float*)d_out);
}

// Round 9
// 2107.614 us; speedup vs baseline: 1.7099x; 1.0727x over previous
//
#include <hip/hip_runtime.h>
#include <hip/hip_bf16.h>
#include <math.h>

typedef __bf16 bf16;
typedef bf16 bf16x8 __attribute__((ext_vector_type(8)));
typedef bf16 bf16x4 __attribute__((ext_vector_type(4)));
typedef float f32x4 __attribute__((ext_vector_type(4)));

#define BQ 32
#define TT 197
#define DD 768
#define HH 12
#define FF 3072
#define LL 12
#define TP 224
#define MR 6304   // B*T
#define MP 6400   // padded to 50*128
#define MQ 75648  // B*T*H rows for qkv gemm (591*128)
#define KST 72    // K LDS row stride (elements)
#define PST 232   // Vt LDS row stride (elements)
#define PST2 136  // P half-buffer row stride (elements)
#define NSPLIT 2  // MLP2 split-K factor

typedef __attribute__((address_space(1))) const void gv_t;
typedef __attribute__((address_space(3))) void lv_t;

__device__ __forceinline__ void gld16(const void* g, void* l) {
    __builtin_amdgcn_global_load_lds((gv_t*)g, (lv_t*)l, 16, 0, 0);
}

__device__ __forceinline__ f32x4 mfma16(bf16x8 a, bf16x8 b, f32x4 c) {
    return __builtin_amdgcn_mfma_f32_16x16x32_bf16(a, b, c, 0, 0, 0);
}

// tanh-approx GELU via hw v_exp_f32; overflow-safe (e=inf -> th=1)
__device__ __forceinline__ float fast_gelu(float v) {
    float t = 0.79788456080286535588f * v * (1.0f + 0.044715f * v * v);
    float e = __expf(2.0f * t);
    float th = 1.0f - 2.0f / (e + 1.0f);
    return 0.5f * v * (1.0f + th);
}

// bijective XCD swizzle (m204): consecutive wgid stay on one XCD
__device__ __forceinline__ int xcd_swz(int bid, int nwg) {
    int q = nwg >> 3, r = nwg & 7;
    int xcd = bid & 7, pos = bid >> 3;
    int base = (xcd < r) ? xcd * (q + 1) : r * (q + 1) + (xcd - r) * q;
    return base + pos;
}

// ---------------------------------------------------------------------------
// C = A(M,K) @ W(N,K)^T GEMM, 128x128 tile, BK=64, 4 waves, single-buffered
// (m97 structure; r5-proven). Compile-time K/N/geometry; full K-loop unroll.
// XOR swizzle cb^(row&7) on global SOURCE (LDS dest linear), mirrored on the
// ds_read side -> 0 bank conflicts (PMC-verified r4/r5).
// EPI 0: +bias, patch-embed; EPI 1: +bias, GELU->bf16; EPI 2: +bias,
// residual +=; EPI 3: raw partial write.
// ---------------------------------------------------------------------------
template <int EPI, int SPLITK, int KTOT, int NN, int GX, int GY>
__global__ __launch_bounds__(256, 4)
void gemm_bt(const bf16* __restrict__ A, const bf16* __restrict__ W,
             const float* __restrict__ bias,
             float* __restrict__ outF, bf16* __restrict__ outB,
             const float* __restrict__ pos) {
    __shared__ bf16 As[128 * 64];
    __shared__ bf16 Bs[128 * 64];
    const int tid = threadIdx.x;
    const int lane = tid & 63, wave = tid >> 6;
    const int wm = wave >> 1, wn = wave & 1;

    const int wgid = xcd_swz(blockIdx.x, GX * GY * SPLITK);
    const int ks   = (SPLITK > 1) ? wgid / (GX * GY) : 0;
    const int rem  = (SPLITK > 1) ? wgid % (GX * GY) : wgid;
    const int bx = rem % GX, by = rem / GX;
    const int m0 = by * 128, n0 = bx * 128;

    constexpr int kb = KTOT / SPLITK;
    constexpr int nt = kb / 64;
    const int k0 = ks * kb;

    f32x4 acc[4][4] = {};
    const bf16* Ab = A + (size_t)m0 * KTOT;
    const bf16* Wb = W + (size_t)n0 * KTOT;

#pragma unroll
    for (int t = 0; t < nt; ++t) {
        const int kt = k0 + t * 64;
#pragma unroll
        for (int i = 0; i < 4; i++) {
            int idx = i * 256 + tid;
            int row = idx >> 3, cb = idx & 7;
            int gcb = cb ^ (row & 7);   // pre-swizzled source column-block
            gld16(Ab + (size_t)row * KTOT + kt + gcb * 8, As + idx * 8);
            gld16(Wb + (size_t)row * KTOT + kt + gcb * 8, Bs + idx * 8);
        }
        __syncthreads();
        bf16x8 af[4][2], bfr[4][2];
        const int ca = lane >> 4;
#pragma unroll
        for (int f = 0; f < 4; f++) {
            int rowa = wm * 64 + f * 16 + (lane & 15);
            int ma = rowa & 7;
            af[f][0] = *(const bf16x8*)(As + rowa * 64 + ((ca    ) ^ ma) * 8);
            af[f][1] = *(const bf16x8*)(As + rowa * 64 + ((ca + 4) ^ ma) * 8);
            int rowb = wn * 64 + f * 16 + (lane & 15);
            int mb = rowb & 7;
            bfr[f][0] = *(const bf16x8*)(Bs + rowb * 64 + ((ca    ) ^ mb) * 8);
            bfr[f][1] = *(const bf16x8*)(Bs + rowb * 64 + ((ca + 4) ^ mb) * 8);
        }
#pragma unroll
        for (int kh = 0; kh < 2; kh++)
#pragma unroll
            for (int mf = 0; mf < 4; mf++)
#pragma unroll
                for (int nf = 0; nf < 4; nf++)
                    acc[mf][nf] = mfma16(af[mf][kh], bfr[nf][kh], acc[mf][nf]);
        __syncthreads();
    }

    const int r0 = m0 + wm * 64, c0 = n0 + wn * 64;
#pragma unroll
    for (int mf = 0; mf < 4; mf++) {
#pragma unroll
        for (int j = 0; j < 4; j++) {
            int row = r0 + mf * 16 + ((lane >> 4) * 4) + j;
            int pb = 0, pn = 0;
            if (EPI == 0) { pb = row / 196; pn = row - pb * 196; }
#pragma unroll
            for (int nf = 0; nf < 4; nf++) {
                int col = c0 + nf * 16 + (lane & 15);
                float v = acc[mf][nf][j];
                if (EPI == 0) {
                    v += bias[col];
                    float pv = pos[(size_t)(1 + pn) * DD + col];
                    outF[(size_t)(pb * TT + 1 + pn) * DD + col] = v + pv;
                } else if (EPI == 1) {
                    v += bias[col];
                    outB[(size_t)row * NN + col] = (bf16)fast_gelu(v);
                } else if (EPI == 2) {
                    v += bias[col];
                    if (row < MR) outF[(size_t)row * DD + col] += v;
                } else {
                    outF[(size_t)(ks * MP + row) * DD + col] = v;
                }
            }
        }
    }
}

// ---------------------------------------------------------------------------
// QKV: A = hn viewed as (B*T*H, 64) contiguous (since D = H*64).
// C (MQ,192) = A @ qkv_w(192,64)^T + qkv_b, scattered to Q/K/V (B*H, 224, 64)
// ---------------------------------------------------------------------------
__global__ __launch_bounds__(256, 2)
void qkv_kernel(const bf16* __restrict__ hn, const bf16* __restrict__ qw,
                const float* __restrict__ qb, bf16* __restrict__ Q,
                bf16* __restrict__ Kb, bf16* __restrict__ Vb) {
    __shared__ bf16 Asm[128 * 64];
    __shared__ bf16 Wsm[192 * 64];
    const int tid = threadIdx.x, lane = tid & 63, wave = tid >> 6;
    const bf16* Ab = hn + (size_t)blockIdx.x * (128 * 64);
#pragma unroll
    for (int i = 0; i < 4; i++) {
        int idx = i * 256 + tid;
        int row = idx >> 3, cb = idx & 7;
        int gcb = cb ^ (row & 7);
        gld16(Ab + (size_t)row * 64 + gcb * 8, Asm + idx * 8);
    }
#pragma unroll
    for (int i = 0; i < 6; i++) {
        int idx = i * 256 + tid;
        int row = idx >> 3, cb = idx & 7;
        int gcb = cb ^ (row & 7);
        gld16(qw + (size_t)row * 64 + gcb * 8, Wsm + idx * 8);
    }
    __syncthreads();

    const int ca = lane >> 4;
    bf16x8 af[2][2];
#pragma unroll
    for (int mf = 0; mf < 2; mf++) {
        int row = wave * 32 + mf * 16 + (lane & 15);
        int m7 = row & 7;
        af[mf][0] = *(const bf16x8*)(Asm + row * 64 + ((ca    ) ^ m7) * 8);
        af[mf][1] = *(const bf16x8*)(Asm + row * 64 + ((ca + 4) ^ m7) * 8);
    }
    f32x4 acc[2][12] = {};
#pragma unroll
    for (int nf = 0; nf < 12; nf++) {
        int row = nf * 16 + (lane & 15);
        int m7 = row & 7;
        bf16x8 b0 = *(const bf16x8*)(Wsm + row * 64 + ((ca    ) ^ m7) * 8);
        bf16x8 b1 = *(const bf16x8*)(Wsm + row * 64 + ((ca + 4) ^ m7) * 8);
#pragma unroll
        for (int mf = 0; mf < 2; mf++) {
            acc[mf][nf] = mfma16(af[mf][0], b0, acc[mf][nf]);
            acc[mf][nf] = mfma16(af[mf][1], b1, acc[mf][nf]);
        }
    }
    const int r0 = blockIdx.x * 128 + wave * 32;
#pragma unroll
    for (int mf = 0; mf < 2; mf++)
#pragma unroll
        for (int j = 0; j < 4; j++) {
            int r = r0 + mf * 16 + (lane >> 4) * 4 + j;
            int bt = r / 12, hh = r - bt * 12;
            int b = bt / 197, t = bt - b * 197;
            size_t dbase = ((size_t)(b * HH + hh) * TP + t) * 64;
#pragma unroll
            for (int nf = 0; nf < 12; nf++) {
                int col = nf * 16 + (lane & 15);
                float v = acc[mf][nf][j] + qb[col];
                int sel = nf >> 2, e = col & 63;
                bf16* dst = (sel == 0) ? Q : (sel == 1 ? Kb : Vb);
                dst[dbase + e] = (bf16)v;
            }
        }
}

// ---------------------------------------------------------------------------
// Fused attention: block = (b,h,half); 768 blocks. LDS 79.4 KB -> 2 blocks/CU.
// PV split into two k-halves (frags 0-7 / 8-13) reusing a per-wave 16x136 P
// buffer. P stored UNNORMALIZED (exp(S-m)); o scaled by 1/sum after PV
// (normalization is linear). Second half's exp recomputed from live s[].
// ---------------------------------------------------------------------------
__global__ __launch_bounds__(256, 2)
void attn_kernel(const bf16* __restrict__ Q, const bf16* __restrict__ Kg,
                 const bf16* __restrict__ Vg, float* __restrict__ h) {
    __shared__ bf16 Ks[TP * KST];        // 32256 B
    __shared__ bf16 Vt[64 * PST];        // 29696 B
    __shared__ bf16 Pw[4 * 16 * PST2];   // 17408 B  (total 79360 B)
    const int tid = threadIdx.x, lane = tid & 63, wave = tid >> 6;
    const int bh = blockIdx.x >> 1, sub = blockIdx.x & 1;
    const int b = bh / HH, hh = bh - b * HH;
    const bf16* Kp = Kg + (size_t)bh * TP * 64;
    const bf16* Vp = Vg + (size_t)bh * TP * 64;
    const bf16* Qp = Q + (size_t)bh * TP * 64;

#pragma unroll
    for (int i = 0; i < 7; i++) {
        int idx = i * 256 + tid;
        int row = idx >> 3, cb = idx & 7;
        bf16x8 kv = *(const bf16x8*)(Kp + idx * 8);
        *(bf16x8*)(Ks + row * KST + cb * 8) = kv;
        bf16x8 vv = *(const bf16x8*)(Vp + idx * 8);
#pragma unroll
        for (int j = 0; j < 8; j++) Vt[(cb * 8 + j) * PST + row] = vv[j];
    }
    __syncthreads();

    bf16* Pm = Pw + wave * 16 * PST2;
    const int cEnd = sub ? 13 : 7;
    for (int ch = sub * 7 + wave; ch < cEnd; ch += 4) {
        const int q0 = ch * 16;
        const bf16* qp = Qp + (q0 + (lane & 15)) * 64 + (lane >> 4) * 8;
        bf16x8 aq0 = *(const bf16x8*)qp;
        bf16x8 aq1 = *(const bf16x8*)(qp + 32);
        f32x4 s[14] = {};
#pragma unroll
        for (int nf = 0; nf < 14; nf++) {
            int rb = (nf * 16 + (lane & 15)) * KST + (lane >> 4) * 8;
            bf16x8 b0 = *(const bf16x8*)(Ks + rb);
            bf16x8 b1 = *(const bf16x8*)(Ks + rb + 32);
            s[nf] = mfma16(aq0, b0, s[nf]);
            s[nf] = mfma16(aq1, b1, s[nf]);
        }
        const int colbase = lane & 15;
        float mmax[4], minv[4];
#pragma unroll
        for (int j = 0; j < 4; j++) {
            float m = -1e30f;
#pragma unroll
            for (int nf = 0; nf < 14; nf++) {
                int col = nf * 16 + colbase;
                float v = (col < TT) ? s[nf][j] * 0.125f : -1e30f;
                m = fmaxf(m, v);
            }
#pragma unroll
            for (int dd = 1; dd < 16; dd <<= 1) m = fmaxf(m, __shfl_xor(m, dd));
            float sum = 0.0f;
#pragma unroll
            for (int nf = 0; nf < 14; nf++) {
                int col = nf * 16 + colbase;
                float v = (col < TT) ? s[nf][j] * 0.125f : -1e30f;
                sum += __expf(v - m);
            }
#pragma unroll
            for (int dd = 1; dd < 16; dd <<= 1) sum += __shfl_xor(sum, dd);
            mmax[j] = m;
            minv[j] = 1.0f / sum;
        }
        f32x4 o[4] = {};
        // ---- half A: frags 0..7 (k = 0..127) ----
#pragma unroll
        for (int j = 0; j < 4; j++) {
            int pr = (lane >> 4) * 4 + j;
#pragma unroll
            for (int nf = 0; nf < 8; nf++) {
                int col = nf * 16 + colbase;
                float v = (col < TT) ? s[nf][j] * 0.125f : -1e30f;
                Pm[pr * PST2 + nf * 16 + colbase] = (bf16)__expf(v - mmax[j]);
            }
        }
        asm volatile("s_waitcnt lgkmcnt(0)" ::: "memory");
#pragma unroll
        for (int ks = 0; ks < 4; ks++) {
            bf16x8 pa = *(const bf16x8*)(Pm + (lane & 15) * PST2 + ks * 32 + (lane >> 4) * 8);
#pragma unroll
            for (int nf = 0; nf < 4; nf++) {
                bf16x8 bv = *(const bf16x8*)(Vt + (nf * 16 + (lane & 15)) * PST + ks * 32 + (lane >> 4) * 8);
                o[nf] = mfma16(pa, bv, o[nf]);
            }
        }
        asm volatile("s_waitcnt lgkmcnt(0)" ::: "memory");
        // ---- half B: frags 8..13 (k = 128..223) ----
#pragma unroll
        for (int j = 0; j < 4; j++) {
            int pr = (lane >> 4) * 4 + j;
#pragma unroll
            for (int nf = 8; nf < 14; nf++) {
                int col = nf * 16 + colbase;
                float v = (col < TT) ? s[nf][j] * 0.125f : -1e30f;
                Pm[pr * PST2 + (nf - 8) * 16 + colbase] = (bf16)__expf(v - mmax[j]);
            }
        }
        asm volatile("s_waitcnt lgkmcnt(0)" ::: "memory");
#pragma unroll
        for (int ks = 4; ks < 7; ks++) {
            bf16x8 pa = *(const bf16x8*)(Pm + (lane & 15) * PST2 + (ks - 4) * 32 + (lane >> 4) * 8);
#pragma unroll
            for (int nf = 0; nf < 4; nf++) {
                bf16x8 bv = *(const bf16x8*)(Vt + (nf * 16 + (lane & 15)) * PST + ks * 32 + (lane >> 4) * 8);
                o[nf] = mfma16(pa, bv, o[nf]);
            }
        }
        asm volatile("s_waitcnt lgkmcnt(0)" ::: "memory");
#pragma unroll
        for (int nf = 0; nf < 4; nf++)
#pragma unroll
            for (int j = 0; j < 4; j++) {
                int qr = q0 + (lane >> 4) * 4 + j;
                if (qr < TT) {
                    int d = nf * 16 + (lane & 15);
                    h[(size_t)(b * TT + qr) * DD + hh * 64 + d] += o[nf][j] * minv[j];
                }
            }
    }
}

// ---------------------------------------------------------------------------
// LayerNorm, one row per wave (4 rows/block), fp32 in -> bf16 out
// ---------------------------------------------------------------------------
__device__ __forceinline__ void ln_core(float4 a[3], const float* g, const float* bt,
                                        bf16* hn, int row, int lane) {
    float sum = 0.0f;
#pragma unroll
    for (int i = 0; i < 3; i++) sum += a[i].x + a[i].y + a[i].z + a[i].w;
#pragma unroll
    for (int dd = 1; dd < 64; dd <<= 1) sum += __shfl_xor(sum, dd);
    const float mu = sum * (1.0f / 768.0f);
    float sq = 0.0f;
#pragma unroll
    for (int i = 0; i < 3; i++) {
        float dx = a[i].x - mu, dy = a[i].y - mu, dz = a[i].z - mu, dw = a[i].w - mu;
        sq += dx * dx + dy * dy + dz * dz + dw * dw;
    }
#pragma unroll
    for (int dd = 1; dd < 64; dd <<= 1) sq += __shfl_xor(sq, dd);
    const float is = rsqrtf(sq * (1.0f / 768.0f) + 1e-5f);
#pragma unroll
    for (int i = 0; i < 3; i++) {
        int c4 = lane + i * 64;
        float4 gg = ((const float4*)g)[c4];
        float4 bb = ((const float4*)bt)[c4];
        bf16x4 o;
        o[0] = (bf16)((a[i].x - mu) * is * gg.x + bb.x);
        o[1] = (bf16)((a[i].y - mu) * is * gg.y + bb.y);
        o[2] = (bf16)((a[i].z - mu) * is * gg.z + bb.z);
        o[3] = (bf16)((a[i].w - mu) * is * gg.w + bb.w);
        ((bf16x4*)(hn + (size_t)row * DD))[c4] = o;
    }
}

__global__ void ln_kernel(const float* __restrict__ h, const float* __restrict__ g,
                          const float* __restrict__ bt, bf16* __restrict__ hn) {
    const int lane = threadIdx.x & 63, wave = threadIdx.x >> 6;
    const int row = blockIdx.x * 4 + wave;
    const float* x = h + (size_t)row * DD;
    float4 a[3];
#pragma unroll
    for (int i = 0; i < 3; i++) a[i] = ((const float4*)x)[lane + i * 64];
    ln_core(a, g, bt, hn, row, lane);
}

// h += sum(NS partials) + b2; write h; hn = LN(h)
template <int NS>
__global__ void ln_acc_kernel(float* __restrict__ h, const float* __restrict__ part,
                              const float* __restrict__ b2,
                              const float* __restrict__ g, const float* __restrict__ bt,
                              bf16* __restrict__ hn) {
    const int lane = threadIdx.x & 63, wave = threadIdx.x >> 6;
    const int row = blockIdx.x * 4 + wave;
    float* x = h + (size_t)row * DD;
    float4 a[3];
#pragma unroll
    for (int i = 0; i < 3; i++) a[i] = ((const float4*)x)[lane + i * 64];
#pragma unroll
    for (int s = 0; s < NS; s++) {
        const float4* ps = (const float4*)(part + ((size_t)s * MP + row) * DD);
#pragma unroll
        for (int i = 0; i < 3; i++) {
            float4 p = ps[lane + i * 64];
            a[i].x += p.x; a[i].y += p.y; a[i].z += p.z; a[i].w += p.w;
        }
    }
#pragma unroll
    for (int i = 0; i < 3; i++) {
        float4 bb = ((const float4*)b2)[lane + i * 64];
        a[i].x += bb.x; a[i].y += bb.y; a[i].z += bb.z; a[i].w += bb.w;
        ((float4*)x)[lane + i * 64] = a[i];
    }
    ln_core(a, g, bt, hn, row, lane);
}

// ---------------------------------------------------------------------------
__global__ void patch_extract(const float* __restrict__ x, bf16* __restrict__ p) {
    int idx = blockIdx.x * 256 + threadIdx.x;
    if (idx >= 6272 * 768) return;
    int k = idx % 768, row = idx / 768;
    int c = k % 3, pc = (k / 3) % 16, pr = k / 48;
    int b = row / 196, n = row - b * 196;
    int hp = n / 14, wp = n - hp * 14;
    p[idx] = (bf16)x[((size_t)(b * 3 + c) * 224 + hp * 16 + pr) * 224 + wp * 16 + pc];
}

__global__ void cast_bf16(const float* __restrict__ in, bf16* __restrict__ out, int n4) {
    int i = blockIdx.x * 256 + threadIdx.x;
    int stride = gridDim.x * 256;
    for (; i < n4; i += stride) {
        float4 v = ((const float4*)in)[i];
        bf16x4 o;
        o[0] = (bf16)v.x; o[1] = (bf16)v.y; o[2] = (bf16)v.z; o[3] = (bf16)v.w;
        ((bf16x4*)out)[i] = o;
    }
}

__global__ void cls_init(const float* __restrict__ cls, const float* __restrict__ pos,
                         float* __restrict__ h) {
    int i = blockIdx.x * 256 + threadIdx.x;
    if (i >= BQ * DD) return;
    int b = i / DD, c = i - b * DD;
    h[(size_t)(b * TT) * DD + c] = cls[c] + pos[c];
}

__global__ void head_kernel(const float* __restrict__ h, const float* __restrict__ hw,
                            const float* __restrict__ hb, float* __restrict__ out) {
    __shared__ float xr[DD];
    const int b = blockIdx.y;
    const int n = blockIdx.x * 256 + threadIdx.x;
    for (int i = threadIdx.x; i < DD; i += 256) xr[i] = h[(size_t)(b * TT) * DD + i];
    __syncthreads();
    if (n < 1000) {
        float s = hb[n];
        const float4* w = (const float4*)(hw + (size_t)n * DD);
        float acc = 0.0f;
#pragma unroll 4
        for (int k = 0; k < DD / 4; k++) {
            float4 wv = w[k];
            float4 xv = ((const float4*)xr)[k];
            acc += wv.x * xv.x + wv.y * xv.y + wv.z * xv.z + wv.w * xv.w;
        }
        out[b * 1000 + n] = s + acc;
    }
}

// ---------------------------------------------------------------------------
extern "C" void kernel_launch(void* const* d_in, const int* in_sizes, int n_in,
                              void* d_out, int out_size, void* d_ws, size_t ws_size,
                              hipStream_t stream) {
    const float* x       = (const float*)d_in[0];
    const float* patch_w = (const float*)d_in[1];
    const float* patch_b = (const float*)d_in[2];
    const float* pos_enc = (const float*)d_in[3];
    const float* cls_tok = (const float*)d_in[4];
    const float* qkv_w   = (const float*)d_in[5];
    const float* qkv_b   = (const float*)d_in[6];
    const float* ln_g    = (const float*)d_in[7];
    const float* ln_b    = (const float*)d_in[8];
    const float* w1      = (const float*)d_in[9];
    const float* b1      = (const float*)d_in[10];
    const float* w2      = (const float*)d_in[11];
    const float* b2      = (const float*)d_in[12];
    const float* head_w  = (const float*)d_in[13];
    const float* head_b  = (const float*)d_in[14];

    char* wp = (char*)d_ws;
    auto carve = [&](size_t bytes) {
        char* r = wp;
        wp += (bytes + 255) & ~(size_t)255;
        return r;
    };
    auto fits = [&](size_t bytes) {
        return (size_t)(wp - (char*)d_ws) + bytes + 256 <= ws_size;
    };
    float* h  = (float*)carve((size_t)MP * DD * 4);
    bf16* hn  = (bf16*)carve((size_t)MP * DD * 2);
    bf16* u   = (bf16*)carve((size_t)MP * FF * 2);
    bf16* qs  = (bf16*)carve((size_t)BQ * HH * TP * 64 * 2);
    bf16* ks  = (bf16*)carve((size_t)BQ * HH * TP * 64 * 2);
    bf16* vs  = (bf16*)carve((size_t)BQ * HH * TP * 64 * 2);
    bf16* p   = (bf16*)carve((size_t)6272 * DD * 2);
    bf16* pwb = (bf16*)carve((size_t)DD * DD * 2);
    bf16* qwb = (bf16*)carve((size_t)LL * 192 * 64 * 2);

    // split-K partials (NSPLIT x MP x DD fp32), if ws allows
    float* part = nullptr;
    if (fits((size_t)NSPLIT * MP * DD * 4))
        part = (float*)carve((size_t)NSPLIT * MP * DD * 4);
    const bool use_part = (part != nullptr);

    // precast-all weights, if ws allows
    const size_t wfull = (size_t)LL * FF * DD * 2;
    const bool precast = fits(2 * (wfull + 256));
    bf16* w1b = (bf16*)carve(precast ? wfull : (size_t)FF * DD * 2);
    bf16* w2b = (bf16*)carve(precast ? wfull : (size_t)DD * FF * 2);

    cast_bf16<<<512, 256, 0, stream>>>(patch_w, pwb, (DD * DD) / 4);
    cast_bf16<<<144, 256, 0, stream>>>(qkv_w, qwb, (LL * 192 * 64) / 4);
    if (precast) {
        cast_bf16<<<4096, 256, 0, stream>>>(w1, w1b, (LL * FF * DD) / 4);
        cast_bf16<<<4096, 256, 0, stream>>>(w2, w2b, (LL * FF * DD) / 4);
    }
    patch_extract<<<18816, 256, 0, stream>>>(x, p);
    cls_init<<<96, 256, 0, stream>>>(cls_tok, pos_enc, h);
    gemm_bt<0, 1, 768, 768, 6, 49><<<294, 256, 0, stream>>>(p, pwb, patch_b,
                                                            h, nullptr, pos_enc);

    for (int i = 0; i < LL; i++) {
        const bf16* w1i = precast ? (w1b + (size_t)i * FF * DD) : w1b;
        const bf16* w2i = precast ? (w2b + (size_t)i * FF * DD) : w2b;

        // ln1 (fused with previous layer's MLP2 partial reduction + b2 + residual)
        if (use_part && i > 0)
            ln_acc_kernel<NSPLIT><<<MP / 4, 256, 0, stream>>>(h, part, b2 + (i - 1) * DD,
                                                              ln_g + i * DD, ln_b + i * DD, hn);
        else
            ln_kernel<<<MP / 4, 256, 0, stream>>>(h, ln_g + i * DD, ln_b + i * DD, hn);

        qkv_kernel<<<MQ / 128, 256, 0, stream>>>(hn, qwb + i * 192 * 64, qkv_b + i * 192,
                                                 qs, ks, vs);
        attn_kernel<<<BQ * HH * 2, 256, 0, stream>>>(qs, ks, vs, h);
        ln_kernel<<<MP / 4, 256, 0, stream>>>(h, ln_g + i * DD, ln_b + i * DD, hn);
        if (!precast)
            cast_bf16<<<2048, 256, 0, stream>>>(w1 + (size_t)i * FF * DD, w1b, (FF * DD) / 4);
        gemm_bt<1, 1, 768, 3072, 24, 50><<<1200, 256, 0, stream>>>(hn, w1i, b1 + i * FF,
                                                                   nullptr, u, nullptr);
        if (!precast)
            cast_bf16<<<2048, 256, 0, stream>>>(w2 + (size_t)i * FF * DD, w2b, (FF * DD) / 4);
        if (use_part)
            gemm_bt<3, NSPLIT, 3072, 768, 6, 50><<<300 * NSPLIT, 256, 0, stream>>>(
                u, w2i, nullptr, part, nullptr, nullptr);
        else
            gemm_bt<2, 1, 3072, 768, 6, 50><<<300, 256, 0, stream>>>(
                u, w2i, b2 + i * DD, h, nullptr, nullptr);
    }
    if (use_part)  // final reduction of layer 11's MLP2 into h (hn output unused)
        ln_acc_kernel<NSPLIT><<<MP / 4, 256, 0, stream>>>(h, part, b2 + 11 * DD,
                                                          ln_g, ln_b, hn);
    head_kernel<<<dim3(4, BQ), 256, 0, stream>>>(h, head_w, head_b, (float*)d_out);
}

// Round 10
// 1995.409 us; speedup vs baseline: 1.8061x; 1.0562x over previous
//
#include <hip/hip_runtime.h>
#include <hip/hip_bf16.h>
#include <math.h>

typedef __bf16 bf16;
typedef bf16 bf16x8 __attribute__((ext_vector_type(8)));
typedef bf16 bf16x4 __attribute__((ext_vector_type(4)));
typedef float f32x4 __attribute__((ext_vector_type(4)));

#define BQ 32
#define TT 197
#define DD 768
#define HH 12
#define FF 3072
#define LL 12
#define TP 224
#define MR 6304   // B*T
#define MP 6400   // padded to 50*128
#define KST 72    // K LDS row stride (elements)
#define PST 232   // Vt LDS row stride (elements)
#define PST2 136  // P half-buffer row stride (elements)
#define NSPLIT 2  // MLP2 split-K factor

typedef __attribute__((address_space(1))) const void gv_t;
typedef __attribute__((address_space(3))) void lv_t;

__device__ __forceinline__ void gld16(const void* g, void* l) {
    __builtin_amdgcn_global_load_lds((gv_t*)g, (lv_t*)l, 16, 0, 0);
}

__device__ __forceinline__ f32x4 mfma16(bf16x8 a, bf16x8 b, f32x4 c) {
    return __builtin_amdgcn_mfma_f32_16x16x32_bf16(a, b, c, 0, 0, 0);
}

// tanh-approx GELU via hw v_exp_f32; overflow-safe (e=inf -> th=1)
__device__ __forceinline__ float fast_gelu(float v) {
    float t = 0.79788456080286535588f * v * (1.0f + 0.044715f * v * v);
    float e = __expf(2.0f * t);
    float th = 1.0f - 2.0f / (e + 1.0f);
    return 0.5f * v * (1.0f + th);
}

// bijective XCD swizzle (m204): consecutive wgid stay on one XCD
__device__ __forceinline__ int xcd_swz(int bid, int nwg) {
    int q = nwg >> 3, r = nwg & 7;
    int xcd = bid & 7, pos = bid >> 3;
    int base = (xcd < r) ? xcd * (q + 1) : r * (q + 1) + (xcd - r) * q;
    return base + pos;
}

// ---------------------------------------------------------------------------
// C = A(M,K) @ W(N,K)^T GEMM, 128x128 tile, BK=64, 4 waves, single-buffered
// (m97 structure; r5-proven). Compile-time K/N/geometry; full K-loop unroll.
// XOR swizzle cb^(row&7) on global SOURCE (LDS dest linear), mirrored on the
// ds_read side -> 0 bank conflicts (PMC-verified r4/r5).
// EPI 0: +bias, patch-embed; EPI 1: +bias, GELU->bf16; EPI 2: +bias,
// residual +=; EPI 3: raw partial write.
// ---------------------------------------------------------------------------
template <int EPI, int SPLITK, int KTOT, int NN, int GX, int GY>
__global__ __launch_bounds__(256, 4)
void gemm_bt(const bf16* __restrict__ A, const bf16* __restrict__ W,
             const float* __restrict__ bias,
             float* __restrict__ outF, bf16* __restrict__ outB,
             const float* __restrict__ pos) {
    __shared__ bf16 As[128 * 64];
    __shared__ bf16 Bs[128 * 64];
    const int tid = threadIdx.x;
    const int lane = tid & 63, wave = tid >> 6;
    const int wm = wave >> 1, wn = wave & 1;

    const int wgid = xcd_swz(blockIdx.x, GX * GY * SPLITK);
    const int ks   = (SPLITK > 1) ? wgid / (GX * GY) : 0;
    const int rem  = (SPLITK > 1) ? wgid % (GX * GY) : wgid;
    const int bx = rem % GX, by = rem / GX;
    const int m0 = by * 128, n0 = bx * 128;

    constexpr int kb = KTOT / SPLITK;
    constexpr int nt = kb / 64;
    const int k0 = ks * kb;

    f32x4 acc[4][4] = {};
    const bf16* Ab = A + (size_t)m0 * KTOT;
    const bf16* Wb = W + (size_t)n0 * KTOT;

#pragma unroll
    for (int t = 0; t < nt; ++t) {
        const int kt = k0 + t * 64;
#pragma unroll
        for (int i = 0; i < 4; i++) {
            int idx = i * 256 + tid;
            int row = idx >> 3, cb = idx & 7;
            int gcb = cb ^ (row & 7);   // pre-swizzled source column-block
            gld16(Ab + (size_t)row * KTOT + kt + gcb * 8, As + idx * 8);
            gld16(Wb + (size_t)row * KTOT + kt + gcb * 8, Bs + idx * 8);
        }
        __syncthreads();
        bf16x8 af[4][2], bfr[4][2];
        const int ca = lane >> 4;
#pragma unroll
        for (int f = 0; f < 4; f++) {
            int rowa = wm * 64 + f * 16 + (lane & 15);
            int ma = rowa & 7;
            af[f][0] = *(const bf16x8*)(As + rowa * 64 + ((ca    ) ^ ma) * 8);
            af[f][1] = *(const bf16x8*)(As + rowa * 64 + ((ca + 4) ^ ma) * 8);
            int rowb = wn * 64 + f * 16 + (lane & 15);
            int mb = rowb & 7;
            bfr[f][0] = *(const bf16x8*)(Bs + rowb * 64 + ((ca    ) ^ mb) * 8);
            bfr[f][1] = *(const bf16x8*)(Bs + rowb * 64 + ((ca + 4) ^ mb) * 8);
        }
#pragma unroll
        for (int kh = 0; kh < 2; kh++)
#pragma unroll
            for (int mf = 0; mf < 4; mf++)
#pragma unroll
                for (int nf = 0; nf < 4; nf++)
                    acc[mf][nf] = mfma16(af[mf][kh], bfr[nf][kh], acc[mf][nf]);
        __syncthreads();
    }

    const int r0 = m0 + wm * 64, c0 = n0 + wn * 64;
#pragma unroll
    for (int mf = 0; mf < 4; mf++) {
#pragma unroll
        for (int j = 0; j < 4; j++) {
            int row = r0 + mf * 16 + ((lane >> 4) * 4) + j;
            int pb = 0, pn = 0;
            if (EPI == 0) { pb = row / 196; pn = row - pb * 196; }
#pragma unroll
            for (int nf = 0; nf < 4; nf++) {
                int col = c0 + nf * 16 + (lane & 15);
                float v = acc[mf][nf][j];
                if (EPI == 0) {
                    v += bias[col];
                    float pv = pos[(size_t)(1 + pn) * DD + col];
                    outF[(size_t)(pb * TT + 1 + pn) * DD + col] = v + pv;
                } else if (EPI == 1) {
                    v += bias[col];
                    outB[(size_t)row * NN + col] = (bf16)fast_gelu(v);
                } else if (EPI == 2) {
                    v += bias[col];
                    if (row < MR) outF[(size_t)row * DD + col] += v;
                } else {
                    outF[(size_t)(ks * MP + row) * DD + col] = v;
                }
            }
        }
    }
}

// ---------------------------------------------------------------------------
// Fused LN1 + QKV. Grid 394 blocks x 16 bt-rows. Phase 1: (optional) partial
// reduce + b2 + residual -> h, LN -> swizzled 192x64 bf16 A-tile in LDS (hn
// round-trip eliminated). Phase 2: (192x192x64) MFMA vs qkv_w, scatter to
// Q/K/V (B*H, 224, 64). W staged via gld16 BEFORE phase 1 (latency hidden).
// ---------------------------------------------------------------------------
template <int ACC>
__global__ __launch_bounds__(256, 2)
void lnqkv_kernel(float* __restrict__ h, const float* __restrict__ part,
                  const float* __restrict__ b2p,
                  const float* __restrict__ g, const float* __restrict__ bt,
                  const bf16* __restrict__ qw, const float* __restrict__ qb,
                  bf16* __restrict__ Q, bf16* __restrict__ Kb,
                  bf16* __restrict__ Vb) {
    __shared__ bf16 Asm[192 * 64];
    __shared__ bf16 Wsm[192 * 64];
    const int tid = threadIdx.x, lane = tid & 63, wave = tid >> 6;
    const int g0 = blockIdx.x * 16;

    // stage W early; drains at the __syncthreads below
#pragma unroll
    for (int i = 0; i < 6; i++) {
        int idx = i * 256 + tid;
        int row = idx >> 3, cb = idx & 7;
        int gcb = cb ^ (row & 7);
        gld16(qw + (size_t)row * 64 + gcb * 8, Wsm + idx * 8);
    }

    // phase 1: 4 rows per wave; residual+LN -> Asm (swizzled col-blocks)
    for (int r = 0; r < 4; r++) {
        const int row = g0 + wave * 4 + r;
        float* x = h + (size_t)row * DD;
        float4 a[3];
#pragma unroll
        for (int i = 0; i < 3; i++) a[i] = ((const float4*)x)[lane + i * 64];
        if (ACC) {
#pragma unroll
            for (int s = 0; s < NSPLIT; s++) {
                const float4* ps = (const float4*)(part + ((size_t)s * MP + row) * DD);
#pragma unroll
                for (int i = 0; i < 3; i++) {
                    float4 p = ps[lane + i * 64];
                    a[i].x += p.x; a[i].y += p.y; a[i].z += p.z; a[i].w += p.w;
                }
            }
#pragma unroll
            for (int i = 0; i < 3; i++) {
                float4 bb = ((const float4*)b2p)[lane + i * 64];
                a[i].x += bb.x; a[i].y += bb.y; a[i].z += bb.z; a[i].w += bb.w;
                ((float4*)x)[lane + i * 64] = a[i];
            }
        }
        float sum = 0.0f;
#pragma unroll
        for (int i = 0; i < 3; i++) sum += a[i].x + a[i].y + a[i].z + a[i].w;
#pragma unroll
        for (int dd = 1; dd < 64; dd <<= 1) sum += __shfl_xor(sum, dd);
        const float mu = sum * (1.0f / 768.0f);
        float sq = 0.0f;
#pragma unroll
        for (int i = 0; i < 3; i++) {
            float dx = a[i].x - mu, dy = a[i].y - mu, dz = a[i].z - mu, dw = a[i].w - mu;
            sq += dx * dx + dy * dy + dz * dz + dw * dw;
        }
#pragma unroll
        for (int dd = 1; dd < 64; dd <<= 1) sq += __shfl_xor(sq, dd);
        const float is = rsqrtf(sq * (1.0f / 768.0f) + 1e-5f);
#pragma unroll
        for (int i = 0; i < 3; i++) {
            int c4 = lane + i * 64;
            float4 gg = ((const float4*)g)[c4];
            float4 bb = ((const float4*)bt)[c4];
            bf16x4 o;
            o[0] = (bf16)((a[i].x - mu) * is * gg.x + bb.x);
            o[1] = (bf16)((a[i].y - mu) * is * gg.y + bb.y);
            o[2] = (bf16)((a[i].z - mu) * is * gg.z + bb.z);
            o[3] = (bf16)((a[i].w - mu) * is * gg.w + bb.w);
            int col = c4 * 4;
            int arow = (row - g0) * 12 + (col >> 6);
            int acol = col & 63;
            int scol = (((acol >> 3) ^ (arow & 7)) << 3) + (acol & 7);
            *(bf16x4*)(Asm + arow * 64 + scol) = o;
        }
    }
    __syncthreads();   // drains W gld16 (vmcnt) + Asm writes (lgkm)

    // phase 2: QKV MFMA, 3 m-frags x 12 n-frags per wave
    const int ca = lane >> 4;
    bf16x8 af[3][2];
#pragma unroll
    for (int mf = 0; mf < 3; mf++) {
        int row = wave * 48 + mf * 16 + (lane & 15);
        int m7 = row & 7;
        af[mf][0] = *(const bf16x8*)(Asm + row * 64 + ((ca    ) ^ m7) * 8);
        af[mf][1] = *(const bf16x8*)(Asm + row * 64 + ((ca + 4) ^ m7) * 8);
    }
    f32x4 acc[3][12] = {};
#pragma unroll
    for (int nf = 0; nf < 12; nf++) {
        int row = nf * 16 + (lane & 15);
        int m7 = row & 7;
        bf16x8 b0 = *(const bf16x8*)(Wsm + row * 64 + ((ca    ) ^ m7) * 8);
        bf16x8 b1 = *(const bf16x8*)(Wsm + row * 64 + ((ca + 4) ^ m7) * 8);
#pragma unroll
        for (int mf = 0; mf < 3; mf++) {
            acc[mf][nf] = mfma16(af[mf][0], b0, acc[mf][nf]);
            acc[mf][nf] = mfma16(af[mf][1], b1, acc[mf][nf]);
        }
    }
    const int r0 = blockIdx.x * 192 + wave * 48;
#pragma unroll
    for (int mf = 0; mf < 3; mf++)
#pragma unroll
        for (int j = 0; j < 4; j++) {
            int r = r0 + mf * 16 + (lane >> 4) * 4 + j;
            int btq = r / 12, hh = r - btq * 12;
            int b = btq / 197, t = btq - b * 197;
            size_t dbase = ((size_t)(b * HH + hh) * TP + t) * 64;
#pragma unroll
            for (int nf = 0; nf < 12; nf++) {
                int col = nf * 16 + (lane & 15);
                float v = acc[mf][nf][j] + qb[col];
                int sel = nf >> 2, e = col & 63;
                bf16* dst = (sel == 0) ? Q : (sel == 1 ? Kb : Vb);
                dst[dbase + e] = (bf16)v;
            }
        }
}

// ---------------------------------------------------------------------------
// Fused attention: block = (b,h,half); 768 blocks. LDS 79.4 KB -> 2 blocks/CU.
// PV split into two k-halves reusing a per-wave 16x136 P buffer; P stored
// unnormalized, o scaled by 1/sum post-PV. (r9-proven)
// ---------------------------------------------------------------------------
__global__ __launch_bounds__(256, 2)
void attn_kernel(const bf16* __restrict__ Q, const bf16* __restrict__ Kg,
                 const bf16* __restrict__ Vg, float* __restrict__ h) {
    __shared__ bf16 Ks[TP * KST];
    __shared__ bf16 Vt[64 * PST];
    __shared__ bf16 Pw[4 * 16 * PST2];
    const int tid = threadIdx.x, lane = tid & 63, wave = tid >> 6;
    const int bh = blockIdx.x >> 1, sub = blockIdx.x & 1;
    const int b = bh / HH, hh = bh - b * HH;
    const bf16* Kp = Kg + (size_t)bh * TP * 64;
    const bf16* Vp = Vg + (size_t)bh * TP * 64;
    const bf16* Qp = Q + (size_t)bh * TP * 64;

#pragma unroll
    for (int i = 0; i < 7; i++) {
        int idx = i * 256 + tid;
        int row = idx >> 3, cb = idx & 7;
        bf16x8 kv = *(const bf16x8*)(Kp + idx * 8);
        *(bf16x8*)(Ks + row * KST + cb * 8) = kv;
        bf16x8 vv = *(const bf16x8*)(Vp + idx * 8);
#pragma unroll
        for (int j = 0; j < 8; j++) Vt[(cb * 8 + j) * PST + row] = vv[j];
    }
    __syncthreads();

    bf16* Pm = Pw + wave * 16 * PST2;
    const int cEnd = sub ? 13 : 7;
    for (int ch = sub * 7 + wave; ch < cEnd; ch += 4) {
        const int q0 = ch * 16;
        const bf16* qp = Qp + (q0 + (lane & 15)) * 64 + (lane >> 4) * 8;
        bf16x8 aq0 = *(const bf16x8*)qp;
        bf16x8 aq1 = *(const bf16x8*)(qp + 32);
        f32x4 s[14] = {};
#pragma unroll
        for (int nf = 0; nf < 14; nf++) {
            int rb = (nf * 16 + (lane & 15)) * KST + (lane >> 4) * 8;
            bf16x8 b0 = *(const bf16x8*)(Ks + rb);
            bf16x8 b1 = *(const bf16x8*)(Ks + rb + 32);
            s[nf] = mfma16(aq0, b0, s[nf]);
            s[nf] = mfma16(aq1, b1, s[nf]);
        }
        const int colbase = lane & 15;
        float mmax[4], minv[4];
#pragma unroll
        for (int j = 0; j < 4; j++) {
            float m = -1e30f;
#pragma unroll
            for (int nf = 0; nf < 14; nf++) {
                int col = nf * 16 + colbase;
                float v = (col < TT) ? s[nf][j] * 0.125f : -1e30f;
                m = fmaxf(m, v);
            }
#pragma unroll
            for (int dd = 1; dd < 16; dd <<= 1) m = fmaxf(m, __shfl_xor(m, dd));
            float sum = 0.0f;
#pragma unroll
            for (int nf = 0; nf < 14; nf++) {
                int col = nf * 16 + colbase;
                float v = (col < TT) ? s[nf][j] * 0.125f : -1e30f;
                sum += __expf(v - m);
            }
#pragma unroll
            for (int dd = 1; dd < 16; dd <<= 1) sum += __shfl_xor(sum, dd);
            mmax[j] = m;
            minv[j] = 1.0f / sum;
        }
        f32x4 o[4] = {};
#pragma unroll
        for (int j = 0; j < 4; j++) {
            int pr = (lane >> 4) * 4 + j;
#pragma unroll
            for (int nf = 0; nf < 8; nf++) {
                int col = nf * 16 + colbase;
                float v = (col < TT) ? s[nf][j] * 0.125f : -1e30f;
                Pm[pr * PST2 + nf * 16 + colbase] = (bf16)__expf(v - mmax[j]);
            }
        }
        asm volatile("s_waitcnt lgkmcnt(0)" ::: "memory");
#pragma unroll
        for (int ks = 0; ks < 4; ks++) {
            bf16x8 pa = *(const bf16x8*)(Pm + (lane & 15) * PST2 + ks * 32 + (lane >> 4) * 8);
#pragma unroll
            for (int nf = 0; nf < 4; nf++) {
                bf16x8 bv = *(const bf16x8*)(Vt + (nf * 16 + (lane & 15)) * PST + ks * 32 + (lane >> 4) * 8);
                o[nf] = mfma16(pa, bv, o[nf]);
            }
        }
        asm volatile("s_waitcnt lgkmcnt(0)" ::: "memory");
#pragma unroll
        for (int j = 0; j < 4; j++) {
            int pr = (lane >> 4) * 4 + j;
#pragma unroll
            for (int nf = 8; nf < 14; nf++) {
                int col = nf * 16 + colbase;
                float v = (col < TT) ? s[nf][j] * 0.125f : -1e30f;
                Pm[pr * PST2 + (nf - 8) * 16 + colbase] = (bf16)__expf(v - mmax[j]);
            }
        }
        asm volatile("s_waitcnt lgkmcnt(0)" ::: "memory");
#pragma unroll
        for (int ks = 4; ks < 7; ks++) {
            bf16x8 pa = *(const bf16x8*)(Pm + (lane & 15) * PST2 + (ks - 4) * 32 + (lane >> 4) * 8);
#pragma unroll
            for (int nf = 0; nf < 4; nf++) {
                bf16x8 bv = *(const bf16x8*)(Vt + (nf * 16 + (lane & 15)) * PST + ks * 32 + (lane >> 4) * 8);
                o[nf] = mfma16(pa, bv, o[nf]);
            }
        }
        asm volatile("s_waitcnt lgkmcnt(0)" ::: "memory");
#pragma unroll
        for (int nf = 0; nf < 4; nf++)
#pragma unroll
            for (int j = 0; j < 4; j++) {
                int qr = q0 + (lane >> 4) * 4 + j;
                if (qr < TT) {
                    int d = nf * 16 + (lane & 15);
                    h[(size_t)(b * TT + qr) * DD + hh * 64 + d] += o[nf][j] * minv[j];
                }
            }
    }
}

// ---------------------------------------------------------------------------
// LayerNorm (LN2 before MLP1), one row per wave, fp32 in -> bf16 out
// ---------------------------------------------------------------------------
__global__ void ln_kernel(const float* __restrict__ h, const float* __restrict__ g,
                          const float* __restrict__ bt, bf16* __restrict__ hn) {
    const int lane = threadIdx.x & 63, wave = threadIdx.x >> 6;
    const int row = blockIdx.x * 4 + wave;
    const float* x = h + (size_t)row * DD;
    float4 a[3];
#pragma unroll
    for (int i = 0; i < 3; i++) a[i] = ((const float4*)x)[lane + i * 64];
    float sum = 0.0f;
#pragma unroll
    for (int i = 0; i < 3; i++) sum += a[i].x + a[i].y + a[i].z + a[i].w;
#pragma unroll
    for (int dd = 1; dd < 64; dd <<= 1) sum += __shfl_xor(sum, dd);
    const float mu = sum * (1.0f / 768.0f);
    float sq = 0.0f;
#pragma unroll
    for (int i = 0; i < 3; i++) {
        float dx = a[i].x - mu, dy = a[i].y - mu, dz = a[i].z - mu, dw = a[i].w - mu;
        sq += dx * dx + dy * dy + dz * dz + dw * dw;
    }
#pragma unroll
    for (int dd = 1; dd < 64; dd <<= 1) sq += __shfl_xor(sq, dd);
    const float is = rsqrtf(sq * (1.0f / 768.0f) + 1e-5f);
#pragma unroll
    for (int i = 0; i < 3; i++) {
        int c4 = lane + i * 64;
        float4 gg = ((const float4*)g)[c4];
        float4 bb = ((const float4*)bt)[c4];
        bf16x4 o;
        o[0] = (bf16)((a[i].x - mu) * is * gg.x + bb.x);
        o[1] = (bf16)((a[i].y - mu) * is * gg.y + bb.y);
        o[2] = (bf16)((a[i].z - mu) * is * gg.z + bb.z);
        o[3] = (bf16)((a[i].w - mu) * is * gg.w + bb.w);
        ((bf16x4*)(hn + (size_t)row * DD))[c4] = o;
    }
}

// ---------------------------------------------------------------------------
__global__ void patch_extract(const float* __restrict__ x, bf16* __restrict__ p) {
    int idx = blockIdx.x * 256 + threadIdx.x;
    if (idx >= 6272 * 768) return;
    int k = idx % 768, row = idx / 768;
    int c = k % 3, pc = (k / 3) % 16, pr = k / 48;
    int b = row / 196, n = row - b * 196;
    int hp = n / 14, wp = n - hp * 14;
    p[idx] = (bf16)x[((size_t)(b * 3 + c) * 224 + hp * 16 + pr) * 224 + wp * 16 + pc];
}

__global__ void cast_bf16(const float* __restrict__ in, bf16* __restrict__ out, int n4) {
    int i = blockIdx.x * 256 + threadIdx.x;
    int stride = gridDim.x * 256;
    for (; i < n4; i += stride) {
        float4 v = ((const float4*)in)[i];
        bf16x4 o;
        o[0] = (bf16)v.x; o[1] = (bf16)v.y; o[2] = (bf16)v.z; o[3] = (bf16)v.w;
        ((bf16x4*)out)[i] = o;
    }
}

__global__ void cls_init(const float* __restrict__ cls, const float* __restrict__ pos,
                         float* __restrict__ h) {
    int i = blockIdx.x * 256 + threadIdx.x;
    if (i >= BQ * DD) return;
    int b = i / DD, c = i - b * DD;
    h[(size_t)(b * TT) * DD + c] = cls[c] + pos[c];
}

// head over cls rows only; ACCP folds the final MLP2 partial-reduce (+b2)
template <int ACCP>
__global__ void head_kernel(const float* __restrict__ h, const float* __restrict__ part,
                            const float* __restrict__ b2,
                            const float* __restrict__ hw, const float* __restrict__ hb,
                            float* __restrict__ out) {
    __shared__ float xr[DD];
    const int b = blockIdx.y;
    const int n = blockIdx.x * 256 + threadIdx.x;
    const size_t rowoff = (size_t)(b * TT) * DD;
    for (int i = threadIdx.x; i < DD; i += 256) {
        float v = h[rowoff + i];
        if (ACCP) {
            v += part[((size_t)0 * MP + b * TT) * DD + i];
            v += part[((size_t)1 * MP + b * TT) * DD + i];
            v += b2[i];
        }
        xr[i] = v;
    }
    __syncthreads();
    if (n < 1000) {
        float s = hb[n];
        const float4* w = (const float4*)(hw + (size_t)n * DD);
        float acc = 0.0f;
#pragma unroll 4
        for (int k = 0; k < DD / 4; k++) {
            float4 wv = w[k];
            float4 xv = ((const float4*)xr)[k];
            acc += wv.x * xv.x + wv.y * xv.y + wv.z * xv.z + wv.w * xv.w;
        }
        out[b * 1000 + n] = s + acc;
    }
}

// ---------------------------------------------------------------------------
extern "C" void kernel_launch(void* const* d_in, const int* in_sizes, int n_in,
                              void* d_out, int out_size, void* d_ws, size_t ws_size,
                              hipStream_t stream) {
    const float* x       = (const float*)d_in[0];
    const float* patch_w = (const float*)d_in[1];
    const float* patch_b = (const float*)d_in[2];
    const float* pos_enc = (const float*)d_in[3];
    const float* cls_tok = (const float*)d_in[4];
    const float* qkv_w   = (const float*)d_in[5];
    const float* qkv_b   = (const float*)d_in[6];
    const float* ln_g    = (const float*)d_in[7];
    const float* ln_b    = (const float*)d_in[8];
    const float* w1      = (const float*)d_in[9];
    const float* b1      = (const float*)d_in[10];
    const float* w2      = (const float*)d_in[11];
    const float* b2      = (const float*)d_in[12];
    const float* head_w  = (const float*)d_in[13];
    const float* head_b  = (const float*)d_in[14];

    char* wp = (char*)d_ws;
    auto carve = [&](size_t bytes) {
        char* r = wp;
        wp += (bytes + 255) & ~(size_t)255;
        return r;
    };
    auto fits = [&](size_t bytes) {
        return (size_t)(wp - (char*)d_ws) + bytes + 256 <= ws_size;
    };
    float* h  = (float*)carve((size_t)MP * DD * 4);
    bf16* hn  = (bf16*)carve((size_t)MP * DD * 2);
    bf16* u   = (bf16*)carve((size_t)MP * FF * 2);
    bf16* qs  = (bf16*)carve((size_t)BQ * HH * TP * 64 * 2);
    bf16* ks  = (bf16*)carve((size_t)BQ * HH * TP * 64 * 2);
    bf16* vs  = (bf16*)carve((size_t)BQ * HH * TP * 64 * 2);
    bf16* p   = (bf16*)carve((size_t)6272 * DD * 2);
    bf16* pwb = (bf16*)carve((size_t)DD * DD * 2);
    bf16* qwb = (bf16*)carve((size_t)LL * 192 * 64 * 2);

    // split-K partials (NSPLIT x MP x DD fp32), if ws allows
    float* part = nullptr;
    if (fits((size_t)NSPLIT * MP * DD * 4))
        part = (float*)carve((size_t)NSPLIT * MP * DD * 4);
    const bool use_part = (part != nullptr);

    // precast-all weights, if ws allows
    const size_t wfull = (size_t)LL * FF * DD * 2;
    const bool precast = fits(2 * (wfull + 256));
    bf16* w1b = (bf16*)carve(precast ? wfull : (size_t)FF * DD * 2);
    bf16* w2b = (bf16*)carve(precast ? wfull : (size_t)DD * FF * 2);

    cast_bf16<<<512, 256, 0, stream>>>(patch_w, pwb, (DD * DD) / 4);
    cast_bf16<<<144, 256, 0, stream>>>(qkv_w, qwb, (LL * 192 * 64) / 4);
    if (precast) {
        cast_bf16<<<4096, 256, 0, stream>>>(w1, w1b, (LL * FF * DD) / 4);
        cast_bf16<<<4096, 256, 0, stream>>>(w2, w2b, (LL * FF * DD) / 4);
    }
    patch_extract<<<18816, 256, 0, stream>>>(x, p);
    cls_init<<<96, 256, 0, stream>>>(cls_tok, pos_enc, h);
    gemm_bt<0, 1, 768, 768, 6, 49><<<294, 256, 0, stream>>>(p, pwb, patch_b,
                                                            h, nullptr, pos_enc);

    for (int i = 0; i < LL; i++) {
        const bf16* w1i = precast ? (w1b + (size_t)i * FF * DD) : w1b;
        const bf16* w2i = precast ? (w2b + (size_t)i * FF * DD) : w2b;

        // fused LN1 (+ previous layer's MLP2 partial reduction) + QKV
        if (use_part && i > 0)
            lnqkv_kernel<1><<<MR / 16, 256, 0, stream>>>(h, part, b2 + (i - 1) * DD,
                                                         ln_g + i * DD, ln_b + i * DD,
                                                         qwb + i * 192 * 64, qkv_b + i * 192,
                                                         qs, ks, vs);
        else
            lnqkv_kernel<0><<<MR / 16, 256, 0, stream>>>(h, nullptr, nullptr,
                                                         ln_g + i * DD, ln_b + i * DD,
                                                         qwb + i * 192 * 64, qkv_b + i * 192,
                                                         qs, ks, vs);

        attn_kernel<<<BQ * HH * 2, 256, 0, stream>>>(qs, ks, vs, h);
        ln_kernel<<<MP / 4, 256, 0, stream>>>(h, ln_g + i * DD, ln_b + i * DD, hn);
        if (!precast)
            cast_bf16<<<2048, 256, 0, stream>>>(w1 + (size_t)i * FF * DD, w1b, (FF * DD) / 4);
        gemm_bt<1, 1, 768, 3072, 24, 50><<<1200, 256, 0, stream>>>(hn, w1i, b1 + i * FF,
                                                                   nullptr, u, nullptr);
        if (!precast)
            cast_bf16<<<2048, 256, 0, stream>>>(w2 + (size_t)i * FF * DD, w2b, (FF * DD) / 4);
        if (use_part)
            gemm_bt<3, NSPLIT, 3072, 768, 6, 50><<<300 * NSPLIT, 256, 0, stream>>>(
                u, w2i, nullptr, part, nullptr, nullptr);
        else
            gemm_bt<2, 1, 3072, 768, 6, 50><<<300, 256, 0, stream>>>(
                u, w2i, b2 + i * DD, h, nullptr, nullptr);
    }
    if (use_part)
        head_kernel<1><<<dim3(4, BQ), 256, 0, stream>>>(h, part, b2 + 11 * DD,
                                                        head_w, head_b, (float*)d_out);
    else
        head_kernel<0><<<dim3(4, BQ), 256, 0, stream>>>(h, nullptr, nullptr,
                                                        head_w, head_b, (float*)d_out);
}

// Round 11
// 1907.187 us; speedup vs baseline: 1.8896x; 1.0463x over previous
//
#include <hip/hip_runtime.h>
#include <hip/hip_bf16.h>
#include <math.h>

typedef __bf16 bf16;
typedef bf16 bf16x8 __attribute__((ext_vector_type(8)));
typedef bf16 bf16x4 __attribute__((ext_vector_type(4)));
typedef float f32x4 __attribute__((ext_vector_type(4)));

#define BQ 32
#define TT 197
#define DD 768
#define HH 12
#define FF 3072
#define LL 12
#define TP 224
#define MR 6304   // B*T
#define MP 6400   // padded to 50*128
#define KST 72    // K LDS row stride (elements)
#define PST 232   // Vt LDS row stride (elements)
#define PST2 136  // P half-buffer row stride (elements)
#define NSPLIT 2  // MLP2 split-K factor

typedef __attribute__((address_space(1))) const void gv_t;
typedef __attribute__((address_space(3))) void lv_t;

__device__ __forceinline__ void gld16(const void* g, void* l) {
    __builtin_amdgcn_global_load_lds((gv_t*)g, (lv_t*)l, 16, 0, 0);
}

__device__ __forceinline__ f32x4 mfma16(bf16x8 a, bf16x8 b, f32x4 c) {
    return __builtin_amdgcn_mfma_f32_16x16x32_bf16(a, b, c, 0, 0, 0);
}

// tanh-approx GELU via hw v_exp_f32; overflow-safe (e=inf -> th=1)
__device__ __forceinline__ float fast_gelu(float v) {
    float t = 0.79788456080286535588f * v * (1.0f + 0.044715f * v * v);
    float e = __expf(2.0f * t);
    float th = 1.0f - 2.0f / (e + 1.0f);
    return 0.5f * v * (1.0f + th);
}

// bijective XCD swizzle (m204): consecutive wgid stay on one XCD
__device__ __forceinline__ int xcd_swz(int bid, int nwg) {
    int q = nwg >> 3, r = nwg & 7;
    int xcd = bid & 7, pos = bid >> 3;
    int base = (xcd < r) ? xcd * (q + 1) : r * (q + 1) + (xcd - r) * q;
    return base + pos;
}

// ---------------------------------------------------------------------------
// C = A(M,K) @ W(N,K)^T GEMM, 128x128 tile, BK=64, 4 waves, single-buffered
// (m97 structure; r5-proven). Compile-time K/N/geometry; full K-loop unroll.
// XOR swizzle cb^(row&7) on global SOURCE (LDS dest linear), mirrored on the
// ds_read side -> 0 bank conflicts (PMC-verified r4/r5).
// EPI 0: +bias, patch-embed; EPI 1: +bias, GELU->bf16; EPI 2: +bias,
// residual +=; EPI 3: raw partial write (bf16, stride DD).
// ---------------------------------------------------------------------------
template <int EPI, int SPLITK, int KTOT, int NN, int GX, int GY>
__global__ __launch_bounds__(256, 4)
void gemm_bt(const bf16* __restrict__ A, const bf16* __restrict__ W,
             const float* __restrict__ bias,
             float* __restrict__ outF, bf16* __restrict__ outB,
             const float* __restrict__ pos) {
    __shared__ bf16 As[128 * 64];
    __shared__ bf16 Bs[128 * 64];
    const int tid = threadIdx.x;
    const int lane = tid & 63, wave = tid >> 6;
    const int wm = wave >> 1, wn = wave & 1;

    const int wgid = xcd_swz(blockIdx.x, GX * GY * SPLITK);
    const int ks   = (SPLITK > 1) ? wgid / (GX * GY) : 0;
    const int rem  = (SPLITK > 1) ? wgid % (GX * GY) : wgid;
    const int bx = rem % GX, by = rem / GX;
    const int m0 = by * 128, n0 = bx * 128;

    constexpr int kb = KTOT / SPLITK;
    constexpr int nt = kb / 64;
    const int k0 = ks * kb;

    f32x4 acc[4][4] = {};
    const bf16* Ab = A + (size_t)m0 * KTOT;
    const bf16* Wb = W + (size_t)n0 * KTOT;

#pragma unroll
    for (int t = 0; t < nt; ++t) {
        const int kt = k0 + t * 64;
#pragma unroll
        for (int i = 0; i < 4; i++) {
            int idx = i * 256 + tid;
            int row = idx >> 3, cb = idx & 7;
            int gcb = cb ^ (row & 7);   // pre-swizzled source column-block
            gld16(Ab + (size_t)row * KTOT + kt + gcb * 8, As + idx * 8);
            gld16(Wb + (size_t)row * KTOT + kt + gcb * 8, Bs + idx * 8);
        }
        __syncthreads();
        bf16x8 af[4][2], bfr[4][2];
        const int ca = lane >> 4;
#pragma unroll
        for (int f = 0; f < 4; f++) {
            int rowa = wm * 64 + f * 16 + (lane & 15);
            int ma = rowa & 7;
            af[f][0] = *(const bf16x8*)(As + rowa * 64 + ((ca    ) ^ ma) * 8);
            af[f][1] = *(const bf16x8*)(As + rowa * 64 + ((ca + 4) ^ ma) * 8);
            int rowb = wn * 64 + f * 16 + (lane & 15);
            int mb = rowb & 7;
            bfr[f][0] = *(const bf16x8*)(Bs + rowb * 64 + ((ca    ) ^ mb) * 8);
            bfr[f][1] = *(const bf16x8*)(Bs + rowb * 64 + ((ca + 4) ^ mb) * 8);
        }
#pragma unroll
        for (int kh = 0; kh < 2; kh++)
#pragma unroll
            for (int mf = 0; mf < 4; mf++)
#pragma unroll
                for (int nf = 0; nf < 4; nf++)
                    acc[mf][nf] = mfma16(af[mf][kh], bfr[nf][kh], acc[mf][nf]);
        __syncthreads();
    }

    const int r0 = m0 + wm * 64, c0 = n0 + wn * 64;
#pragma unroll
    for (int mf = 0; mf < 4; mf++) {
#pragma unroll
        for (int j = 0; j < 4; j++) {
            int row = r0 + mf * 16 + ((lane >> 4) * 4) + j;
            int pb = 0, pn = 0;
            if (EPI == 0) { pb = row / 196; pn = row - pb * 196; }
#pragma unroll
            for (int nf = 0; nf < 4; nf++) {
                int col = c0 + nf * 16 + (lane & 15);
                float v = acc[mf][nf][j];
                if (EPI == 0) {
                    v += bias[col];
                    float pv = pos[(size_t)(1 + pn) * DD + col];
                    outF[(size_t)(pb * TT + 1 + pn) * DD + col] = v + pv;
                } else if (EPI == 1) {
                    v += bias[col];
                    outB[(size_t)row * NN + col] = (bf16)fast_gelu(v);
                } else if (EPI == 2) {
                    v += bias[col];
                    if (row < MR) outF[(size_t)row * DD + col] += v;
                } else {
                    outB[(size_t)(ks * MP + row) * DD + col] = (bf16)v;
                }
            }
        }
    }
}

// ---------------------------------------------------------------------------
// Fused LN1 + QKV. Grid 394 blocks x 16 bt-rows. Phase 1: (optional) bf16
// partial reduce + b2 + residual -> h, LN -> swizzled 192x64 bf16 A-tile in
// LDS. Phase 2: (192x192x64) MFMA vs qkv_w, scatter to Q/K/V (B*H, 224, 64).
// W staged via gld16 BEFORE phase 1 (latency hidden).
// ---------------------------------------------------------------------------
template <int ACC>
__global__ __launch_bounds__(256, 2)
void lnqkv_kernel(float* __restrict__ h, const bf16* __restrict__ part,
                  const float* __restrict__ b2p,
                  const float* __restrict__ g, const float* __restrict__ bt,
                  const bf16* __restrict__ qw, const float* __restrict__ qb,
                  bf16* __restrict__ Q, bf16* __restrict__ Kb,
                  bf16* __restrict__ Vb) {
    __shared__ bf16 Asm[192 * 64];
    __shared__ bf16 Wsm[192 * 64];
    const int tid = threadIdx.x, lane = tid & 63, wave = tid >> 6;
    const int g0 = blockIdx.x * 16;

    // stage W early; drains at the __syncthreads below
#pragma unroll
    for (int i = 0; i < 6; i++) {
        int idx = i * 256 + tid;
        int row = idx >> 3, cb = idx & 7;
        int gcb = cb ^ (row & 7);
        gld16(qw + (size_t)row * 64 + gcb * 8, Wsm + idx * 8);
    }

    // phase 1: 4 rows per wave; residual+LN -> Asm (swizzled col-blocks)
    for (int r = 0; r < 4; r++) {
        const int row = g0 + wave * 4 + r;
        float* x = h + (size_t)row * DD;
        float4 a[3];
#pragma unroll
        for (int i = 0; i < 3; i++) a[i] = ((const float4*)x)[lane + i * 64];
        if (ACC) {
#pragma unroll
            for (int s = 0; s < NSPLIT; s++) {
                const bf16x4* ps = (const bf16x4*)(part + ((size_t)s * MP + row) * DD);
#pragma unroll
                for (int i = 0; i < 3; i++) {
                    bf16x4 p = ps[lane + i * 64];
                    a[i].x += (float)p[0]; a[i].y += (float)p[1];
                    a[i].z += (float)p[2]; a[i].w += (float)p[3];
                }
            }
#pragma unroll
            for (int i = 0; i < 3; i++) {
                float4 bb = ((const float4*)b2p)[lane + i * 64];
                a[i].x += bb.x; a[i].y += bb.y; a[i].z += bb.z; a[i].w += bb.w;
                ((float4*)x)[lane + i * 64] = a[i];
            }
        }
        float sum = 0.0f;
#pragma unroll
        for (int i = 0; i < 3; i++) sum += a[i].x + a[i].y + a[i].z + a[i].w;
#pragma unroll
        for (int dd = 1; dd < 64; dd <<= 1) sum += __shfl_xor(sum, dd);
        const float mu = sum * (1.0f / 768.0f);
        float sq = 0.0f;
#pragma unroll
        for (int i = 0; i < 3; i++) {
            float dx = a[i].x - mu, dy = a[i].y - mu, dz = a[i].z - mu, dw = a[i].w - mu;
            sq += dx * dx + dy * dy + dz * dz + dw * dw;
        }
#pragma unroll
        for (int dd = 1; dd < 64; dd <<= 1) sq += __shfl_xor(sq, dd);
        const float is = rsqrtf(sq * (1.0f / 768.0f) + 1e-5f);
#pragma unroll
        for (int i = 0; i < 3; i++) {
            int c4 = lane + i * 64;
            float4 gg = ((const float4*)g)[c4];
            float4 bb = ((const float4*)bt)[c4];
            bf16x4 o;
            o[0] = (bf16)((a[i].x - mu) * is * gg.x + bb.x);
            o[1] = (bf16)((a[i].y - mu) * is * gg.y + bb.y);
            o[2] = (bf16)((a[i].z - mu) * is * gg.z + bb.z);
            o[3] = (bf16)((a[i].w - mu) * is * gg.w + bb.w);
            int col = c4 * 4;
            int arow = (row - g0) * 12 + (col >> 6);
            int acol = col & 63;
            int scol = (((acol >> 3) ^ (arow & 7)) << 3) + (acol & 7);
            *(bf16x4*)(Asm + arow * 64 + scol) = o;
        }
    }
    __syncthreads();   // drains W gld16 (vmcnt) + Asm writes (lgkm)

    // phase 2: QKV MFMA, 3 m-frags x 12 n-frags per wave
    const int ca = lane >> 4;
    bf16x8 af[3][2];
#pragma unroll
    for (int mf = 0; mf < 3; mf++) {
        int row = wave * 48 + mf * 16 + (lane & 15);
        int m7 = row & 7;
        af[mf][0] = *(const bf16x8*)(Asm + row * 64 + ((ca    ) ^ m7) * 8);
        af[mf][1] = *(const bf16x8*)(Asm + row * 64 + ((ca + 4) ^ m7) * 8);
    }
    f32x4 acc[3][12] = {};
#pragma unroll
    for (int nf = 0; nf < 12; nf++) {
        int row = nf * 16 + (lane & 15);
        int m7 = row & 7;
        bf16x8 b0 = *(const bf16x8*)(Wsm + row * 64 + ((ca    ) ^ m7) * 8);
        bf16x8 b1 = *(const bf16x8*)(Wsm + row * 64 + ((ca + 4) ^ m7) * 8);
#pragma unroll
        for (int mf = 0; mf < 3; mf++) {
            acc[mf][nf] = mfma16(af[mf][0], b0, acc[mf][nf]);
            acc[mf][nf] = mfma16(af[mf][1], b1, acc[mf][nf]);
        }
    }
    const int r0 = blockIdx.x * 192 + wave * 48;
#pragma unroll
    for (int mf = 0; mf < 3; mf++)
#pragma unroll
        for (int j = 0; j < 4; j++) {
            int r = r0 + mf * 16 + (lane >> 4) * 4 + j;
            int btq = r / 12, hh = r - btq * 12;
            int b = btq / 197, t = btq - b * 197;
            size_t dbase = ((size_t)(b * HH + hh) * TP + t) * 64;
#pragma unroll
            for (int nf = 0; nf < 12; nf++) {
                int col = nf * 16 + (lane & 15);
                float v = acc[mf][nf][j] + qb[col];
                int sel = nf >> 2, e = col & 63;
                bf16* dst = (sel == 0) ? Q : (sel == 1 ? Kb : Vb);
                dst[dbase + e] = (bf16)v;
            }
        }
}

// ---------------------------------------------------------------------------
// Fused attention: block = (b,h,half); 768 blocks. LDS 79.4 KB -> 2 blocks/CU.
// PV split into two k-halves reusing a per-wave 16x136 P buffer; P stored
// unnormalized, o scaled by 1/sum post-PV. (r9-proven)
// ---------------------------------------------------------------------------
__global__ __launch_bounds__(256, 2)
void attn_kernel(const bf16* __restrict__ Q, const bf16* __restrict__ Kg,
                 const bf16* __restrict__ Vg, float* __restrict__ h) {
    __shared__ bf16 Ks[TP * KST];
    __shared__ bf16 Vt[64 * PST];
    __shared__ bf16 Pw[4 * 16 * PST2];
    const int tid = threadIdx.x, lane = tid & 63, wave = tid >> 6;
    const int bh = blockIdx.x >> 1, sub = blockIdx.x & 1;
    const int b = bh / HH, hh = bh - b * HH;
    const bf16* Kp = Kg + (size_t)bh * TP * 64;
    const bf16* Vp = Vg + (size_t)bh * TP * 64;
    const bf16* Qp = Q + (size_t)bh * TP * 64;

#pragma unroll
    for (int i = 0; i < 7; i++) {
        int idx = i * 256 + tid;
        int row = idx >> 3, cb = idx & 7;
        bf16x8 kv = *(const bf16x8*)(Kp + idx * 8);
        *(bf16x8*)(Ks + row * KST + cb * 8) = kv;
        bf16x8 vv = *(const bf16x8*)(Vp + idx * 8);
#pragma unroll
        for (int j = 0; j < 8; j++) Vt[(cb * 8 + j) * PST + row] = vv[j];
    }
    __syncthreads();

    bf16* Pm = Pw + wave * 16 * PST2;
    const int cEnd = sub ? 13 : 7;
    for (int ch = sub * 7 + wave; ch < cEnd; ch += 4) {
        const int q0 = ch * 16;
        const bf16* qp = Qp + (q0 + (lane & 15)) * 64 + (lane >> 4) * 8;
        bf16x8 aq0 = *(const bf16x8*)qp;
        bf16x8 aq1 = *(const bf16x8*)(qp + 32);
        f32x4 s[14] = {};
#pragma unroll
        for (int nf = 0; nf < 14; nf++) {
            int rb = (nf * 16 + (lane & 15)) * KST + (lane >> 4) * 8;
            bf16x8 b0 = *(const bf16x8*)(Ks + rb);
            bf16x8 b1 = *(const bf16x8*)(Ks + rb + 32);
            s[nf] = mfma16(aq0, b0, s[nf]);
            s[nf] = mfma16(aq1, b1, s[nf]);
        }
        const int colbase = lane & 15;
        float mmax[4], minv[4];
#pragma unroll
        for (int j = 0; j < 4; j++) {
            float m = -1e30f;
#pragma unroll
            for (int nf = 0; nf < 14; nf++) {
                int col = nf * 16 + colbase;
                float v = (col < TT) ? s[nf][j] * 0.125f : -1e30f;
                m = fmaxf(m, v);
            }
#pragma unroll
            for (int dd = 1; dd < 16; dd <<= 1) m = fmaxf(m, __shfl_xor(m, dd));
            float sum = 0.0f;
#pragma unroll
            for (int nf = 0; nf < 14; nf++) {
                int col = nf * 16 + colbase;
                float v = (col < TT) ? s[nf][j] * 0.125f : -1e30f;
                sum += __expf(v - m);
            }
#pragma unroll
            for (int dd = 1; dd < 16; dd <<= 1) sum += __shfl_xor(sum, dd);
            mmax[j] = m;
            minv[j] = 1.0f / sum;
        }
        f32x4 o[4] = {};
#pragma unroll
        for (int j = 0; j < 4; j++) {
            int pr = (lane >> 4) * 4 + j;
#pragma unroll
            for (int nf = 0; nf < 8; nf++) {
                int col = nf * 16 + colbase;
                float v = (col < TT) ? s[nf][j] * 0.125f : -1e30f;
                Pm[pr * PST2 + nf * 16 + colbase] = (bf16)__expf(v - mmax[j]);
            }
        }
        asm volatile("s_waitcnt lgkmcnt(0)" ::: "memory");
#pragma unroll
        for (int ks = 0; ks < 4; ks++) {
            bf16x8 pa = *(const bf16x8*)(Pm + (lane & 15) * PST2 + ks * 32 + (lane >> 4) * 8);
#pragma unroll
            for (int nf = 0; nf < 4; nf++) {
                bf16x8 bv = *(const bf16x8*)(Vt + (nf * 16 + (lane & 15)) * PST + ks * 32 + (lane >> 4) * 8);
                o[nf] = mfma16(pa, bv, o[nf]);
            }
        }
        asm volatile("s_waitcnt lgkmcnt(0)" ::: "memory");
#pragma unroll
        for (int j = 0; j < 4; j++) {
            int pr = (lane >> 4) * 4 + j;
#pragma unroll
            for (int nf = 8; nf < 14; nf++) {
                int col = nf * 16 + colbase;
                float v = (col < TT) ? s[nf][j] * 0.125f : -1e30f;
                Pm[pr * PST2 + (nf - 8) * 16 + colbase] = (bf16)__expf(v - mmax[j]);
            }
        }
        asm volatile("s_waitcnt lgkmcnt(0)" ::: "memory");
#pragma unroll
        for (int ks = 4; ks < 7; ks++) {
            bf16x8 pa = *(const bf16x8*)(Pm + (lane & 15) * PST2 + (ks - 4) * 32 + (lane >> 4) * 8);
#pragma unroll
            for (int nf = 0; nf < 4; nf++) {
                bf16x8 bv = *(const bf16x8*)(Vt + (nf * 16 + (lane & 15)) * PST + ks * 32 + (lane >> 4) * 8);
                o[nf] = mfma16(pa, bv, o[nf]);
            }
        }
        asm volatile("s_waitcnt lgkmcnt(0)" ::: "memory");
#pragma unroll
        for (int nf = 0; nf < 4; nf++)
#pragma unroll
            for (int j = 0; j < 4; j++) {
                int qr = q0 + (lane >> 4) * 4 + j;
                if (qr < TT) {
                    int d = nf * 16 + (lane & 15);
                    h[(size_t)(b * TT + qr) * DD + hh * 64 + d] += o[nf][j] * minv[j];
                }
            }
    }
}

// ---------------------------------------------------------------------------
// LayerNorm (LN2 before MLP1), one row per wave, fp32 in -> bf16 out
// ---------------------------------------------------------------------------
__global__ void ln_kernel(const float* __restrict__ h, const float* __restrict__ g,
                          const float* __restrict__ bt, bf16* __restrict__ hn) {
    const int lane = threadIdx.x & 63, wave = threadIdx.x >> 6;
    const int row = blockIdx.x * 4 + wave;
    const float* x = h + (size_t)row * DD;
    float4 a[3];
#pragma unroll
    for (int i = 0; i < 3; i++) a[i] = ((const float4*)x)[lane + i * 64];
    float sum = 0.0f;
#pragma unroll
    for (int i = 0; i < 3; i++) sum += a[i].x + a[i].y + a[i].z + a[i].w;
#pragma unroll
    for (int dd = 1; dd < 64; dd <<= 1) sum += __shfl_xor(sum, dd);
    const float mu = sum * (1.0f / 768.0f);
    float sq = 0.0f;
#pragma unroll
    for (int i = 0; i < 3; i++) {
        float dx = a[i].x - mu, dy = a[i].y - mu, dz = a[i].z - mu, dw = a[i].w - mu;
        sq += dx * dx + dy * dy + dz * dz + dw * dw;
    }
#pragma unroll
    for (int dd = 1; dd < 64; dd <<= 1) sq += __shfl_xor(sq, dd);
    const float is = rsqrtf(sq * (1.0f / 768.0f) + 1e-5f);
#pragma unroll
    for (int i = 0; i < 3; i++) {
        int c4 = lane + i * 64;
        float4 gg = ((const float4*)g)[c4];
        float4 bb = ((const float4*)bt)[c4];
        bf16x4 o;
        o[0] = (bf16)((a[i].x - mu) * is * gg.x + bb.x);
        o[1] = (bf16)((a[i].y - mu) * is * gg.y + bb.y);
        o[2] = (bf16)((a[i].z - mu) * is * gg.z + bb.z);
        o[3] = (bf16)((a[i].w - mu) * is * gg.w + bb.w);
        ((bf16x4*)(hn + (size_t)row * DD))[c4] = o;
    }
}

// ---------------------------------------------------------------------------
__global__ void patch_extract(const float* __restrict__ x, bf16* __restrict__ p) {
    int idx = blockIdx.x * 256 + threadIdx.x;
    if (idx >= 6272 * 768) return;
    int k = idx % 768, row = idx / 768;
    int c = k % 3, pc = (k / 3) % 16, pr = k / 48;
    int b = row / 196, n = row - b * 196;
    int hp = n / 14, wp = n - hp * 14;
    p[idx] = (bf16)x[((size_t)(b * 3 + c) * 224 + hp * 16 + pr) * 224 + wp * 16 + pc];
}

// dual-range cast: [0,n4a) -> oa, [n4a, n4a+n4b) -> ob
__global__ void cast2_bf16(const float* __restrict__ ia, bf16* __restrict__ oa,
                           const float* __restrict__ ib, bf16* __restrict__ ob,
                           int n4a, int n4b) {
    int i = blockIdx.x * 256 + threadIdx.x;
    int stride = gridDim.x * 256;
    for (; i < n4a + n4b; i += stride) {
        const float4* src = (i < n4a) ? (const float4*)ia + i
                                      : (const float4*)ib + (i - n4a);
        bf16x4* dst = (i < n4a) ? (bf16x4*)oa + i : (bf16x4*)ob + (i - n4a);
        float4 v = *src;
        bf16x4 o;
        o[0] = (bf16)v.x; o[1] = (bf16)v.y; o[2] = (bf16)v.z; o[3] = (bf16)v.w;
        *dst = o;
    }
}

__global__ void cast_bf16(const float* __restrict__ in, bf16* __restrict__ out, int n4) {
    int i = blockIdx.x * 256 + threadIdx.x;
    int stride = gridDim.x * 256;
    for (; i < n4; i += stride) {
        float4 v = ((const float4*)in)[i];
        bf16x4 o;
        o[0] = (bf16)v.x; o[1] = (bf16)v.y; o[2] = (bf16)v.z; o[3] = (bf16)v.w;
        ((bf16x4*)out)[i] = o;
    }
}

__global__ void cls_init(const float* __restrict__ cls, const float* __restrict__ pos,
                         float* __restrict__ h) {
    int i = blockIdx.x * 256 + threadIdx.x;
    if (i >= BQ * DD) return;
    int b = i / DD, c = i - b * DD;
    h[(size_t)(b * TT) * DD + c] = cls[c] + pos[c];
}

// head over cls rows only; ACCP folds the final MLP2 bf16-partial reduce (+b2)
template <int ACCP>
__global__ void head_kernel(const float* __restrict__ h, const bf16* __restrict__ part,
                            const float* __restrict__ b2,
                            const float* __restrict__ hw, const float* __restrict__ hb,
                            float* __restrict__ out) {
    __shared__ float xr[DD];
    const int b = blockIdx.y;
    const int n = blockIdx.x * 256 + threadIdx.x;
    const size_t rowoff = (size_t)(b * TT) * DD;
    for (int i = threadIdx.x; i < DD; i += 256) {
        float v = h[rowoff + i];
        if (ACCP) {
            v += (float)part[((size_t)0 * MP + b * TT) * DD + i];
            v += (float)part[((size_t)1 * MP + b * TT) * DD + i];
            v += b2[i];
        }
        xr[i] = v;
    }
    __syncthreads();
    if (n < 1000) {
        float s = hb[n];
        const float4* w = (const float4*)(hw + (size_t)n * DD);
        float acc = 0.0f;
#pragma unroll 4
        for (int k = 0; k < DD / 4; k++) {
            float4 wv = w[k];
            float4 xv = ((const float4*)xr)[k];
            acc += wv.x * xv.x + wv.y * xv.y + wv.z * xv.z + wv.w * xv.w;
        }
        out[b * 1000 + n] = s + acc;
    }
}

// ---------------------------------------------------------------------------
extern "C" void kernel_launch(void* const* d_in, const int* in_sizes, int n_in,
                              void* d_out, int out_size, void* d_ws, size_t ws_size,
                              hipStream_t stream) {
    const float* x       = (const float*)d_in[0];
    const float* patch_w = (const float*)d_in[1];
    const float* patch_b = (const float*)d_in[2];
    const float* pos_enc = (const float*)d_in[3];
    const float* cls_tok = (const float*)d_in[4];
    const float* qkv_w   = (const float*)d_in[5];
    const float* qkv_b   = (const float*)d_in[6];
    const float* ln_g    = (const float*)d_in[7];
    const float* ln_b    = (const float*)d_in[8];
    const float* w1      = (const float*)d_in[9];
    const float* b1      = (const float*)d_in[10];
    const float* w2      = (const float*)d_in[11];
    const float* b2      = (const float*)d_in[12];
    const float* head_w  = (const float*)d_in[13];
    const float* head_b  = (const float*)d_in[14];

    char* wp = (char*)d_ws;
    auto carve = [&](size_t bytes) {
        char* r = wp;
        wp += (bytes + 255) & ~(size_t)255;
        return r;
    };
    auto fits = [&](size_t bytes) {
        return (size_t)(wp - (char*)d_ws) + bytes + 256 <= ws_size;
    };
    float* h  = (float*)carve((size_t)MP * DD * 4);
    bf16* hn  = (bf16*)carve((size_t)MP * DD * 2);
    bf16* u   = (bf16*)carve((size_t)MP * FF * 2);
    bf16* qs  = (bf16*)carve((size_t)BQ * HH * TP * 64 * 2);
    bf16* ks  = (bf16*)carve((size_t)BQ * HH * TP * 64 * 2);
    bf16* vs  = (bf16*)carve((size_t)BQ * HH * TP * 64 * 2);
    bf16* p   = (bf16*)carve((size_t)6272 * DD * 2);
    bf16* pwb = (bf16*)carve((size_t)DD * DD * 2);
    bf16* qwb = (bf16*)carve((size_t)LL * 192 * 64 * 2);

    // split-K partials (NSPLIT x MP x DD bf16), if ws allows
    bf16* part = nullptr;
    if (fits((size_t)NSPLIT * MP * DD * 2))
        part = (bf16*)carve((size_t)NSPLIT * MP * DD * 2);
    const bool use_part = (part != nullptr);

    // precast-all weights, if ws allows
    const size_t wfull = (size_t)LL * FF * DD * 2;
    const bool precast = fits(2 * (wfull + 256));
    bf16* w1b = (bf16*)carve(precast ? wfull : (size_t)FF * DD * 2);
    bf16* w2b = (bf16*)carve(precast ? wfull : (size_t)DD * FF * 2);

    cast2_bf16<<<720, 256, 0, stream>>>(patch_w, pwb, qkv_w, qwb,
                                        (DD * DD) / 4, (LL * 192 * 64) / 4);
    if (precast) {
        cast2_bf16<<<8192, 256, 0, stream>>>(w1, w1b, w2, w2b,
                                             (LL * FF * DD) / 4, (LL * FF * DD) / 4);
    }
    patch_extract<<<18816, 256, 0, stream>>>(x, p);
    cls_init<<<96, 256, 0, stream>>>(cls_tok, pos_enc, h);
    gemm_bt<0, 1, 768, 768, 6, 49><<<294, 256, 0, stream>>>(p, pwb, patch_b,
                                                            h, nullptr, pos_enc);

    for (int i = 0; i < LL; i++) {
        const bf16* w1i = precast ? (w1b + (size_t)i * FF * DD) : w1b;
        const bf16* w2i = precast ? (w2b + (size_t)i * FF * DD) : w2b;

        // fused LN1 (+ previous layer's MLP2 bf16-partial reduction) + QKV
        if (use_part && i > 0)
            lnqkv_kernel<1><<<MR / 16, 256, 0, stream>>>(h, part, b2 + (i - 1) * DD,
                                                         ln_g + i * DD, ln_b + i * DD,
                                                         qwb + i * 192 * 64, qkv_b + i * 192,
                                                         qs, ks, vs);
        else
            lnqkv_kernel<0><<<MR / 16, 256, 0, stream>>>(h, nullptr, nullptr,
                                                         ln_g + i * DD, ln_b + i * DD,
                                                         qwb + i * 192 * 64, qkv_b + i * 192,
                                                         qs, ks, vs);

        attn_kernel<<<BQ * HH * 2, 256, 0, stream>>>(qs, ks, vs, h);
        ln_kernel<<<MP / 4, 256, 0, stream>>>(h, ln_g + i * DD, ln_b + i * DD, hn);
        if (!precast)
            cast_bf16<<<2048, 256, 0, stream>>>(w1 + (size_t)i * FF * DD, w1b, (FF * DD) / 4);
        gemm_bt<1, 1, 768, 3072, 24, 50><<<1200, 256, 0, stream>>>(hn, w1i, b1 + i * FF,
                                                                   nullptr, u, nullptr);
        if (!precast)
            cast_bf16<<<2048, 256, 0, stream>>>(w2 + (size_t)i * FF * DD, w2b, (FF * DD) / 4);
        if (use_part)
            gemm_bt<3, NSPLIT, 3072, 768, 6, 50><<<300 * NSPLIT, 256, 0, stream>>>(
                u, w2i, nullptr, nullptr, part, nullptr);
        else
            gemm_bt<2, 1, 3072, 768, 6, 50><<<300, 256, 0, stream>>>(
                u, w2i, b2 + i * DD, h, nullptr, nullptr);
    }
    if (use_part)
        head_kernel<1><<<dim3(4, BQ), 256, 0, stream>>>(h, part, b2 + 11 * DD,
                                                        head_w, head_b, (float*)d_out);
    else
        head_kernel<0><<<dim3(4, BQ), 256, 0, stream>>>(h, nullptr, nullptr,
                                                        head_w, head_b, (float*)d_out);
}

// Round 12
// 1898.079 us; speedup vs baseline: 1.8987x; 1.0048x over previous
//
#include <hip/hip_runtime.h>
#include <hip/hip_bf16.h>
#include <math.h>

typedef __bf16 bf16;
typedef bf16 bf16x8 __attribute__((ext_vector_type(8)));
typedef bf16 bf16x4 __attribute__((ext_vector_type(4)));
typedef float f32x4 __attribute__((ext_vector_type(4)));

#define BQ 32
#define TT 197
#define DD 768
#define HH 12
#define FF 3072
#define LL 12
#define TP 224
#define MR 6304   // B*T
#define MP 6400   // padded to 50*128
#define KST 72    // K LDS row stride (elements)
#define PST 232   // Vt LDS row stride (elements)
#define PST2 136  // P half-buffer row stride (elements)
#define NSPLIT 2  // MLP2 split-K factor

typedef __attribute__((address_space(1))) const void gv_t;
typedef __attribute__((address_space(3))) void lv_t;

__device__ __forceinline__ void gld16(const void* g, void* l) {
    __builtin_amdgcn_global_load_lds((gv_t*)g, (lv_t*)l, 16, 0, 0);
}

__device__ __forceinline__ f32x4 mfma16(bf16x8 a, bf16x8 b, f32x4 c) {
    return __builtin_amdgcn_mfma_f32_16x16x32_bf16(a, b, c, 0, 0, 0);
}

// tanh-approx GELU via hw v_exp_f32; overflow-safe (e=inf -> th=1)
__device__ __forceinline__ float fast_gelu(float v) {
    float t = 0.79788456080286535588f * v * (1.0f + 0.044715f * v * v);
    float e = __expf(2.0f * t);
    float th = 1.0f - 2.0f / (e + 1.0f);
    return 0.5f * v * (1.0f + th);
}

// bijective XCD swizzle (m204): consecutive wgid stay on one XCD
__device__ __forceinline__ int xcd_swz(int bid, int nwg) {
    int q = nwg >> 3, r = nwg & 7;
    int xcd = bid & 7, pos = bid >> 3;
    int base = (xcd < r) ? xcd * (q + 1) : r * (q + 1) + (xcd - r) * q;
    return base + pos;
}

// ---------------------------------------------------------------------------
// C = A(M,K) @ W(N,K)^T GEMM, 128x128 tile, BK=64, 4 waves, single-buffered
// (m97 structure; r5-proven). Compile-time K/N/geometry; full K-loop unroll.
// XOR swizzle cb^(row&7) on global SOURCE (LDS dest linear), mirrored on the
// ds_read side -> 0 bank conflicts (PMC-verified r4/r5).
// EPI 0: +bias, patch-embed; EPI 1: +bias, GELU->bf16; EPI 2: +bias,
// residual +=; EPI 3: raw partial write (bf16, stride DD).
// ---------------------------------------------------------------------------
template <int EPI, int SPLITK, int KTOT, int NN, int GX, int GY>
__global__ __launch_bounds__(256, 4)
void gemm_bt(const bf16* __restrict__ A, const bf16* __restrict__ W,
             const float* __restrict__ bias,
             float* __restrict__ outF, bf16* __restrict__ outB,
             const float* __restrict__ pos) {
    __shared__ bf16 As[128 * 64];
    __shared__ bf16 Bs[128 * 64];
    const int tid = threadIdx.x;
    const int lane = tid & 63, wave = tid >> 6;
    const int wm = wave >> 1, wn = wave & 1;

    const int wgid = xcd_swz(blockIdx.x, GX * GY * SPLITK);
    const int ks   = (SPLITK > 1) ? wgid / (GX * GY) : 0;
    const int rem  = (SPLITK > 1) ? wgid % (GX * GY) : wgid;
    const int bx = rem % GX, by = rem / GX;
    const int m0 = by * 128, n0 = bx * 128;

    constexpr int kb = KTOT / SPLITK;
    constexpr int nt = kb / 64;
    const int k0 = ks * kb;

    f32x4 acc[4][4] = {};
    const bf16* Ab = A + (size_t)m0 * KTOT;
    const bf16* Wb = W + (size_t)n0 * KTOT;

#pragma unroll
    for (int t = 0; t < nt; ++t) {
        const int kt = k0 + t * 64;
#pragma unroll
        for (int i = 0; i < 4; i++) {
            int idx = i * 256 + tid;
            int row = idx >> 3, cb = idx & 7;
            int gcb = cb ^ (row & 7);   // pre-swizzled source column-block
            gld16(Ab + (size_t)row * KTOT + kt + gcb * 8, As + idx * 8);
            gld16(Wb + (size_t)row * KTOT + kt + gcb * 8, Bs + idx * 8);
        }
        __syncthreads();
        bf16x8 af[4][2], bfr[4][2];
        const int ca = lane >> 4;
#pragma unroll
        for (int f = 0; f < 4; f++) {
            int rowa = wm * 64 + f * 16 + (lane & 15);
            int ma = rowa & 7;
            af[f][0] = *(const bf16x8*)(As + rowa * 64 + ((ca    ) ^ ma) * 8);
            af[f][1] = *(const bf16x8*)(As + rowa * 64 + ((ca + 4) ^ ma) * 8);
            int rowb = wn * 64 + f * 16 + (lane & 15);
            int mb = rowb & 7;
            bfr[f][0] = *(const bf16x8*)(Bs + rowb * 64 + ((ca    ) ^ mb) * 8);
            bfr[f][1] = *(const bf16x8*)(Bs + rowb * 64 + ((ca + 4) ^ mb) * 8);
        }
#pragma unroll
        for (int kh = 0; kh < 2; kh++)
#pragma unroll
            for (int mf = 0; mf < 4; mf++)
#pragma unroll
                for (int nf = 0; nf < 4; nf++)
                    acc[mf][nf] = mfma16(af[mf][kh], bfr[nf][kh], acc[mf][nf]);
        __syncthreads();
    }

    const int r0 = m0 + wm * 64, c0 = n0 + wn * 64;
#pragma unroll
    for (int mf = 0; mf < 4; mf++) {
#pragma unroll
        for (int j = 0; j < 4; j++) {
            int row = r0 + mf * 16 + ((lane >> 4) * 4) + j;
            int pb = 0, pn = 0;
            if (EPI == 0) { pb = row / 196; pn = row - pb * 196; }
#pragma unroll
            for (int nf = 0; nf < 4; nf++) {
                int col = c0 + nf * 16 + (lane & 15);
                float v = acc[mf][nf][j];
                if (EPI == 0) {
                    v += bias[col];
                    float pv = pos[(size_t)(1 + pn) * DD + col];
                    outF[(size_t)(pb * TT + 1 + pn) * DD + col] = v + pv;
                } else if (EPI == 1) {
                    v += bias[col];
                    outB[(size_t)row * NN + col] = (bf16)fast_gelu(v);
                } else if (EPI == 2) {
                    v += bias[col];
                    if (row < MR) outF[(size_t)row * DD + col] += v;
                } else {
                    outB[(size_t)(ks * MP + row) * DD + col] = (bf16)v;
                }
            }
        }
    }
}

// ---------------------------------------------------------------------------
// Fused LN1 + QKV. Grid 394 blocks x 16 bt-rows. Phase 1: (optional) bf16
// partial reduce + b2 + residual -> h, LN -> swizzled 192x64 bf16 A-tile in
// LDS. Phase 2: (192x192x64) MFMA vs qkv_w, scatter to Q/K/V (B*H, 224, 64).
// W staged via gld16 BEFORE phase 1 (latency hidden).
// ---------------------------------------------------------------------------
template <int ACC>
__global__ __launch_bounds__(256, 2)
void lnqkv_kernel(float* __restrict__ h, const bf16* __restrict__ part,
                  const float* __restrict__ b2p,
                  const float* __restrict__ g, const float* __restrict__ bt,
                  const bf16* __restrict__ qw, const float* __restrict__ qb,
                  bf16* __restrict__ Q, bf16* __restrict__ Kb,
                  bf16* __restrict__ Vb) {
    __shared__ bf16 Asm[192 * 64];
    __shared__ bf16 Wsm[192 * 64];
    const int tid = threadIdx.x, lane = tid & 63, wave = tid >> 6;
    const int g0 = blockIdx.x * 16;

    // stage W early; drains at the __syncthreads below
#pragma unroll
    for (int i = 0; i < 6; i++) {
        int idx = i * 256 + tid;
        int row = idx >> 3, cb = idx & 7;
        int gcb = cb ^ (row & 7);
        gld16(qw + (size_t)row * 64 + gcb * 8, Wsm + idx * 8);
    }

    // phase 1: 4 rows per wave; residual+LN -> Asm (swizzled col-blocks)
    for (int r = 0; r < 4; r++) {
        const int row = g0 + wave * 4 + r;
        float* x = h + (size_t)row * DD;
        float4 a[3];
#pragma unroll
        for (int i = 0; i < 3; i++) a[i] = ((const float4*)x)[lane + i * 64];
        if (ACC) {
#pragma unroll
            for (int s = 0; s < NSPLIT; s++) {
                const bf16x4* ps = (const bf16x4*)(part + ((size_t)s * MP + row) * DD);
#pragma unroll
                for (int i = 0; i < 3; i++) {
                    bf16x4 p = ps[lane + i * 64];
                    a[i].x += (float)p[0]; a[i].y += (float)p[1];
                    a[i].z += (float)p[2]; a[i].w += (float)p[3];
                }
            }
#pragma unroll
            for (int i = 0; i < 3; i++) {
                float4 bb = ((const float4*)b2p)[lane + i * 64];
                a[i].x += bb.x; a[i].y += bb.y; a[i].z += bb.z; a[i].w += bb.w;
                ((float4*)x)[lane + i * 64] = a[i];
            }
        }
        float sum = 0.0f;
#pragma unroll
        for (int i = 0; i < 3; i++) sum += a[i].x + a[i].y + a[i].z + a[i].w;
#pragma unroll
        for (int dd = 1; dd < 64; dd <<= 1) sum += __shfl_xor(sum, dd);
        const float mu = sum * (1.0f / 768.0f);
        float sq = 0.0f;
#pragma unroll
        for (int i = 0; i < 3; i++) {
            float dx = a[i].x - mu, dy = a[i].y - mu, dz = a[i].z - mu, dw = a[i].w - mu;
            sq += dx * dx + dy * dy + dz * dz + dw * dw;
        }
#pragma unroll
        for (int dd = 1; dd < 64; dd <<= 1) sq += __shfl_xor(sq, dd);
        const float is = rsqrtf(sq * (1.0f / 768.0f) + 1e-5f);
#pragma unroll
        for (int i = 0; i < 3; i++) {
            int c4 = lane + i * 64;
            float4 gg = ((const float4*)g)[c4];
            float4 bb = ((const float4*)bt)[c4];
            bf16x4 o;
            o[0] = (bf16)((a[i].x - mu) * is * gg.x + bb.x);
            o[1] = (bf16)((a[i].y - mu) * is * gg.y + bb.y);
            o[2] = (bf16)((a[i].z - mu) * is * gg.z + bb.z);
            o[3] = (bf16)((a[i].w - mu) * is * gg.w + bb.w);
            int col = c4 * 4;
            int arow = (row - g0) * 12 + (col >> 6);
            int acol = col & 63;
            int scol = (((acol >> 3) ^ (arow & 7)) << 3) + (acol & 7);
            *(bf16x4*)(Asm + arow * 64 + scol) = o;
        }
    }
    __syncthreads();   // drains W gld16 (vmcnt) + Asm writes (lgkm)

    // phase 2: QKV MFMA, 3 m-frags x 12 n-frags per wave
    const int ca = lane >> 4;
    bf16x8 af[3][2];
#pragma unroll
    for (int mf = 0; mf < 3; mf++) {
        int row = wave * 48 + mf * 16 + (lane & 15);
        int m7 = row & 7;
        af[mf][0] = *(const bf16x8*)(Asm + row * 64 + ((ca    ) ^ m7) * 8);
        af[mf][1] = *(const bf16x8*)(Asm + row * 64 + ((ca + 4) ^ m7) * 8);
    }
    f32x4 acc[3][12] = {};
#pragma unroll
    for (int nf = 0; nf < 12; nf++) {
        int row = nf * 16 + (lane & 15);
        int m7 = row & 7;
        bf16x8 b0 = *(const bf16x8*)(Wsm + row * 64 + ((ca    ) ^ m7) * 8);
        bf16x8 b1 = *(const bf16x8*)(Wsm + row * 64 + ((ca + 4) ^ m7) * 8);
#pragma unroll
        for (int mf = 0; mf < 3; mf++) {
            acc[mf][nf] = mfma16(af[mf][0], b0, acc[mf][nf]);
            acc[mf][nf] = mfma16(af[mf][1], b1, acc[mf][nf]);
        }
    }
    const int r0 = blockIdx.x * 192 + wave * 48;
#pragma unroll
    for (int mf = 0; mf < 3; mf++)
#pragma unroll
        for (int j = 0; j < 4; j++) {
            int r = r0 + mf * 16 + (lane >> 4) * 4 + j;
            int btq = r / 12, hh = r - btq * 12;
            int b = btq / 197, t = btq - b * 197;
            size_t dbase = ((size_t)(b * HH + hh) * TP + t) * 64;
#pragma unroll
            for (int nf = 0; nf < 12; nf++) {
                int col = nf * 16 + (lane & 15);
                float v = acc[mf][nf][j] + qb[col];
                int sel = nf >> 2, e = col & 63;
                bf16* dst = (sel == 0) ? Q : (sel == 1 ? Kb : Vb);
                dst[dbase + e] = (bf16)v;
            }
        }
}

// ---------------------------------------------------------------------------
// Fused attention: block = (b,h,half); 768 blocks. LDS 79.4 KB -> 2 blocks/CU.
// PV split into two k-halves reusing a per-wave 16x136 P buffer; P stored
// unnormalized, o scaled by 1/sum post-PV. (r9-proven)
// ---------------------------------------------------------------------------
__global__ __launch_bounds__(256, 2)
void attn_kernel(const bf16* __restrict__ Q, const bf16* __restrict__ Kg,
                 const bf16* __restrict__ Vg, float* __restrict__ h) {
    __shared__ bf16 Ks[TP * KST];
    __shared__ bf16 Vt[64 * PST];
    __shared__ bf16 Pw[4 * 16 * PST2];
    const int tid = threadIdx.x, lane = tid & 63, wave = tid >> 6;
    const int bh = blockIdx.x >> 1, sub = blockIdx.x & 1;
    const int b = bh / HH, hh = bh - b * HH;
    const bf16* Kp = Kg + (size_t)bh * TP * 64;
    const bf16* Vp = Vg + (size_t)bh * TP * 64;
    const bf16* Qp = Q + (size_t)bh * TP * 64;

#pragma unroll
    for (int i = 0; i < 7; i++) {
        int idx = i * 256 + tid;
        int row = idx >> 3, cb = idx & 7;
        bf16x8 kv = *(const bf16x8*)(Kp + idx * 8);
        *(bf16x8*)(Ks + row * KST + cb * 8) = kv;
        bf16x8 vv = *(const bf16x8*)(Vp + idx * 8);
#pragma unroll
        for (int j = 0; j < 8; j++) Vt[(cb * 8 + j) * PST + row] = vv[j];
    }
    __syncthreads();

    bf16* Pm = Pw + wave * 16 * PST2;
    const int cEnd = sub ? 13 : 7;
    for (int ch = sub * 7 + wave; ch < cEnd; ch += 4) {
        const int q0 = ch * 16;
        const bf16* qp = Qp + (q0 + (lane & 15)) * 64 + (lane >> 4) * 8;
        bf16x8 aq0 = *(const bf16x8*)qp;
        bf16x8 aq1 = *(const bf16x8*)(qp + 32);
        f32x4 s[14] = {};
#pragma unroll
        for (int nf = 0; nf < 14; nf++) {
            int rb = (nf * 16 + (lane & 15)) * KST + (lane >> 4) * 8;
            bf16x8 b0 = *(const bf16x8*)(Ks + rb);
            bf16x8 b1 = *(const bf16x8*)(Ks + rb + 32);
            s[nf] = mfma16(aq0, b0, s[nf]);
            s[nf] = mfma16(aq1, b1, s[nf]);
        }
        const int colbase = lane & 15;
        float mmax[4], minv[4];
#pragma unroll
        for (int j = 0; j < 4; j++) {
            float m = -1e30f;
#pragma unroll
            for (int nf = 0; nf < 14; nf++) {
                int col = nf * 16 + colbase;
                float v = (col < TT) ? s[nf][j] * 0.125f : -1e30f;
                m = fmaxf(m, v);
            }
#pragma unroll
            for (int dd = 1; dd < 16; dd <<= 1) m = fmaxf(m, __shfl_xor(m, dd));
            float sum = 0.0f;
#pragma unroll
            for (int nf = 0; nf < 14; nf++) {
                int col = nf * 16 + colbase;
                float v = (col < TT) ? s[nf][j] * 0.125f : -1e30f;
                sum += __expf(v - m);
            }
#pragma unroll
            for (int dd = 1; dd < 16; dd <<= 1) sum += __shfl_xor(sum, dd);
            mmax[j] = m;
            minv[j] = 1.0f / sum;
        }
        f32x4 o[4] = {};
#pragma unroll
        for (int j = 0; j < 4; j++) {
            int pr = (lane >> 4) * 4 + j;
#pragma unroll
            for (int nf = 0; nf < 8; nf++) {
                int col = nf * 16 + colbase;
                float v = (col < TT) ? s[nf][j] * 0.125f : -1e30f;
                Pm[pr * PST2 + nf * 16 + colbase] = (bf16)__expf(v - mmax[j]);
            }
        }
        asm volatile("s_waitcnt lgkmcnt(0)" ::: "memory");
#pragma unroll
        for (int ks = 0; ks < 4; ks++) {
            bf16x8 pa = *(const bf16x8*)(Pm + (lane & 15) * PST2 + ks * 32 + (lane >> 4) * 8);
#pragma unroll
            for (int nf = 0; nf < 4; nf++) {
                bf16x8 bv = *(const bf16x8*)(Vt + (nf * 16 + (lane & 15)) * PST + ks * 32 + (lane >> 4) * 8);
                o[nf] = mfma16(pa, bv, o[nf]);
            }
        }
        asm volatile("s_waitcnt lgkmcnt(0)" ::: "memory");
#pragma unroll
        for (int j = 0; j < 4; j++) {
            int pr = (lane >> 4) * 4 + j;
#pragma unroll
            for (int nf = 8; nf < 14; nf++) {
                int col = nf * 16 + colbase;
                float v = (col < TT) ? s[nf][j] * 0.125f : -1e30f;
                Pm[pr * PST2 + (nf - 8) * 16 + colbase] = (bf16)__expf(v - mmax[j]);
            }
        }
        asm volatile("s_waitcnt lgkmcnt(0)" ::: "memory");
#pragma unroll
        for (int ks = 4; ks < 7; ks++) {
            bf16x8 pa = *(const bf16x8*)(Pm + (lane & 15) * PST2 + (ks - 4) * 32 + (lane >> 4) * 8);
#pragma unroll
            for (int nf = 0; nf < 4; nf++) {
                bf16x8 bv = *(const bf16x8*)(Vt + (nf * 16 + (lane & 15)) * PST + ks * 32 + (lane >> 4) * 8);
                o[nf] = mfma16(pa, bv, o[nf]);
            }
        }
        asm volatile("s_waitcnt lgkmcnt(0)" ::: "memory");
#pragma unroll
        for (int nf = 0; nf < 4; nf++)
#pragma unroll
            for (int j = 0; j < 4; j++) {
                int qr = q0 + (lane >> 4) * 4 + j;
                if (qr < TT) {
                    int d = nf * 16 + (lane & 15);
                    h[(size_t)(b * TT + qr) * DD + hh * 64 + d] += o[nf][j] * minv[j];
                }
            }
    }
}

// ---------------------------------------------------------------------------
// LayerNorm (LN2 before MLP1), one row per wave, fp32 in -> bf16 out
// ---------------------------------------------------------------------------
__global__ void ln_kernel(const float* __restrict__ h, const float* __restrict__ g,
                          const float* __restrict__ bt, bf16* __restrict__ hn) {
    const int lane = threadIdx.x & 63, wave = threadIdx.x >> 6;
    const int row = blockIdx.x * 4 + wave;
    const float* x = h + (size_t)row * DD;
    float4 a[3];
#pragma unroll
    for (int i = 0; i < 3; i++) a[i] = ((const float4*)x)[lane + i * 64];
    float sum = 0.0f;
#pragma unroll
    for (int i = 0; i < 3; i++) sum += a[i].x + a[i].y + a[i].z + a[i].w;
#pragma unroll
    for (int dd = 1; dd < 64; dd <<= 1) sum += __shfl_xor(sum, dd);
    const float mu = sum * (1.0f / 768.0f);
    float sq = 0.0f;
#pragma unroll
    for (int i = 0; i < 3; i++) {
        float dx = a[i].x - mu, dy = a[i].y - mu, dz = a[i].z - mu, dw = a[i].w - mu;
        sq += dx * dx + dy * dy + dz * dz + dw * dw;
    }
#pragma unroll
    for (int dd = 1; dd < 64; dd <<= 1) sq += __shfl_xor(sq, dd);
    const float is = rsqrtf(sq * (1.0f / 768.0f) + 1e-5f);
#pragma unroll
    for (int i = 0; i < 3; i++) {
        int c4 = lane + i * 64;
        float4 gg = ((const float4*)g)[c4];
        float4 bb = ((const float4*)bt)[c4];
        bf16x4 o;
        o[0] = (bf16)((a[i].x - mu) * is * gg.x + bb.x);
        o[1] = (bf16)((a[i].y - mu) * is * gg.y + bb.y);
        o[2] = (bf16)((a[i].z - mu) * is * gg.z + bb.z);
        o[3] = (bf16)((a[i].w - mu) * is * gg.w + bb.w);
        ((bf16x4*)(hn + (size_t)row * DD))[c4] = o;
    }
}

// ---------------------------------------------------------------------------
__global__ void patch_extract(const float* __restrict__ x, bf16* __restrict__ p) {
    int idx = blockIdx.x * 256 + threadIdx.x;
    if (idx >= 6272 * 768) return;
    int k = idx % 768, row = idx / 768;
    int c = k % 3, pc = (k / 3) % 16, pr = k / 48;
    int b = row / 196, n = row - b * 196;
    int hp = n / 14, wp = n - hp * 14;
    p[idx] = (bf16)x[((size_t)(b * 3 + c) * 224 + hp * 16 + pr) * 224 + wp * 16 + pc];
}

// dual-range 8-wide cast: [0,n8a) -> oa, [n8a, n8a+n8b) -> ob.
// 32B load + 16B store per lane per iteration (write-combine sweet spot).
__global__ void cast2w_bf16(const float* __restrict__ ia, bf16* __restrict__ oa,
                            const float* __restrict__ ib, bf16* __restrict__ ob,
                            int n8a, int n8b) {
    int i = blockIdx.x * 256 + threadIdx.x;
    int stride = gridDim.x * 256;
    for (; i < n8a + n8b; i += stride) {
        const float4* src = (i < n8a) ? (const float4*)ia + 2 * i
                                      : (const float4*)ib + 2 * (i - n8a);
        bf16x8* dst = (i < n8a) ? (bf16x8*)oa + i : (bf16x8*)ob + (i - n8a);
        float4 v0 = src[0];
        float4 v1 = src[1];
        bf16x8 o;
        o[0] = (bf16)v0.x; o[1] = (bf16)v0.y; o[2] = (bf16)v0.z; o[3] = (bf16)v0.w;
        o[4] = (bf16)v1.x; o[5] = (bf16)v1.y; o[6] = (bf16)v1.z; o[7] = (bf16)v1.w;
        *dst = o;
    }
}

__global__ void cast_bf16(const float* __restrict__ in, bf16* __restrict__ out, int n4) {
    int i = blockIdx.x * 256 + threadIdx.x;
    int stride = gridDim.x * 256;
    for (; i < n4; i += stride) {
        float4 v = ((const float4*)in)[i];
        bf16x4 o;
        o[0] = (bf16)v.x; o[1] = (bf16)v.y; o[2] = (bf16)v.z; o[3] = (bf16)v.w;
        ((bf16x4*)out)[i] = o;
    }
}

__global__ void cls_init(const float* __restrict__ cls, const float* __restrict__ pos,
                         float* __restrict__ h) {
    int i = blockIdx.x * 256 + threadIdx.x;
    if (i >= BQ * DD) return;
    int b = i / DD, c = i - b * DD;
    h[(size_t)(b * TT) * DD + c] = cls[c] + pos[c];
}

// head over cls rows only; ACCP folds the final MLP2 bf16-partial reduce (+b2)
template <int ACCP>
__global__ void head_kernel(const float* __restrict__ h, const bf16* __restrict__ part,
                            const float* __restrict__ b2,
                            const float* __restrict__ hw, const float* __restrict__ hb,
                            float* __restrict__ out) {
    __shared__ float xr[DD];
    const int b = blockIdx.y;
    const int n = blockIdx.x * 256 + threadIdx.x;
    const size_t rowoff = (size_t)(b * TT) * DD;
    for (int i = threadIdx.x; i < DD; i += 256) {
        float v = h[rowoff + i];
        if (ACCP) {
            v += (float)part[((size_t)0 * MP + b * TT) * DD + i];
            v += (float)part[((size_t)1 * MP + b * TT) * DD + i];
            v += b2[i];
        }
        xr[i] = v;
    }
    __syncthreads();
    if (n < 1000) {
        float s = hb[n];
        const float4* w = (const float4*)(hw + (size_t)n * DD);
        float acc = 0.0f;
#pragma unroll 4
        for (int k = 0; k < DD / 4; k++) {
            float4 wv = w[k];
            float4 xv = ((const float4*)xr)[k];
            acc += wv.x * xv.x + wv.y * xv.y + wv.z * xv.z + wv.w * xv.w;
        }
        out[b * 1000 + n] = s + acc;
    }
}

// ---------------------------------------------------------------------------
extern "C" void kernel_launch(void* const* d_in, const int* in_sizes, int n_in,
                              void* d_out, int out_size, void* d_ws, size_t ws_size,
                              hipStream_t stream) {
    const float* x       = (const float*)d_in[0];
    const float* patch_w = (const float*)d_in[1];
    const float* patch_b = (const float*)d_in[2];
    const float* pos_enc = (const float*)d_in[3];
    const float* cls_tok = (const float*)d_in[4];
    const float* qkv_w   = (const float*)d_in[5];
    const float* qkv_b   = (const float*)d_in[6];
    const float* ln_g    = (const float*)d_in[7];
    const float* ln_b    = (const float*)d_in[8];
    const float* w1      = (const float*)d_in[9];
    const float* b1      = (const float*)d_in[10];
    const float* w2      = (const float*)d_in[11];
    const float* b2      = (const float*)d_in[12];
    const float* head_w  = (const float*)d_in[13];
    const float* head_b  = (const float*)d_in[14];

    char* wp = (char*)d_ws;
    auto carve = [&](size_t bytes) {
        char* r = wp;
        wp += (bytes + 255) & ~(size_t)255;
        return r;
    };
    auto fits = [&](size_t bytes) {
        return (size_t)(wp - (char*)d_ws) + bytes + 256 <= ws_size;
    };
    float* h  = (float*)carve((size_t)MP * DD * 4);
    bf16* hn  = (bf16*)carve((size_t)MP * DD * 2);
    bf16* u   = (bf16*)carve((size_t)MP * FF * 2);
    bf16* qs  = (bf16*)carve((size_t)BQ * HH * TP * 64 * 2);
    bf16* ks  = (bf16*)carve((size_t)BQ * HH * TP * 64 * 2);
    bf16* vs  = (bf16*)carve((size_t)BQ * HH * TP * 64 * 2);
    bf16* p   = (bf16*)carve((size_t)6272 * DD * 2);
    bf16* pwb = (bf16*)carve((size_t)DD * DD * 2);
    bf16* qwb = (bf16*)carve((size_t)LL * 192 * 64 * 2);

    // split-K partials (NSPLIT x MP x DD bf16), if ws allows
    bf16* part = nullptr;
    if (fits((size_t)NSPLIT * MP * DD * 2))
        part = (bf16*)carve((size_t)NSPLIT * MP * DD * 2);
    const bool use_part = (part != nullptr);

    // precast-all weights, if ws allows
    const size_t wfull = (size_t)LL * FF * DD * 2;
    const bool precast = fits(2 * (wfull + 256));
    bf16* w1b = (bf16*)carve(precast ? wfull : (size_t)FF * DD * 2);
    bf16* w2b = (bf16*)carve(precast ? wfull : (size_t)DD * FF * 2);

    cast2w_bf16<<<720, 256, 0, stream>>>(patch_w, pwb, qkv_w, qwb,
                                         (DD * DD) / 8, (LL * 192 * 64) / 8);
    if (precast) {
        cast2w_bf16<<<8192, 256, 0, stream>>>(w1, w1b, w2, w2b,
                                              (LL * FF * DD) / 8, (LL * FF * DD) / 8);
    }
    patch_extract<<<18816, 256, 0, stream>>>(x, p);
    cls_init<<<96, 256, 0, stream>>>(cls_tok, pos_enc, h);
    gemm_bt<0, 1, 768, 768, 6, 49><<<294, 256, 0, stream>>>(p, pwb, patch_b,
                                                            h, nullptr, pos_enc);

    for (int i = 0; i < LL; i++) {
        const bf16* w1i = precast ? (w1b + (size_t)i * FF * DD) : w1b;
        const bf16* w2i = precast ? (w2b + (size_t)i * FF * DD) : w2b;

        // fused LN1 (+ previous layer's MLP2 bf16-partial reduction) + QKV
        if (use_part && i > 0)
            lnqkv_kernel<1><<<MR / 16, 256, 0, stream>>>(h, part, b2 + (i - 1) * DD,
                                                         ln_g + i * DD, ln_b + i * DD,
                                                         qwb + i * 192 * 64, qkv_b + i * 192,
                                                         qs, ks, vs);
        else
            lnqkv_kernel<0><<<MR / 16, 256, 0, stream>>>(h, nullptr, nullptr,
                                                         ln_g + i * DD, ln_b + i * DD,
                                                         qwb + i * 192 * 64, qkv_b + i * 192,
                                                         qs, ks, vs);

        attn_kernel<<<BQ * HH * 2, 256, 0, stream>>>(qs, ks, vs, h);
        ln_kernel<<<MP / 4, 256, 0, stream>>>(h, ln_g + i * DD, ln_b + i * DD, hn);
        if (!precast)
            cast_bf16<<<2048, 256, 0, stream>>>(w1 + (size_t)i * FF * DD, w1b, (FF * DD) / 4);
        gemm_bt<1, 1, 768, 3072, 24, 50><<<1200, 256, 0, stream>>>(hn, w1i, b1 + i * FF,
                                                                   nullptr, u, nullptr);
        if (!precast)
            cast_bf16<<<2048, 256, 0, stream>>>(w2 + (size_t)i * FF * DD, w2b, (FF * DD) / 4);
        if (use_part)
            gemm_bt<3, NSPLIT, 3072, 768, 6, 50><<<300 * NSPLIT, 256, 0, stream>>>(
                u, w2i, nullptr, nullptr, part, nullptr);
        else
            gemm_bt<2, 1, 3072, 768, 6, 50><<<300, 256, 0, stream>>>(
                u, w2i, b2 + i * DD, h, nullptr, nullptr);
    }
    if (use_part)
        head_kernel<1><<<dim3(4, BQ), 256, 0, stream>>>(h, part, b2 + 11 * DD,
                                                        head_w, head_b, (float*)d_out);
    else
        head_kernel<0><<<dim3(4, BQ), 256, 0, stream>>>(h, nullptr, nullptr,
                                                        head_w, head_b, (float*)d_out);
}